// Round 1
// 459.993 us; speedup vs baseline: 1.0300x; 1.0300x over previous
//
#include <hip/hip_runtime.h>
#include <hip/hip_bf16.h>

#define N_NODES 50000
#define E_EDGES 800000
#define D_MODEL 256
#define H_HEADS 8
#define HDIM    32
#define F_FFN   1024
#define ATT_SCALE 0.0625f   // 256^-0.5
#define LN_EPS  1e-5f
#define NB_SCAN 196         // ceil(N_NODES/256)

typedef __attribute__((ext_vector_type(8))) short bf16x8;
typedef __attribute__((ext_vector_type(4))) float f32x4;

__device__ __forceinline__ float bf2f(__hip_bfloat16 v) { return __bfloat162float(v); }
__device__ __forceinline__ __hip_bfloat16 f2bf(float v) { return __float2bfloat16(v); }
__device__ __forceinline__ unsigned short bfbits(float f) {
    __hip_bfloat16 h = __float2bfloat16(f);
    return *reinterpret_cast<unsigned short*>(&h);
}
__device__ __forceinline__ unsigned char f2fp8(float v) {
    return (unsigned char)(__builtin_amdgcn_cvt_pk_fp8_f32(v, v, 0, false) & 0xff);
}

// load 4 consecutive bf16 (8B aligned) -> float4
__device__ __forceinline__ float4 load_bf16x4(const __hip_bfloat16* p) {
    uint2 u = *reinterpret_cast<const uint2*>(p);
    float4 r;
    r.x = __uint_as_float(u.x << 16);
    r.y = __uint_as_float(u.x & 0xFFFF0000u);
    r.z = __uint_as_float(u.y << 16);
    r.w = __uint_as_float(u.y & 0xFFFF0000u);
    return r;
}

// async global->LDS, 16B per lane; LDS dest must be wave-uniform base (+lane*16 implicit)
__device__ __forceinline__ void load_lds16(const void* g, void* l) {
    __builtin_amdgcn_global_load_lds(
        (const __attribute__((address_space(1))) unsigned*)g,
        (__attribute__((address_space(3))) unsigned*)l, 16, 0, 0);
}

// ---------------- fused prep: cvt_x + 3 weight transposes + zero counts/cursor --------
#define PREP_X   3200000                    // N*256/4 float4 units
#define PREP_WQ  (768 * 256)
#define PREP_W1  (1024 * 256)
#define PREP_W2  (256 * 1024)
#define PREP_TOT (PREP_X + PREP_WQ + PREP_W1 + PREP_W2 + N_NODES)
__global__ void prep_kernel(const float* __restrict__ x, unsigned short* __restrict__ xb,
                            const float* __restrict__ wq, __hip_bfloat16* __restrict__ wtq,
                            const float* __restrict__ w1, __hip_bfloat16* __restrict__ wt1,
                            const float* __restrict__ w2, __hip_bfloat16* __restrict__ wt2,
                            unsigned* __restrict__ counts, unsigned* __restrict__ cursor) {
    int i = blockIdx.x * blockDim.x + threadIdx.x;
    if (i < PREP_X) {
        float4 v = reinterpret_cast<const float4*>(x)[i];
        ushort4 o;
        o.x = bfbits(v.x); o.y = bfbits(v.y); o.z = bfbits(v.z); o.w = bfbits(v.w);
        reinterpret_cast<ushort4*>(xb)[i] = o;
        return;
    }
    i -= PREP_X;
    if (i < PREP_WQ) {
        int n = i >> 8, k = i & 255;
        wtq[i] = f2bf(wq[(size_t)k * 768 + n]);
        return;
    }
    i -= PREP_WQ;
    if (i < PREP_W1) {
        int n = i >> 8, k = i & 255;
        wt1[i] = f2bf(w1[(size_t)k * 1024 + n]);
        return;
    }
    i -= PREP_W1;
    if (i < PREP_W2) {
        int n = i >> 10, k = i & 1023;
        wt2[i] = f2bf(w2[(size_t)k * 256 + n]);
        return;
    }
    i -= PREP_W2;
    if (i < N_NODES) { counts[i] = 0u; cursor[i] = 0u; }
}

// ---------------- MFMA GEMM: out = A @ Wt^T + bias [,relu][,qkv-split] ----------------
// A: MxK bf16 row-major. Wt: NxK bf16 row-major (pre-transposed weights).
// 128x128 tile, 256 threads = 4 waves (2x2 of 64x64), 16x16x32 bf16 MFMA, BK=32.
// LDS layout [128 rows][32 k] with k-part XOR swizzle (stage and read use same perm).
// SPLIT: out col gn -> head h=gn/96, rr=gn%96:
//   rr<32 -> qb[m][h*32+rr] bf16; else fp8 e4m3 into kv8[m] (512 B/row):
//   chunk layout: byte (d>>2)*8 + (d&3) for k-dim d, +4 for v-dim d.
template<bool RELU, bool OUT_BF16, bool SPLIT>
__global__ __launch_bounds__(256)
void mfma_gemm(const __hip_bfloat16* __restrict__ A,
               const __hip_bfloat16* __restrict__ Wt,
               const float* __restrict__ bias,
               void* __restrict__ outp,
               __hip_bfloat16* __restrict__ qb,
               unsigned char* __restrict__ kv8,
               int M, int Ncols, int K) {
    __shared__ short Al[128 * 32];
    __shared__ short Bl[128 * 32];
    const int t = threadIdx.x;
    const int wave = t >> 6, lane = t & 63;
    const int m0 = blockIdx.y * 128, n0 = blockIdx.x * 128;
    const int wr = wave >> 1, wc = wave & 1;

    const int srow = lane >> 2;                        // row within chunk 0..15
    const int skp  = (lane & 3) ^ ((lane >> 3) & 3);   // swizzled global k-part
    const int c0 = wave * 2;
    int ar0 = m0 + c0 * 16 + srow;      if (ar0 >= M) ar0 = M - 1;
    int ar1 = m0 + c0 * 16 + 16 + srow; if (ar1 >= M) ar1 = M - 1;
    const __hip_bfloat16* ga0 = A + (size_t)ar0 * K + skp * 8;
    const __hip_bfloat16* ga1 = A + (size_t)ar1 * K + skp * 8;
    const __hip_bfloat16* gb0 = Wt + (size_t)(n0 + c0 * 16 + srow) * K + skp * 8;
    const __hip_bfloat16* gb1 = Wt + (size_t)(n0 + c0 * 16 + 16 + srow) * K + skp * 8;
    short* la0 = &Al[c0 * 512];
    short* la1 = &Al[c0 * 512 + 512];
    short* lb0 = &Bl[c0 * 512];
    short* lb1 = &Bl[c0 * 512 + 512];

    const int lh = lane & 15, q = lane >> 4;
    const int qs = q ^ ((lane >> 1) & 3);
    const short* fa = &Al[(wr * 64 + lh) * 32 + qs * 8];
    const short* fb = &Bl[(wc * 64 + lh) * 32 + qs * 8];

    f32x4 acc[4][4] = {};

    for (int k0 = 0; k0 < K; k0 += 32) {
        load_lds16(ga0, la0);
        load_lds16(ga1, la1);
        load_lds16(gb0, lb0);
        load_lds16(gb1, lb1);
        ga0 += 32; ga1 += 32; gb0 += 32; gb1 += 32;
        __syncthreads();

        bf16x8 af[4], bfr[4];
#pragma unroll
        for (int i = 0; i < 4; i++) {
            af[i]  = *reinterpret_cast<const bf16x8*>(fa + i * 16 * 32);
            bfr[i] = *reinterpret_cast<const bf16x8*>(fb + i * 16 * 32);
        }
#pragma unroll
        for (int mi = 0; mi < 4; mi++)
#pragma unroll
            for (int nj = 0; nj < 4; nj++)
                acc[mi][nj] = __builtin_amdgcn_mfma_f32_16x16x32_bf16(
                    af[mi], bfr[nj], acc[mi][nj], 0, 0, 0);
        __syncthreads();
    }

    // epilogue: C/D layout col = lane&15, row = (lane>>4)*4 + reg
    const int gnbase = n0 + wc * 64 + lh;
    float bv[4];
#pragma unroll
    for (int nj = 0; nj < 4; nj++) bv[nj] = bias[gnbase + nj * 16];

#pragma unroll
    for (int mi = 0; mi < 4; mi++) {
        int gmb = m0 + wr * 64 + mi * 16 + q * 4;
#pragma unroll
        for (int r = 0; r < 4; r++) {
            int gm = gmb + r;
            if (gm >= M) continue;
#pragma unroll
            for (int nj = 0; nj < 4; nj++) {
                int gn = gnbase + nj * 16;
                float v = acc[mi][nj][r] + bv[nj];
                if (RELU) v = fmaxf(v, 0.f);
                if (SPLIT) {
                    int h  = gn / 96;        // magic-mul
                    int rr = gn - h * 96;
                    if (rr < 32) {
                        qb[(size_t)gm * 256 + h * 32 + rr] = f2bf(v);
                    } else {
                        int d   = h * 32 + (rr < 64 ? rr - 32 : rr - 64);
                        int off = (d >> 2) * 8 + (d & 3) + (rr < 64 ? 0 : 4);
                        kv8[(size_t)gm * 512 + off] = f2fp8(v);
                    }
                } else if (OUT_BF16) {
                    ((__hip_bfloat16*)outp)[(size_t)gm * Ncols + gn] = f2bf(v);
                } else {
                    ((float*)outp)[(size_t)gm * Ncols + gn] = v;
                }
            }
        }
    }
}

// ---------------- ffn2 + fused LN2: out = LN(hbuf @ wt2^T + b2 + xn) ------------------
// Re-tiled for occupancy: 64 x 256 tile (full rows), 512 threads = 8 waves
// (2 row-groups x 4 col-groups of 32x64 each), K=1024, BK=32.
// Grid = 782 blocks (vs 391 at 128-row tile): ~3 blocks/CU -> ~24 waves/CU so the
// per-K-step vmcnt(0)+barrier drain overlaps with co-resident blocks' MFMA.
// Staging: 20 chunks of 16 rows (A:4, B:16); wave w stages {w, w+8}, waves 0-3 also {w+16}.
// LN via lh-shfl + LDS merge over the 4 col-groups.
__global__ __launch_bounds__(512)
void ffn2_ln_kernel(const __hip_bfloat16* __restrict__ A,    // M x 1024
                    const __hip_bfloat16* __restrict__ Wt,   // 256 x 1024
                    const float* __restrict__ bias,
                    const __hip_bfloat16* __restrict__ resid,// M x 256
                    const float* __restrict__ g, const float* __restrict__ bb,
                    float* __restrict__ out, int M) {
    __shared__ short Al[64 * 32];
    __shared__ short Bl[256 * 32];
    const int t = threadIdx.x;
    const int wave = t >> 6, lane = t & 63;
    const int m0 = blockIdx.x * 64;
    const int wr = wave >> 2, wc = wave & 3;

    const int srow = lane >> 2;                        // row within chunk 0..15
    const int skp  = (lane & 3) ^ ((lane >> 3) & 3);   // swizzled global k-part

    const __hip_bfloat16* gsrc0; short* ldst0;
    const __hip_bfloat16* gsrc1; short* ldst1;
    const __hip_bfloat16* gsrc2 = A; short* ldst2 = Al;   // dummy for waves 4-7
    {
#define STAGE_INIT(GS, LD, C)                                            \
        if ((C) < 4) {                                                   \
            int r_ = m0 + (C) * 16 + srow; if (r_ >= M) r_ = M - 1;      \
            GS = A + (size_t)r_ * 1024 + skp * 8;                        \
            LD = &Al[(C) * 512];                                         \
        } else {                                                         \
            GS = Wt + (size_t)(((C) - 4) * 16 + srow) * 1024 + skp * 8;  \
            LD = &Bl[((C) - 4) * 512];                                   \
        }
        STAGE_INIT(gsrc0, ldst0, wave)
        STAGE_INIT(gsrc1, ldst1, wave + 8)
        if (wave < 4) { STAGE_INIT(gsrc2, ldst2, wave + 16) }
#undef STAGE_INIT
    }

    const int lh = lane & 15, q = lane >> 4;
    const int qs = q ^ ((lane >> 1) & 3);
    const short* fa = &Al[(wr * 32 + lh) * 32 + qs * 8];
    const short* fb = &Bl[(wc * 64 + lh) * 32 + qs * 8];

    f32x4 acc[2][4] = {};

    for (int k0 = 0; k0 < 1024; k0 += 32) {
        load_lds16(gsrc0, ldst0);
        load_lds16(gsrc1, ldst1);
        if (wave < 4) load_lds16(gsrc2, ldst2);
        gsrc0 += 32; gsrc1 += 32; gsrc2 += 32;
        __syncthreads();

        bf16x8 af[2], bfr[4];
#pragma unroll
        for (int i = 0; i < 2; i++)
            af[i]  = *reinterpret_cast<const bf16x8*>(fa + i * 16 * 32);
#pragma unroll
        for (int i = 0; i < 4; i++)
            bfr[i] = *reinterpret_cast<const bf16x8*>(fb + i * 16 * 32);
#pragma unroll
        for (int mi = 0; mi < 2; mi++)
#pragma unroll
            for (int nj = 0; nj < 4; nj++)
                acc[mi][nj] = __builtin_amdgcn_mfma_f32_16x16x32_bf16(
                    af[mi], bfr[nj], acc[mi][nj], 0, 0, 0);
        __syncthreads();
    }

    // ---- epilogue: v = acc + b2 + xn; per-row LN over 256 cols; write f32 ----
    const int colbase = wc * 64 + lh;   // + nj*16
    float bv[4], gv[4], bbv[4];
#pragma unroll
    for (int nj = 0; nj < 4; nj++) {
        bv[nj]  = bias[colbase + nj * 16];
        gv[nj]  = g[colbase + nj * 16];
        bbv[nj] = bb[colbase + nj * 16];
    }

    float ps[2][4], pq[2][4];   // [mi][r] partial row sums over this lane's 4 cols
#pragma unroll
    for (int mi = 0; mi < 2; mi++) {
#pragma unroll
        for (int r = 0; r < 4; r++) {
            int gm = m0 + wr * 32 + mi * 16 + q * 4 + r;
            int rgm = (gm < M) ? gm : M - 1;
            float s = 0.f, s2 = 0.f;
#pragma unroll
            for (int nj = 0; nj < 4; nj++) {
                float v = acc[mi][nj][r] + bv[nj]
                        + bf2f(resid[(size_t)rgm * 256 + colbase + nj * 16]);
                acc[mi][nj][r] = v;
                s += v; s2 += v * v;
            }
            ps[mi][r] = s; pq[mi][r] = s2;
        }
    }
    // reduce over the 16-lane col group (lh)
#pragma unroll
    for (int off = 1; off <= 8; off <<= 1) {
#pragma unroll
        for (int mi = 0; mi < 2; mi++)
#pragma unroll
            for (int r = 0; r < 4; r++) {
                ps[mi][r] += __shfl_xor(ps[mi][r], off);
                pq[mi][r] += __shfl_xor(pq[mi][r], off);
            }
    }
    // cross-wave (wc) merge via LDS (reuse Al: 64 rows x 4 wc x 2 vals = 2 KB)
    float* rs = (float*)Al;            // [64][4]
    float* rq = (float*)(Al + 512);    // +1024 B
    if (lh == 0) {
#pragma unroll
        for (int mi = 0; mi < 2; mi++)
#pragma unroll
            for (int r = 0; r < 4; r++) {
                int m = wr * 32 + mi * 16 + q * 4 + r;
                rs[m * 4 + wc] = ps[mi][r];
                rq[m * 4 + wc] = pq[mi][r];
            }
    }
    __syncthreads();

#pragma unroll
    for (int mi = 0; mi < 2; mi++) {
#pragma unroll
        for (int r = 0; r < 4; r++) {
            int m = wr * 32 + mi * 16 + q * 4 + r;
            int gm = m0 + m;
            if (gm >= M) continue;
            float4 rsv = *reinterpret_cast<const float4*>(&rs[m * 4]);
            float4 rqv = *reinterpret_cast<const float4*>(&rq[m * 4]);
            float S  = (rsv.x + rsv.y) + (rsv.z + rsv.w);
            float S2 = (rqv.x + rqv.y) + (rqv.z + rqv.w);
            float mean = S * (1.f / (float)D_MODEL);
            float var  = S2 * (1.f / (float)D_MODEL) - mean * mean;
            float inv  = rsqrtf(var + LN_EPS);
#pragma unroll
            for (int nj = 0; nj < 4; nj++)
                out[(size_t)gm * 256 + colbase + nj * 16] =
                    (acc[mi][nj][r] - mean) * inv * gv[nj] + bbv[nj];
        }
    }
}

// ---------------- CSR build ----------------
__global__ void count_kernel(const int* __restrict__ rows, unsigned* __restrict__ counts) {
    int e = blockIdx.x * blockDim.x + threadIdx.x;
    if (e < E_EDGES) atomicAdd(&counts[rows[e]], 1u);
}

__global__ void scan_blk_kernel(const unsigned* __restrict__ counts,
                                unsigned* __restrict__ offs, unsigned* __restrict__ bsum) {
    __shared__ unsigned sh[256];
    int t = threadIdx.x;
    int i = blockIdx.x * 256 + t;
    unsigned v = (i < N_NODES) ? counts[i] : 0u;
    sh[t] = v;
    __syncthreads();
#pragma unroll
    for (int off = 1; off < 256; off <<= 1) {
        unsigned u = (t >= off) ? sh[t - off] : 0u;
        __syncthreads();
        sh[t] += u;
        __syncthreads();
    }
    if (i < N_NODES) offs[i] = sh[t] - v;
    if (t == 255) bsum[blockIdx.x] = sh[255];
}

__global__ void scan_top_kernel(const unsigned* __restrict__ bsum, unsigned* __restrict__ bpre) {
    __shared__ unsigned sh[256];
    int t = threadIdx.x;
    unsigned v = (t < NB_SCAN) ? bsum[t] : 0u;
    sh[t] = v;
    __syncthreads();
#pragma unroll
    for (int off = 1; off < 256; off <<= 1) {
        unsigned u = (t >= off) ? sh[t - off] : 0u;
        __syncthreads();
        sh[t] += u;
        __syncthreads();
    }
    if (t < NB_SCAN) bpre[t] = sh[t] - v;
    if (t == NB_SCAN - 1) bpre[NB_SCAN] = sh[t];
}

__global__ void scan_add_kernel(unsigned* __restrict__ offs, const unsigned* __restrict__ bpre) {
    int i = blockIdx.x * 256 + threadIdx.x;
    if (i < N_NODES) offs[i] += bpre[blockIdx.x];
    if (i == 0) offs[N_NODES] = bpre[NB_SCAN];
}

__global__ void scatter_kernel(const int* __restrict__ rows, const int* __restrict__ cols,
                               const unsigned* __restrict__ offsets, unsigned* __restrict__ cursor,
                               int* __restrict__ scol) {
    int e = blockIdx.x * blockDim.x + threadIdx.x;
    if (e >= E_EDGES) return;
    int r = rows[e];
    unsigned idx = atomicAdd(&cursor[r], 1u);
    scol[offsets[r] + idx] = cols[e];
}

// ---------------- attention (wave-per-node, fp8 k/v) + fused LN1 ----------------
// Block = 4 nodes, one wave each. kv8 row (512 B) = 64 chunks: chunk c = 4 fp8 k-dims
// (4c..4c+3) then 4 fp8 v-dims. Lane c loads ONE 8B chunk per edge. 8 lanes/head.
// Single-pass exp (|s|<=8 here; softmax shift-invariant => identical to reference).
__global__ __launch_bounds__(256)
void att_agg_kernel(const __hip_bfloat16* __restrict__ qb,
                    const unsigned char* __restrict__ kv8,
                    const unsigned* __restrict__ offsets,
                    const int* __restrict__ scol,
                    const float* __restrict__ x,
                    const float* __restrict__ g, const float* __restrict__ bb,
                    __hip_bfloat16* __restrict__ xn) {
    int n = blockIdx.x * 4 + (threadIdx.x >> 6);
    if (n >= N_NODES) return;
    int lam = threadIdx.x & 63;
    unsigned beg = offsets[n], end = offsets[n + 1];

    float4 qf = load_bf16x4(qb + (size_t)n * 256 + lam * 4);
    qf.x *= ATT_SCALE; qf.y *= ATT_SCALE; qf.z *= ATT_SCALE; qf.w *= ATT_SCALE;

    float4 acc = {0.f, 0.f, 0.f, 0.f};
    float l = 0.f;

#define EDGE_BODY(KV, SV, PV)                                                 \
    unsigned klo = (unsigned)(KV), vhi = (unsigned)((KV) >> 32);              \
    auto k01 = __builtin_amdgcn_cvt_pk_f32_fp8((int)klo, false);              \
    auto k23 = __builtin_amdgcn_cvt_pk_f32_fp8((int)klo, true);               \
    float SV = qf.x * k01[0] + qf.y * k01[1] + qf.z * k23[0] + qf.w * k23[1]; \
    SV += __shfl_xor(SV, 1);                                                  \
    SV += __shfl_xor(SV, 2);                                                  \
    SV += __shfl_xor(SV, 4);                                                  \
    float PV = __expf(SV);                                                    \
    auto v01 = __builtin_amdgcn_cvt_pk_f32_fp8((int)vhi, false);              \
    auto v23 = __builtin_amdgcn_cvt_pk_f32_fp8((int)vhi, true);               \
    l += PV;                                                                  \
    acc.x += PV * v01[0]; acc.y += PV * v01[1];                               \
    acc.z += PV * v23[0]; acc.w += PV * v23[1];

    unsigned e = beg;
    for (; e + 4 <= end; e += 4) {
        int c0 = scol[e], c1 = scol[e + 1], c2 = scol[e + 2], c3 = scol[e + 3];
        unsigned long long kv0 = *(const unsigned long long*)(kv8 + (size_t)c0 * 512 + lam * 8);
        unsigned long long kv1 = *(const unsigned long long*)(kv8 + (size_t)c1 * 512 + lam * 8);
        unsigned long long kv2 = *(const unsigned long long*)(kv8 + (size_t)c2 * 512 + lam * 8);
        unsigned long long kv3 = *(const unsigned long long*)(kv8 + (size_t)c3 * 512 + lam * 8);
        { EDGE_BODY(kv0, s0, p0) }
        { EDGE_BODY(kv1, s1, p1) }
        { EDGE_BODY(kv2, s2, p2) }
        { EDGE_BODY(kv3, s3, p3) }
    }
    for (; e < end; e++) {
        int c0 = scol[e];
        unsigned long long kv0 = *(const unsigned long long*)(kv8 + (size_t)c0 * 512 + lam * 8);
        { EDGE_BODY(kv0, s0, p0) }
    }
#undef EDGE_BODY

    float inv_l = (l > 0.f) ? 1.f / l : 0.f;
    float4 xr = reinterpret_cast<const float4*>(x + (size_t)n * D_MODEL)[lam];
    float4 tv;
    tv.x = acc.x * inv_l + xr.x;
    tv.y = acc.y * inv_l + xr.y;
    tv.z = acc.z * inv_l + xr.z;
    tv.w = acc.w * inv_l + xr.w;

    float s  = tv.x + tv.y + tv.z + tv.w;
    float s2 = tv.x * tv.x + tv.y * tv.y + tv.z * tv.z + tv.w * tv.w;
#pragma unroll
    for (int off = 1; off <= 32; off <<= 1) {
        s  += __shfl_xor(s, off);
        s2 += __shfl_xor(s2, off);
    }
    float mean = s * (1.f / (float)D_MODEL);
    float var  = s2 * (1.f / (float)D_MODEL) - mean * mean;
    float inv  = rsqrtf(var + LN_EPS);

    float4 gr = reinterpret_cast<const float4*>(g  + lam * 4)[0];
    float4 br = reinterpret_cast<const float4*>(bb + lam * 4)[0];
    ushort4 o;
    o.x = bfbits((tv.x - mean) * inv * gr.x + br.x);
    o.y = bfbits((tv.y - mean) * inv * gr.y + br.y);
    o.z = bfbits((tv.z - mean) * inv * gr.z + br.z);
    o.w = bfbits((tv.w - mean) * inv * gr.w + br.w);
    reinterpret_cast<ushort4*>(xn + (size_t)n * D_MODEL)[lam] = o;
}

extern "C" void kernel_launch(void* const* d_in, const int* in_sizes, int n_in,
                              void* d_out, int out_size, void* d_ws, size_t ws_size,
                              hipStream_t stream) {
    const float* x     = (const float*)d_in[0];
    const int*   ei    = (const int*)d_in[1];
    const float* w_qkv = (const float*)d_in[2];
    const float* b_qkv = (const float*)d_in[3];
    const float* ln1_g = (const float*)d_in[4];
    const float* ln1_b = (const float*)d_in[5];
    const float* ln2_g = (const float*)d_in[6];
    const float* ln2_b = (const float*)d_in[7];
    const float* w1    = (const float*)d_in[8];
    const float* b1    = (const float*)d_in[9];
    const float* w2    = (const float*)d_in[10];
    const float* b2    = (const float*)d_in[11];
    const int* rows = ei;
    const int* cols = ei + E_EDGES;

    // workspace layout (bytes), total < 179,200,000 (known-good footprint):
    //   [0,          25,600,000)  qb  bf16 N*256 } dead after att_agg;
    //   [25,600,000, 51,200,000)  kv8 fp8  N*512 } region [0,102.4e6) reused
    //                                            } as hbuf bf16 N*1024
    //   [102,400,000,128,000,000) xb bf16 N*256 (dead after qkv gemm)
    //   [128,000,000,128,393,216) wtq bf16 768x256
    //   [128,400,000,128,924,288) wt1 bf16 1024x256
    //   [129,000,000,129,524,288) wt2 bf16 256x1024
    //   [129,600,000,129,800,000) counts u32 N
    //   [129,800,000,130,000,004) offsets u32 N+1
    //   [130,000,008,130,200,008) cursor u32 N
    //   [130,200,008,133,400,008) scol i32 E
    //   [133,400,008,133,401,032) bsum u32 256
    //   [133,401,032,133,402,060) bpre u32 257
    //   [153,600,000,179,200,000) xn bf16 N*256
    char* ws = (char*)d_ws;
    __hip_bfloat16* qb      = (__hip_bfloat16*)(ws + 0);
    unsigned char*  kv8     = (unsigned char*)(ws + 25600000);
    __hip_bfloat16* hbuf    = (__hip_bfloat16*)(ws + 0);
    __hip_bfloat16* xb      = (__hip_bfloat16*)(ws + 102400000);
    __hip_bfloat16* wtq     = (__hip_bfloat16*)(ws + 128000000);
    __hip_bfloat16* wt1     = (__hip_bfloat16*)(ws + 128400000);
    __hip_bfloat16* wt2     = (__hip_bfloat16*)(ws + 129000000);
    unsigned*       counts  = (unsigned*)(ws + 129600000);
    unsigned*       offsets = (unsigned*)(ws + 129800000);
    unsigned*       cursor  = (unsigned*)(ws + 130000008);
    int*            scol    = (int*)(ws + 130200008);
    unsigned*       bsum    = (unsigned*)(ws + 133400008);
    unsigned*       bpre    = (unsigned*)(ws + 133401032);
    __hip_bfloat16* xn      = (__hip_bfloat16*)(ws + 153600000);

    const int nbM = (N_NODES + 127) / 128;   // 391

    // fused prep: x->bf16, weights->bf16 transposed, zero counts/cursor
    prep_kernel<<<(PREP_TOT + 255) / 256, 256, 0, stream>>>(
        x, (unsigned short*)xb, w_qkv, wtq, w1, wt1, w2, wt2, counts, cursor);

    // q(bf16)/kv(fp8) = split(xb @ wtq^T + b_qkv)
    mfma_gemm<false, true, true><<<dim3(768 / 128, nbM), 256, 0, stream>>>(
        xb, wtq, b_qkv, nullptr, qb, kv8, N_NODES, 768, D_MODEL);

    // CSR build (hierarchical scan)
    count_kernel<<<(E_EDGES + 255) / 256, 256, 0, stream>>>(rows, counts);
    scan_blk_kernel<<<NB_SCAN, 256, 0, stream>>>(counts, offsets, bsum);
    scan_top_kernel<<<1, 256, 0, stream>>>(bsum, bpre);
    scan_add_kernel<<<NB_SCAN, 256, 0, stream>>>(offsets, bpre);
    scatter_kernel<<<(E_EDGES + 255) / 256, 256, 0, stream>>>(rows, cols, offsets, cursor, scol);

    // attention (wave-per-node, fp8 kv, 4-edge unroll) + fused LN1 -> xn
    att_agg_kernel<<<(N_NODES + 3) / 4, 256, 0, stream>>>(qb, kv8, offsets, scol,
                                                          x, ln1_g, ln1_b, xn);

    // hbuf = relu(xn @ wt1^T + b1)
    mfma_gemm<true, true, false><<<dim3(F_FFN / 128, nbM), 256, 0, stream>>>(
        xn, wt1, b1, hbuf, nullptr, nullptr, N_NODES, F_FFN, D_MODEL);

    // d_out = LN2(hbuf @ wt2^T + b2 + xn)   (fused, f32 out; 64-row tiles -> 782 blocks)
    ffn2_ln_kernel<<<(N_NODES + 63) / 64, 512, 0, stream>>>(hbuf, wt2, b2, xn, ln2_g, ln2_b,
                                                            (float*)d_out, N_NODES);
}

// Round 2
// 426.505 us; speedup vs baseline: 1.1109x; 1.0785x over previous
//
#include <hip/hip_runtime.h>
#include <hip/hip_bf16.h>

#define N_NODES 50000
#define E_EDGES 800000
#define D_MODEL 256
#define H_HEADS 8
#define HDIM    32
#define F_FFN   1024
#define ATT_SCALE 0.0625f   // 256^-0.5
#define LN_EPS  1e-5f
#define NB_SCAN 196         // ceil(N_NODES/256)

typedef __attribute__((ext_vector_type(8))) short bf16x8;
typedef __attribute__((ext_vector_type(4))) float f32x4;

__device__ __forceinline__ float bf2f(__hip_bfloat16 v) { return __bfloat162float(v); }
__device__ __forceinline__ __hip_bfloat16 f2bf(float v) { return __float2bfloat16(v); }
__device__ __forceinline__ unsigned short bfbits(float f) {
    __hip_bfloat16 h = __float2bfloat16(f);
    return *reinterpret_cast<unsigned short*>(&h);
}

// load 4 consecutive bf16 (8B aligned) -> float4
__device__ __forceinline__ float4 load_bf16x4(const __hip_bfloat16* p) {
    uint2 u = *reinterpret_cast<const uint2*>(p);
    float4 r;
    r.x = __uint_as_float(u.x << 16);
    r.y = __uint_as_float(u.x & 0xFFFF0000u);
    r.z = __uint_as_float(u.y << 16);
    r.w = __uint_as_float(u.y & 0xFFFF0000u);
    return r;
}

// async global->LDS, 16B per lane; LDS dest must be wave-uniform base (+lane*16 implicit)
__device__ __forceinline__ void load_lds16(const void* g, void* l) {
    __builtin_amdgcn_global_load_lds(
        (const __attribute__((address_space(1))) unsigned*)g,
        (__attribute__((address_space(3))) unsigned*)l, 16, 0, 0);
}

// Column permutation (16x4 transpose within each 64-col block):
//   gemm perm-col p  <->  logical col T(p) = (p&~63) + ((p&15)<<2) + ((p>>4)&3)
// Weights are built so gemm col p holds original col T(p); the packed epilogue then
// stores each lane's 4 nj-values (perm cols B+lh+16j) at contiguous logical cols
// B + lh*4 + j  ->  outputs land in ORIGINAL logical order (att/wt2 unchanged).

// ---------------- fused prep: cvt_x + 3 weight transposes + bias perms + zero ---------
#define PREP_X   3200000                    // N*256/4 float4 units
#define PREP_WQ  (768 * 256)
#define PREP_W1  (1024 * 256)
#define PREP_W2  (256 * 1024)
#define PREP_BQ  768
#define PREP_B1  1024
#define PREP_TOT (PREP_X + PREP_WQ + PREP_W1 + PREP_W2 + PREP_BQ + PREP_B1 + N_NODES)
__global__ void prep_kernel(const float* __restrict__ x, unsigned short* __restrict__ xb,
                            const float* __restrict__ wq, __hip_bfloat16* __restrict__ wtq,
                            const float* __restrict__ w1, __hip_bfloat16* __restrict__ wt1,
                            const float* __restrict__ w2, __hip_bfloat16* __restrict__ wt2,
                            const float* __restrict__ bq, float* __restrict__ bqp,
                            const float* __restrict__ b1, float* __restrict__ b1p,
                            unsigned* __restrict__ counts, unsigned* __restrict__ cursor) {
    int i = blockIdx.x * blockDim.x + threadIdx.x;
    if (i < PREP_X) {
        float4 v = reinterpret_cast<const float4*>(x)[i];
        ushort4 o;
        o.x = bfbits(v.x); o.y = bfbits(v.y); o.z = bfbits(v.z); o.w = bfbits(v.w);
        reinterpret_cast<ushort4*>(xb)[i] = o;
        return;
    }
    i -= PREP_X;
    if (i < PREP_WQ) {
        int n = i >> 8, k = i & 255;          // n = perm col in [0,768)
        int s = n >> 8, prel = n & 255;       // section 0=q,1=k,2=v
        int d = (prel & 192) + ((prel & 15) << 2) + ((prel >> 4) & 3);  // logical dim
        int co = (d >> 5) * 96 + s * 32 + (d & 31);                     // orig col
        wtq[i] = f2bf(wq[(size_t)k * 768 + co]);
        return;
    }
    i -= PREP_WQ;
    if (i < PREP_W1) {
        int n = i >> 8, k = i & 255;          // n = perm col in [0,1024)
        int f = (n & ~63) + ((n & 15) << 2) + ((n >> 4) & 3);
        wt1[i] = f2bf(w1[(size_t)k * 1024 + f]);
        return;
    }
    i -= PREP_W1;
    if (i < PREP_W2) {
        int n = i >> 10, k = i & 1023;        // unpermuted (hbuf is logical order)
        wt2[i] = f2bf(w2[(size_t)k * 256 + n]);
        return;
    }
    i -= PREP_W2;
    if (i < PREP_BQ) {
        int s = i >> 8, prel = i & 255;
        int d = (prel & 192) + ((prel & 15) << 2) + ((prel >> 4) & 3);
        bqp[i] = bq[(d >> 5) * 96 + s * 32 + (d & 31)];
        return;
    }
    i -= PREP_BQ;
    if (i < PREP_B1) {
        int f = (i & ~63) + ((i & 15) << 2) + ((i >> 4) & 3);
        b1p[i] = b1[f];
        return;
    }
    i -= PREP_B1;
    if (i < N_NODES) { counts[i] = 0u; cursor[i] = 0u; }
}

// ---------------- MFMA GEMM: out = A @ Wt^T + bias (perm cols, packed epilogue) ------
// A: MxK bf16 row-major. Wt: NxK bf16 row-major (perm-transposed weights).
// 128x128 tile, 256 threads = 4 waves (2x2 of 64x64), 16x16x32 bf16 MFMA, BK=32.
// XCD-aware bijective swizzle (m204) so same-A-row tiles share one XCD's L2.
// EPI==0 (qkv): perm col space [q:0-255][k:256-511][v:512-767]; tile is section-pure.
//   q: one ushort4 store per (mi,r) at qb[gm*256 + c*4]        (c = blk16 + lh)
//   k: 4 fp8 packed -> u32 store at kv8[gm*512 + c*8]
//   v: 4 fp8 packed -> u32 store at kv8[gm*512 + c*8 + 4]
// EPI==1: relu + one ushort4 store per (mi,r) at out[gm*Ncols + B + lh*4].
template<bool RELU, int EPI>
__global__ __launch_bounds__(256)
void mfma_gemm(const __hip_bfloat16* __restrict__ A,
               const __hip_bfloat16* __restrict__ Wt,
               const float* __restrict__ bias,
               __hip_bfloat16* __restrict__ outp,
               __hip_bfloat16* __restrict__ qb,
               unsigned char* __restrict__ kv8,
               int M, int Ncols, int K) {
    __shared__ short Al[128 * 32];
    __shared__ short Bl[128 * 32];
    const int t = threadIdx.x;
    const int wave = t >> 6, lane = t & 63;

    // bijective XCD swizzle: contiguous wg runs per XCD -> same-row tiles co-located
    unsigned flat = blockIdx.y * gridDim.x + blockIdx.x;
    unsigned nwg = gridDim.x * gridDim.y;
    unsigned q8 = nwg >> 3, r8 = nwg & 7;
    unsigned xcd = flat & 7, pos = flat >> 3;
    unsigned wg = (xcd < r8) ? (xcd * (q8 + 1) + pos)
                             : (r8 * (q8 + 1) + (xcd - r8) * q8 + pos);
    const int m0 = (int)(wg / gridDim.x) * 128;
    const int n0 = (int)(wg % gridDim.x) * 128;

    const int wr = wave >> 1, wc = wave & 1;

    const int srow = lane >> 2;                        // row within chunk 0..15
    const int skp  = (lane & 3) ^ ((lane >> 3) & 3);   // swizzled global k-part
    const int c0 = wave * 2;
    int ar0 = m0 + c0 * 16 + srow;      if (ar0 >= M) ar0 = M - 1;
    int ar1 = m0 + c0 * 16 + 16 + srow; if (ar1 >= M) ar1 = M - 1;
    const __hip_bfloat16* ga0 = A + (size_t)ar0 * K + skp * 8;
    const __hip_bfloat16* ga1 = A + (size_t)ar1 * K + skp * 8;
    const __hip_bfloat16* gb0 = Wt + (size_t)(n0 + c0 * 16 + srow) * K + skp * 8;
    const __hip_bfloat16* gb1 = Wt + (size_t)(n0 + c0 * 16 + 16 + srow) * K + skp * 8;
    short* la0 = &Al[c0 * 512];
    short* la1 = &Al[c0 * 512 + 512];
    short* lb0 = &Bl[c0 * 512];
    short* lb1 = &Bl[c0 * 512 + 512];

    const int lh = lane & 15, q = lane >> 4;
    const int qs = q ^ ((lane >> 1) & 3);
    const short* fa = &Al[(wr * 64 + lh) * 32 + qs * 8];
    const short* fb = &Bl[(wc * 64 + lh) * 32 + qs * 8];

    f32x4 acc[4][4] = {};

    for (int k0 = 0; k0 < K; k0 += 32) {
        load_lds16(ga0, la0);
        load_lds16(ga1, la1);
        load_lds16(gb0, lb0);
        load_lds16(gb1, lb1);
        ga0 += 32; ga1 += 32; gb0 += 32; gb1 += 32;
        __syncthreads();

        bf16x8 af[4], bfr[4];
#pragma unroll
        for (int i = 0; i < 4; i++) {
            af[i]  = *reinterpret_cast<const bf16x8*>(fa + i * 16 * 32);
            bfr[i] = *reinterpret_cast<const bf16x8*>(fb + i * 16 * 32);
        }
#pragma unroll
        for (int mi = 0; mi < 4; mi++)
#pragma unroll
            for (int nj = 0; nj < 4; nj++)
                acc[mi][nj] = __builtin_amdgcn_mfma_f32_16x16x32_bf16(
                    af[mi], bfr[nj], acc[mi][nj], 0, 0, 0);
        __syncthreads();
    }

    // epilogue: C/D layout col = lane&15, row = (lane>>4)*4 + reg
    const int B = n0 + wc * 64;
    const int gnbase = B + lh;
    float bv[4];
#pragma unroll
    for (int nj = 0; nj < 4; nj++) bv[nj] = bias[gnbase + nj * 16];

    if (EPI == 0) {
        const int sec = B >> 8;                       // 0=q,1=k,2=v (block-uniform)
        const int c = ((B & 255) >> 6) * 16 + lh;     // chunk index [0,64)
#pragma unroll
        for (int mi = 0; mi < 4; mi++) {
            int gmb = m0 + wr * 64 + mi * 16 + q * 4;
#pragma unroll
            for (int r = 0; r < 4; r++) {
                int gm = gmb + r;
                if (gm >= M) continue;
                float v0 = acc[mi][0][r] + bv[0];
                float v1 = acc[mi][1][r] + bv[1];
                float v2 = acc[mi][2][r] + bv[2];
                float v3 = acc[mi][3][r] + bv[3];
                if (sec == 0) {
                    ushort4 o;
                    o.x = bfbits(v0); o.y = bfbits(v1); o.z = bfbits(v2); o.w = bfbits(v3);
                    *reinterpret_cast<ushort4*>(qb + (size_t)gm * 256 + c * 4) = o;
                } else {
                    unsigned u = (unsigned)__builtin_amdgcn_cvt_pk_fp8_f32(v0, v1, 0, false);
                    u = (unsigned)__builtin_amdgcn_cvt_pk_fp8_f32(v2, v3, (int)u, true);
                    *reinterpret_cast<unsigned*>(
                        kv8 + (size_t)gm * 512 + c * 8 + (sec == 1 ? 0 : 4)) = u;
                }
            }
        }
    } else {
        const int cb = B + lh * 4;                    // logical col base (T-perm)
#pragma unroll
        for (int mi = 0; mi < 4; mi++) {
            int gmb = m0 + wr * 64 + mi * 16 + q * 4;
#pragma unroll
            for (int r = 0; r < 4; r++) {
                int gm = gmb + r;
                if (gm >= M) continue;
                float v0 = acc[mi][0][r] + bv[0];
                float v1 = acc[mi][1][r] + bv[1];
                float v2 = acc[mi][2][r] + bv[2];
                float v3 = acc[mi][3][r] + bv[3];
                if (RELU) {
                    v0 = fmaxf(v0, 0.f); v1 = fmaxf(v1, 0.f);
                    v2 = fmaxf(v2, 0.f); v3 = fmaxf(v3, 0.f);
                }
                ushort4 o;
                o.x = bfbits(v0); o.y = bfbits(v1); o.z = bfbits(v2); o.w = bfbits(v3);
                *reinterpret_cast<ushort4*>(outp + (size_t)gm * Ncols + cb) = o;
            }
        }
    }
}

// ---------------- ffn2 + fused LN2: out = LN(hbuf @ wt2^T + b2 + xn) ------------------
// 64 x 256 tile, 512 threads = 8 waves (2x4 of 32x64), K=1024, BK=32,
// 2-phase double-buffered LDS: STAGE(t+1) issued BEFORE compute(t), single
// __syncthreads per K-step -> load latency hides under ds_read+MFMA.
// LDS 2 x (64+256) x 32 x 2B = 40 KB -> 4 blocks/CU.
__global__ __launch_bounds__(512)
void ffn2_ln_kernel(const __hip_bfloat16* __restrict__ A,    // M x 1024
                    const __hip_bfloat16* __restrict__ Wt,   // 256 x 1024
                    const float* __restrict__ bias,
                    const __hip_bfloat16* __restrict__ resid,// M x 256
                    const float* __restrict__ g, const float* __restrict__ bb,
                    float* __restrict__ out, int M) {
    __shared__ short LDS[2][(64 + 256) * 32];   // A at [0,2048), B at [2048,10240)
    const int t = threadIdx.x;
    const int wave = t >> 6, lane = t & 63;
    const int m0 = blockIdx.x * 64;
    const int wr = wave >> 2, wc = wave & 3;

    const int srow = lane >> 2;                        // row within chunk 0..15
    const int skp  = (lane & 3) ^ ((lane >> 3) & 3);   // swizzled global k-part

    const __hip_bfloat16* gsrc0; int loff0;
    const __hip_bfloat16* gsrc1; int loff1;
    const __hip_bfloat16* gsrc2; int loff2;
    {
#define STAGE_INIT(GS, LO, C)                                            \
        if ((C) < 4) {                                                   \
            int r_ = m0 + (C) * 16 + srow; if (r_ >= M) r_ = M - 1;      \
            GS = A + (size_t)r_ * 1024 + skp * 8;                        \
            LO = (C) * 512;                                              \
        } else {                                                         \
            GS = Wt + (size_t)(((C) - 4) * 16 + srow) * 1024 + skp * 8;  \
            LO = 2048 + ((C) - 4) * 512;                                 \
        }
        STAGE_INIT(gsrc0, loff0, wave)
        STAGE_INIT(gsrc1, loff1, wave + 8)
        int c2 = (wave < 4) ? wave + 16 : 16;
        STAGE_INIT(gsrc2, loff2, c2)
#undef STAGE_INIT
    }

    const int lh = lane & 15, q = lane >> 4;
    const int qs = q ^ ((lane >> 1) & 3);
    const short* fa0 = &LDS[0][(wr * 32 + lh) * 32 + qs * 8];
    const short* fb0 = &LDS[0][2048 + (wc * 64 + lh) * 32 + qs * 8];
    const short* fa1 = &LDS[1][(wr * 32 + lh) * 32 + qs * 8];
    const short* fb1 = &LDS[1][2048 + (wc * 64 + lh) * 32 + qs * 8];

    f32x4 acc[2][4] = {};

#define FFN2_STAGE(BUF)                                      \
    load_lds16(gsrc0, &LDS[BUF][loff0]);                     \
    load_lds16(gsrc1, &LDS[BUF][loff1]);                     \
    if (wave < 4) load_lds16(gsrc2, &LDS[BUF][loff2]);       \
    gsrc0 += 32; gsrc1 += 32; gsrc2 += 32;

#define FFN2_STEP(FA, FB)                                                   \
    {                                                                       \
        bf16x8 af[2], bfr[4];                                               \
        _Pragma("unroll")                                                   \
        for (int i = 0; i < 2; i++)                                         \
            af[i] = *reinterpret_cast<const bf16x8*>((FA) + i * 16 * 32);   \
        _Pragma("unroll")                                                   \
        for (int i = 0; i < 4; i++)                                         \
            bfr[i] = *reinterpret_cast<const bf16x8*>((FB) + i * 16 * 32);  \
        _Pragma("unroll")                                                   \
        for (int mi = 0; mi < 2; mi++)                                      \
            _Pragma("unroll")                                               \
            for (int nj = 0; nj < 4; nj++)                                  \
                acc[mi][nj] = __builtin_amdgcn_mfma_f32_16x16x32_bf16(      \
                    af[mi], bfr[nj], acc[mi][nj], 0, 0, 0);                 \
    }

    // prologue: stage step 0 into buf0
    FFN2_STAGE(0)
    __syncthreads();

    for (int s = 0; s < 32; s += 2) {
        FFN2_STAGE(1)                      // loads for step s+1 (always valid, s+1<=31)
        FFN2_STEP(fa0, fb0)                // compute step s
        __syncthreads();
        if (s < 30) { FFN2_STAGE(0) }      // loads for step s+2
        FFN2_STEP(fa1, fb1)                // compute step s+1
        __syncthreads();
    }
#undef FFN2_STAGE
#undef FFN2_STEP

    // ---- epilogue: v = acc + b2 + xn; per-row LN over 256 cols; write f32 ----
    const int colbase = wc * 64 + lh;   // + nj*16
    float bv[4], gv[4], bbv[4];
#pragma unroll
    for (int nj = 0; nj < 4; nj++) {
        bv[nj]  = bias[colbase + nj * 16];
        gv[nj]  = g[colbase + nj * 16];
        bbv[nj] = bb[colbase + nj * 16];
    }

    float ps[2][4], pq[2][4];
#pragma unroll
    for (int mi = 0; mi < 2; mi++) {
#pragma unroll
        for (int r = 0; r < 4; r++) {
            int gm = m0 + wr * 32 + mi * 16 + q * 4 + r;
            int rgm = (gm < M) ? gm : M - 1;
            float s = 0.f, s2 = 0.f;
#pragma unroll
            for (int nj = 0; nj < 4; nj++) {
                float v = acc[mi][nj][r] + bv[nj]
                        + bf2f(resid[(size_t)rgm * 256 + colbase + nj * 16]);
                acc[mi][nj][r] = v;
                s += v; s2 += v * v;
            }
            ps[mi][r] = s; pq[mi][r] = s2;
        }
    }
#pragma unroll
    for (int off = 1; off <= 8; off <<= 1) {
#pragma unroll
        for (int mi = 0; mi < 2; mi++)
#pragma unroll
            for (int r = 0; r < 4; r++) {
                ps[mi][r] += __shfl_xor(ps[mi][r], off);
                pq[mi][r] += __shfl_xor(pq[mi][r], off);
            }
    }
    // cross-wave (wc) merge via LDS (reuse buf0: 64 rows x 4 wc x 2 vals = 2 KB)
    float* rs = (float*)(&LDS[0][0]);   // [64][4]
    float* rq = rs + 256;
    if (lh == 0) {
#pragma unroll
        for (int mi = 0; mi < 2; mi++)
#pragma unroll
            for (int r = 0; r < 4; r++) {
                int m = wr * 32 + mi * 16 + q * 4 + r;
                rs[m * 4 + wc] = ps[mi][r];
                rq[m * 4 + wc] = pq[mi][r];
            }
    }
    __syncthreads();

#pragma unroll
    for (int mi = 0; mi < 2; mi++) {
#pragma unroll
        for (int r = 0; r < 4; r++) {
            int m = wr * 32 + mi * 16 + q * 4 + r;
            int gm = m0 + m;
            if (gm >= M) continue;
            float4 rsv = *reinterpret_cast<const float4*>(&rs[m * 4]);
            float4 rqv = *reinterpret_cast<const float4*>(&rq[m * 4]);
            float S  = (rsv.x + rsv.y) + (rsv.z + rsv.w);
            float S2 = (rqv.x + rqv.y) + (rqv.z + rqv.w);
            float mean = S * (1.f / (float)D_MODEL);
            float var  = S2 * (1.f / (float)D_MODEL) - mean * mean;
            float inv  = rsqrtf(var + LN_EPS);
#pragma unroll
            for (int nj = 0; nj < 4; nj++)
                out[(size_t)gm * 256 + colbase + nj * 16] =
                    (acc[mi][nj][r] - mean) * inv * gv[nj] + bbv[nj];
        }
    }
}

// ---------------- CSR build ----------------
__global__ void count_kernel(const int* __restrict__ rows, unsigned* __restrict__ counts) {
    int e = blockIdx.x * blockDim.x + threadIdx.x;
    if (e < E_EDGES) atomicAdd(&counts[rows[e]], 1u);
}

__global__ void scan_blk_kernel(const unsigned* __restrict__ counts,
                                unsigned* __restrict__ offs, unsigned* __restrict__ bsum) {
    __shared__ unsigned sh[256];
    int t = threadIdx.x;
    int i = blockIdx.x * 256 + t;
    unsigned v = (i < N_NODES) ? counts[i] : 0u;
    sh[t] = v;
    __syncthreads();
#pragma unroll
    for (int off = 1; off < 256; off <<= 1) {
        unsigned u = (t >= off) ? sh[t - off] : 0u;
        __syncthreads();
        sh[t] += u;
        __syncthreads();
    }
    if (i < N_NODES) offs[i] = sh[t] - v;
    if (t == 255) bsum[blockIdx.x] = sh[255];
}

__global__ void scan_top_kernel(const unsigned* __restrict__ bsum, unsigned* __restrict__ bpre) {
    __shared__ unsigned sh[256];
    int t = threadIdx.x;
    unsigned v = (t < NB_SCAN) ? bsum[t] : 0u;
    sh[t] = v;
    __syncthreads();
#pragma unroll
    for (int off = 1; off < 256; off <<= 1) {
        unsigned u = (t >= off) ? sh[t - off] : 0u;
        __syncthreads();
        sh[t] += u;
        __syncthreads();
    }
    if (t < NB_SCAN) bpre[t] = sh[t] - v;
    if (t == NB_SCAN - 1) bpre[NB_SCAN] = sh[t];
}

__global__ void scan_add_kernel(unsigned* __restrict__ offs, const unsigned* __restrict__ bpre) {
    int i = blockIdx.x * 256 + threadIdx.x;
    if (i < N_NODES) offs[i] += bpre[blockIdx.x];
    if (i == 0) offs[N_NODES] = bpre[NB_SCAN];
}

__global__ void scatter_kernel(const int* __restrict__ rows, const int* __restrict__ cols,
                               const unsigned* __restrict__ offsets, unsigned* __restrict__ cursor,
                               int* __restrict__ scol) {
    int e = blockIdx.x * blockDim.x + threadIdx.x;
    if (e >= E_EDGES) return;
    int r = rows[e];
    unsigned idx = atomicAdd(&cursor[r], 1u);
    scol[offsets[r] + idx] = cols[e];
}

// ---------------- attention (wave-per-node, fp8 k/v) + fused LN1 ----------------
// Block = 4 nodes, one wave each. kv8 row (512 B) = 64 chunks: chunk c = 4 fp8 k-dims
// (4c..4c+3) then 4 fp8 v-dims. Lane c loads ONE 8B chunk per edge. 8 lanes/head.
// Single-pass exp (|s|<=8 here; softmax shift-invariant => identical to reference).
__global__ __launch_bounds__(256)
void att_agg_kernel(const __hip_bfloat16* __restrict__ qb,
                    const unsigned char* __restrict__ kv8,
                    const unsigned* __restrict__ offsets,
                    const int* __restrict__ scol,
                    const float* __restrict__ x,
                    const float* __restrict__ g, const float* __restrict__ bb,
                    __hip_bfloat16* __restrict__ xn) {
    int n = blockIdx.x * 4 + (threadIdx.x >> 6);
    if (n >= N_NODES) return;
    int lam = threadIdx.x & 63;
    unsigned beg = offsets[n], end = offsets[n + 1];

    float4 qf = load_bf16x4(qb + (size_t)n * 256 + lam * 4);
    qf.x *= ATT_SCALE; qf.y *= ATT_SCALE; qf.z *= ATT_SCALE; qf.w *= ATT_SCALE;

    float4 acc = {0.f, 0.f, 0.f, 0.f};
    float l = 0.f;

#define EDGE_BODY(KV, SV, PV)                                                 \
    unsigned klo = (unsigned)(KV), vhi = (unsigned)((KV) >> 32);              \
    auto k01 = __builtin_amdgcn_cvt_pk_f32_fp8((int)klo, false);              \
    auto k23 = __builtin_amdgcn_cvt_pk_f32_fp8((int)klo, true);               \
    float SV = qf.x * k01[0] + qf.y * k01[1] + qf.z * k23[0] + qf.w * k23[1]; \
    SV += __shfl_xor(SV, 1);                                                  \
    SV += __shfl_xor(SV, 2);                                                  \
    SV += __shfl_xor(SV, 4);                                                  \
    float PV = __expf(SV);                                                    \
    auto v01 = __builtin_amdgcn_cvt_pk_f32_fp8((int)vhi, false);              \
    auto v23 = __builtin_amdgcn_cvt_pk_f32_fp8((int)vhi, true);               \
    l += PV;                                                                  \
    acc.x += PV * v01[0]; acc.y += PV * v01[1];                               \
    acc.z += PV * v23[0]; acc.w += PV * v23[1];

    unsigned e = beg;
    for (; e + 4 <= end; e += 4) {
        int c0 = scol[e], c1 = scol[e + 1], c2 = scol[e + 2], c3 = scol[e + 3];
        unsigned long long kv0 = *(const unsigned long long*)(kv8 + (size_t)c0 * 512 + lam * 8);
        unsigned long long kv1 = *(const unsigned long long*)(kv8 + (size_t)c1 * 512 + lam * 8);
        unsigned long long kv2 = *(const unsigned long long*)(kv8 + (size_t)c2 * 512 + lam * 8);
        unsigned long long kv3 = *(const unsigned long long*)(kv8 + (size_t)c3 * 512 + lam * 8);
        { EDGE_BODY(kv0, s0, p0) }
        { EDGE_BODY(kv1, s1, p1) }
        { EDGE_BODY(kv2, s2, p2) }
        { EDGE_BODY(kv3, s3, p3) }
    }
    for (; e < end; e++) {
        int c0 = scol[e];
        unsigned long long kv0 = *(const unsigned long long*)(kv8 + (size_t)c0 * 512 + lam * 8);
        { EDGE_BODY(kv0, s0, p0) }
    }
#undef EDGE_BODY

    float inv_l = (l > 0.f) ? 1.f / l : 0.f;
    float4 xr = reinterpret_cast<const float4*>(x + (size_t)n * D_MODEL)[lam];
    float4 tv;
    tv.x = acc.x * inv_l + xr.x;
    tv.y = acc.y * inv_l + xr.y;
    tv.z = acc.z * inv_l + xr.z;
    tv.w = acc.w * inv_l + xr.w;

    float s  = tv.x + tv.y + tv.z + tv.w;
    float s2 = tv.x * tv.x + tv.y * tv.y + tv.z * tv.z + tv.w * tv.w;
#pragma unroll
    for (int off = 1; off <= 32; off <<= 1) {
        s  += __shfl_xor(s, off);
        s2 += __shfl_xor(s2, off);
    }
    float mean = s * (1.f / (float)D_MODEL);
    float var  = s2 * (1.f / (float)D_MODEL) - mean * mean;
    float inv  = rsqrtf(var + LN_EPS);

    float4 gr = reinterpret_cast<const float4*>(g  + lam * 4)[0];
    float4 br = reinterpret_cast<const float4*>(bb + lam * 4)[0];
    ushort4 o;
    o.x = bfbits((tv.x - mean) * inv * gr.x + br.x);
    o.y = bfbits((tv.y - mean) * inv * gr.y + br.y);
    o.z = bfbits((tv.z - mean) * inv * gr.z + br.z);
    o.w = bfbits((tv.w - mean) * inv * gr.w + br.w);
    reinterpret_cast<ushort4*>(xn + (size_t)n * D_MODEL)[lam] = o;
}

extern "C" void kernel_launch(void* const* d_in, const int* in_sizes, int n_in,
                              void* d_out, int out_size, void* d_ws, size_t ws_size,
                              hipStream_t stream) {
    const float* x     = (const float*)d_in[0];
    const int*   ei    = (const int*)d_in[1];
    const float* w_qkv = (const float*)d_in[2];
    const float* b_qkv = (const float*)d_in[3];
    const float* ln1_g = (const float*)d_in[4];
    const float* ln1_b = (const float*)d_in[5];
    const float* ln2_g = (const float*)d_in[6];
    const float* ln2_b = (const float*)d_in[7];
    const float* w1    = (const float*)d_in[8];
    const float* b1    = (const float*)d_in[9];
    const float* w2    = (const float*)d_in[10];
    const float* b2    = (const float*)d_in[11];
    const int* rows = ei;
    const int* cols = ei + E_EDGES;

    // workspace layout (bytes), total < 179,200,000 (known-good footprint):
    //   [0,          25,600,000)  qb  bf16 N*256 } dead after att_agg;
    //   [25,600,000, 51,200,000)  kv8 fp8  N*512 } region [0,102.4e6) reused
    //                                            } as hbuf bf16 N*1024
    //   [102,400,000,128,000,000) xb bf16 N*256 (dead after qkv gemm)
    //   [128,000,000,128,393,216) wtq bf16 768x256 (perm cols)
    //   [128,400,000,128,924,288) wt1 bf16 1024x256 (perm cols)
    //   [129,000,000,129,524,288) wt2 bf16 256x1024
    //   [129,600,000,129,800,000) counts u32 N
    //   [129,800,000,130,000,004) offsets u32 N+1
    //   [130,000,008,130,200,008) cursor u32 N
    //   [130,200,008,133,400,008) scol i32 E
    //   [133,400,008,133,401,032) bsum u32 256
    //   [133,401,032,133,402,060) bpre u32 257
    //   [133,500,000,133,503,072) bqp f32 768 (perm qkv bias)
    //   [133,510,000,133,514,096) b1p f32 1024 (perm ffn1 bias)
    //   [153,600,000,179,200,000) xn bf16 N*256
    char* ws = (char*)d_ws;
    __hip_bfloat16* qb      = (__hip_bfloat16*)(ws + 0);
    unsigned char*  kv8     = (unsigned char*)(ws + 25600000);
    __hip_bfloat16* hbuf    = (__hip_bfloat16*)(ws + 0);
    __hip_bfloat16* xb      = (__hip_bfloat16*)(ws + 102400000);
    __hip_bfloat16* wtq     = (__hip_bfloat16*)(ws + 128000000);
    __hip_bfloat16* wt1     = (__hip_bfloat16*)(ws + 128400000);
    __hip_bfloat16* wt2     = (__hip_bfloat16*)(ws + 129000000);
    unsigned*       counts  = (unsigned*)(ws + 129600000);
    unsigned*       offsets = (unsigned*)(ws + 129800000);
    unsigned*       cursor  = (unsigned*)(ws + 130000008);
    int*            scol    = (int*)(ws + 130200008);
    unsigned*       bsum    = (unsigned*)(ws + 133400008);
    unsigned*       bpre    = (unsigned*)(ws + 133401032);
    float*          bqp     = (float*)(ws + 133500000);
    float*          b1p     = (float*)(ws + 133510000);
    __hip_bfloat16* xn      = (__hip_bfloat16*)(ws + 153600000);

    const int nbM = (N_NODES + 127) / 128;   // 391

    // fused prep: x->bf16, perm weights/biases, zero counts/cursor
    prep_kernel<<<(PREP_TOT + 255) / 256, 256, 0, stream>>>(
        x, (unsigned short*)xb, w_qkv, wtq, w1, wt1, w2, wt2,
        b_qkv, bqp, b1, b1p, counts, cursor);

    // q(bf16)/kv(fp8) = split(xb @ wtq^T + bqp), packed epilogue
    mfma_gemm<false, 0><<<dim3(768 / 128, nbM), 256, 0, stream>>>(
        xb, wtq, bqp, nullptr, qb, kv8, N_NODES, 768, D_MODEL);

    // CSR build (hierarchical scan)
    count_kernel<<<(E_EDGES + 255) / 256, 256, 0, stream>>>(rows, counts);
    scan_blk_kernel<<<NB_SCAN, 256, 0, stream>>>(counts, offsets, bsum);
    scan_top_kernel<<<1, 256, 0, stream>>>(bsum, bpre);
    scan_add_kernel<<<NB_SCAN, 256, 0, stream>>>(offsets, bpre);
    scatter_kernel<<<(E_EDGES + 255) / 256, 256, 0, stream>>>(rows, cols, offsets, cursor, scol);

    // attention (wave-per-node, fp8 kv, 4-edge unroll) + fused LN1 -> xn
    att_agg_kernel<<<(N_NODES + 3) / 4, 256, 0, stream>>>(qb, kv8, offsets, scol,
                                                          x, ln1_g, ln1_b, xn);

    // hbuf = relu(xn @ wt1^T + b1p), packed epilogue (hbuf in logical col order)
    mfma_gemm<true, 1><<<dim3(F_FFN / 128, nbM), 256, 0, stream>>>(
        xn, wt1, b1p, hbuf, nullptr, nullptr, N_NODES, F_FFN, D_MODEL);

    // d_out = LN2(hbuf @ wt2^T + b2 + xn)   (fused, f32 out; dbuf pipeline)
    ffn2_ln_kernel<<<(N_NODES + 63) / 64, 512, 0, stream>>>(hbuf, wt2, b2, xn, ln2_g, ln2_b,
                                                            (float*)d_out, N_NODES);
}

// Round 3
// 415.557 us; speedup vs baseline: 1.1401x; 1.0263x over previous
//
#include <hip/hip_runtime.h>
#include <hip/hip_bf16.h>

#define N_NODES 50000
#define E_EDGES 800000
#define D_MODEL 256
#define H_HEADS 8
#define HDIM    32
#define F_FFN   1024
#define ATT_SCALE 0.0625f   // 256^-0.5
#define LN_EPS  1e-5f
#define NB_SCAN 196         // ceil(N_NODES/256)

typedef __attribute__((ext_vector_type(8))) short bf16x8;
typedef __attribute__((ext_vector_type(8))) unsigned short u16x8;
typedef __attribute__((ext_vector_type(4))) float f32x4;

__device__ __forceinline__ float bf2f(__hip_bfloat16 v) { return __bfloat162float(v); }
__device__ __forceinline__ __hip_bfloat16 f2bf(float v) { return __float2bfloat16(v); }
__device__ __forceinline__ unsigned short bfbits(float f) {
    __hip_bfloat16 h = __float2bfloat16(f);
    return *reinterpret_cast<unsigned short*>(&h);
}

// unpack 8 consecutive bf16 (16B aligned) -> 8 floats
__device__ __forceinline__ void unpack_bf8(uint4 u, float* f) {
    f[0] = __uint_as_float(u.x << 16); f[1] = __uint_as_float(u.x & 0xFFFF0000u);
    f[2] = __uint_as_float(u.y << 16); f[3] = __uint_as_float(u.y & 0xFFFF0000u);
    f[4] = __uint_as_float(u.z << 16); f[5] = __uint_as_float(u.z & 0xFFFF0000u);
    f[6] = __uint_as_float(u.w << 16); f[7] = __uint_as_float(u.w & 0xFFFF0000u);
}

// async global->LDS, 16B per lane; LDS dest must be wave-uniform base (+lane*16 implicit)
__device__ __forceinline__ void load_lds16(const void* g, void* l) {
    __builtin_amdgcn_global_load_lds(
        (const __attribute__((address_space(1))) unsigned*)g,
        (__attribute__((address_space(3))) unsigned*)l, 16, 0, 0);
}

// Column permutation (16x4 transpose within each 64-col block):
//   gemm perm-col p  <->  logical col T(p) = (p&~63) + ((p&15)<<2) + ((p>>4)&3)
// Weights are built so gemm col p holds original col T(p); the packed epilogue then
// stores each lane's 4 nj-values (perm cols B+lh+16j) at contiguous logical cols
// B + lh*4 + j  ->  outputs land in ORIGINAL logical order (att/wt2 unchanged).

// ---------------- fused prep: cvt_x + 3 weight transposes + bias perms + zero ---------
#define PREP_X   3200000                    // N*256/4 float4 units
#define PREP_WQ  (768 * 256)
#define PREP_W1  (1024 * 256)
#define PREP_W2  (256 * 1024)
#define PREP_BQ  768
#define PREP_B1  1024
#define PREP_TOT (PREP_X + PREP_WQ + PREP_W1 + PREP_W2 + PREP_BQ + PREP_B1 + N_NODES)
__global__ void prep_kernel(const float* __restrict__ x, unsigned short* __restrict__ xb,
                            const float* __restrict__ wq, __hip_bfloat16* __restrict__ wtq,
                            const float* __restrict__ w1, __hip_bfloat16* __restrict__ wt1,
                            const float* __restrict__ w2, __hip_bfloat16* __restrict__ wt2,
                            const float* __restrict__ bq, float* __restrict__ bqp,
                            const float* __restrict__ b1, float* __restrict__ b1p,
                            unsigned* __restrict__ counts, unsigned* __restrict__ cursor) {
    int i = blockIdx.x * blockDim.x + threadIdx.x;
    if (i < PREP_X) {
        float4 v = reinterpret_cast<const float4*>(x)[i];
        ushort4 o;
        o.x = bfbits(v.x); o.y = bfbits(v.y); o.z = bfbits(v.z); o.w = bfbits(v.w);
        reinterpret_cast<ushort4*>(xb)[i] = o;
        return;
    }
    i -= PREP_X;
    if (i < PREP_WQ) {
        int n = i >> 8, k = i & 255;          // n = perm col in [0,768)
        int s = n >> 8, prel = n & 255;       // section 0=q,1=k,2=v
        int d = (prel & 192) + ((prel & 15) << 2) + ((prel >> 4) & 3);  // logical dim
        int co = (d >> 5) * 96 + s * 32 + (d & 31);                     // orig col
        wtq[i] = f2bf(wq[(size_t)k * 768 + co]);
        return;
    }
    i -= PREP_WQ;
    if (i < PREP_W1) {
        int n = i >> 8, k = i & 255;          // n = perm col in [0,1024)
        int f = (n & ~63) + ((n & 15) << 2) + ((n >> 4) & 3);
        wt1[i] = f2bf(w1[(size_t)k * 1024 + f]);
        return;
    }
    i -= PREP_W1;
    if (i < PREP_W2) {
        int n = i >> 10, k = i & 1023;        // unpermuted (hbuf is logical order)
        wt2[i] = f2bf(w2[(size_t)k * 256 + n]);
        return;
    }
    i -= PREP_W2;
    if (i < PREP_BQ) {
        int s = i >> 8, prel = i & 255;
        int d = (prel & 192) + ((prel & 15) << 2) + ((prel >> 4) & 3);
        bqp[i] = bq[(d >> 5) * 96 + s * 32 + (d & 31)];
        return;
    }
    i -= PREP_BQ;
    if (i < PREP_B1) {
        int f = (i & ~63) + ((i & 15) << 2) + ((i >> 4) & 3);
        b1p[i] = b1[f];
        return;
    }
    i -= PREP_B1;
    if (i < N_NODES) { counts[i] = 0u; cursor[i] = 0u; }
}

// ---------------- MFMA GEMM: out = A @ Wt^T + bias (perm cols, packed epilogue) ------
// A: MxK bf16 row-major. Wt: NxK bf16 row-major (perm-transposed weights).
// 128x128 tile, 256 threads = 4 waves (2x2 of 64x64), 16x16x32 bf16 MFMA, BK=32.
// 2-phase LDS double-buffer: STAGE(s+1) issued BEFORE compute(s), one barrier/step.
// XCD-aware bijective swizzle (m204) so same-A-row tiles share one XCD's L2.
// EPI==0 (qkv): perm col space [q:0-255][k:256-511][v:512-767]; tile is section-pure.
// EPI==1: relu + one ushort4 store per (mi,r) at out[gm*Ncols + B + lh*4].
template<bool RELU, int EPI>
__global__ __launch_bounds__(256)
void mfma_gemm(const __hip_bfloat16* __restrict__ A,
               const __hip_bfloat16* __restrict__ Wt,
               const float* __restrict__ bias,
               __hip_bfloat16* __restrict__ outp,
               __hip_bfloat16* __restrict__ qb,
               unsigned char* __restrict__ kv8,
               int M, int Ncols, int K) {
    __shared__ short Al[2][128 * 32];
    __shared__ short Bl[2][128 * 32];
    const int t = threadIdx.x;
    const int wave = t >> 6, lane = t & 63;

    // bijective XCD swizzle: contiguous wg runs per XCD -> same-row tiles co-located
    unsigned flat = blockIdx.y * gridDim.x + blockIdx.x;
    unsigned nwg = gridDim.x * gridDim.y;
    unsigned q8 = nwg >> 3, r8 = nwg & 7;
    unsigned xcd = flat & 7, pos = flat >> 3;
    unsigned wg = (xcd < r8) ? (xcd * (q8 + 1) + pos)
                             : (r8 * (q8 + 1) + (xcd - r8) * q8 + pos);
    const int m0 = (int)(wg / gridDim.x) * 128;
    const int n0 = (int)(wg % gridDim.x) * 128;

    const int wr = wave >> 1, wc = wave & 1;

    const int srow = lane >> 2;                        // row within chunk 0..15
    const int skp  = (lane & 3) ^ ((lane >> 3) & 3);   // swizzled global k-part
    const int c0 = wave * 2;
    int ar0 = m0 + c0 * 16 + srow;      if (ar0 >= M) ar0 = M - 1;
    int ar1 = m0 + c0 * 16 + 16 + srow; if (ar1 >= M) ar1 = M - 1;
    const __hip_bfloat16* ga0 = A + (size_t)ar0 * K + skp * 8;
    const __hip_bfloat16* ga1 = A + (size_t)ar1 * K + skp * 8;
    const __hip_bfloat16* gb0 = Wt + (size_t)(n0 + c0 * 16 + srow) * K + skp * 8;
    const __hip_bfloat16* gb1 = Wt + (size_t)(n0 + c0 * 16 + 16 + srow) * K + skp * 8;

    const int lh = lane & 15, q = lane >> 4;
    const int qs = q ^ ((lane >> 1) & 3);
    const short* fa0 = &Al[0][(wr * 64 + lh) * 32 + qs * 8];
    const short* fb0 = &Bl[0][(wc * 64 + lh) * 32 + qs * 8];
    const short* fa1 = &Al[1][(wr * 64 + lh) * 32 + qs * 8];
    const short* fb1 = &Bl[1][(wc * 64 + lh) * 32 + qs * 8];

    f32x4 acc[4][4] = {};

#define GSTAGE(B)                                    \
    load_lds16(ga0, &Al[B][c0 * 512]);               \
    load_lds16(ga1, &Al[B][c0 * 512 + 512]);         \
    load_lds16(gb0, &Bl[B][c0 * 512]);               \
    load_lds16(gb1, &Bl[B][c0 * 512 + 512]);         \
    ga0 += 32; ga1 += 32; gb0 += 32; gb1 += 32;

#define GSTEP(FA, FB)                                                       \
    {                                                                       \
        bf16x8 af[4], bfr[4];                                               \
        _Pragma("unroll")                                                   \
        for (int i = 0; i < 4; i++) {                                       \
            af[i]  = *reinterpret_cast<const bf16x8*>((FA) + i * 16 * 32);  \
            bfr[i] = *reinterpret_cast<const bf16x8*>((FB) + i * 16 * 32);  \
        }                                                                   \
        _Pragma("unroll")                                                   \
        for (int mi = 0; mi < 4; mi++)                                      \
            _Pragma("unroll")                                               \
            for (int nj = 0; nj < 4; nj++)                                  \
                acc[mi][nj] = __builtin_amdgcn_mfma_f32_16x16x32_bf16(      \
                    af[mi], bfr[nj], acc[mi][nj], 0, 0, 0);                 \
    }

    const int nsteps = K >> 5;          // 8 for K=256 (even)
    GSTAGE(0)
    __syncthreads();
    for (int s = 0; s < nsteps; s += 2) {
        if (s + 1 < nsteps) { GSTAGE(1) }
        GSTEP(fa0, fb0)
        __syncthreads();
        if (s + 2 < nsteps) { GSTAGE(0) }
        GSTEP(fa1, fb1)
        __syncthreads();
    }
#undef GSTAGE
#undef GSTEP

    // epilogue: C/D layout col = lane&15, row = (lane>>4)*4 + reg
    const int B = n0 + wc * 64;
    const int gnbase = B + lh;
    float bv[4];
#pragma unroll
    for (int nj = 0; nj < 4; nj++) bv[nj] = bias[gnbase + nj * 16];

    if (EPI == 0) {
        const int sec = B >> 8;                       // 0=q,1=k,2=v (block-uniform)
        const int c = ((B & 255) >> 6) * 16 + lh;     // chunk index [0,64)
#pragma unroll
        for (int mi = 0; mi < 4; mi++) {
            int gmb = m0 + wr * 64 + mi * 16 + q * 4;
#pragma unroll
            for (int r = 0; r < 4; r++) {
                int gm = gmb + r;
                if (gm >= M) continue;
                float v0 = acc[mi][0][r] + bv[0];
                float v1 = acc[mi][1][r] + bv[1];
                float v2 = acc[mi][2][r] + bv[2];
                float v3 = acc[mi][3][r] + bv[3];
                if (sec == 0) {
                    ushort4 o;
                    o.x = bfbits(v0); o.y = bfbits(v1); o.z = bfbits(v2); o.w = bfbits(v3);
                    *reinterpret_cast<ushort4*>(qb + (size_t)gm * 256 + c * 4) = o;
                } else {
                    unsigned u = (unsigned)__builtin_amdgcn_cvt_pk_fp8_f32(v0, v1, 0, false);
                    u = (unsigned)__builtin_amdgcn_cvt_pk_fp8_f32(v2, v3, (int)u, true);
                    *reinterpret_cast<unsigned*>(
                        kv8 + (size_t)gm * 512 + c * 8 + (sec == 1 ? 0 : 4)) = u;
                }
            }
        }
    } else {
        const int cb = B + lh * 4;                    // logical col base (T-perm)
#pragma unroll
        for (int mi = 0; mi < 4; mi++) {
            int gmb = m0 + wr * 64 + mi * 16 + q * 4;
#pragma unroll
            for (int r = 0; r < 4; r++) {
                int gm = gmb + r;
                if (gm >= M) continue;
                float v0 = acc[mi][0][r] + bv[0];
                float v1 = acc[mi][1][r] + bv[1];
                float v2 = acc[mi][2][r] + bv[2];
                float v3 = acc[mi][3][r] + bv[3];
                if (RELU) {
                    v0 = fmaxf(v0, 0.f); v1 = fmaxf(v1, 0.f);
                    v2 = fmaxf(v2, 0.f); v3 = fmaxf(v3, 0.f);
                }
                ushort4 o;
                o.x = bfbits(v0); o.y = bfbits(v1); o.z = bfbits(v2); o.w = bfbits(v3);
                *reinterpret_cast<ushort4*>(outp + (size_t)gm * Ncols + cb) = o;
            }
        }
    }
}

// ---------------- ffn2 + fused LN2: out = LN(hbuf @ wt2^T + b2 + xn) ------------------
// 64 x 256 tile, 512 threads = 8 waves (2x4 of 32x64), K=1024, BK=32,
// 2-phase double-buffered LDS, single __syncthreads per K-step.
__global__ __launch_bounds__(512)
void ffn2_ln_kernel(const __hip_bfloat16* __restrict__ A,    // M x 1024
                    const __hip_bfloat16* __restrict__ Wt,   // 256 x 1024
                    const float* __restrict__ bias,
                    const __hip_bfloat16* __restrict__ resid,// M x 256
                    const float* __restrict__ g, const float* __restrict__ bb,
                    float* __restrict__ out, int M) {
    __shared__ short LDS[2][(64 + 256) * 32];   // A at [0,2048), B at [2048,10240)
    const int t = threadIdx.x;
    const int wave = t >> 6, lane = t & 63;
    const int m0 = blockIdx.x * 64;
    const int wr = wave >> 2, wc = wave & 3;

    const int srow = lane >> 2;                        // row within chunk 0..15
    const int skp  = (lane & 3) ^ ((lane >> 3) & 3);   // swizzled global k-part

    const __hip_bfloat16* gsrc0; int loff0;
    const __hip_bfloat16* gsrc1; int loff1;
    const __hip_bfloat16* gsrc2; int loff2;
    {
#define STAGE_INIT(GS, LO, C)                                            \
        if ((C) < 4) {                                                   \
            int r_ = m0 + (C) * 16 + srow; if (r_ >= M) r_ = M - 1;      \
            GS = A + (size_t)r_ * 1024 + skp * 8;                        \
            LO = (C) * 512;                                              \
        } else {                                                         \
            GS = Wt + (size_t)(((C) - 4) * 16 + srow) * 1024 + skp * 8;  \
            LO = 2048 + ((C) - 4) * 512;                                 \
        }
        STAGE_INIT(gsrc0, loff0, wave)
        STAGE_INIT(gsrc1, loff1, wave + 8)
        int c2 = (wave < 4) ? wave + 16 : 16;
        STAGE_INIT(gsrc2, loff2, c2)
#undef STAGE_INIT
    }

    const int lh = lane & 15, q = lane >> 4;
    const int qs = q ^ ((lane >> 1) & 3);
    const short* fa0 = &LDS[0][(wr * 32 + lh) * 32 + qs * 8];
    const short* fb0 = &LDS[0][2048 + (wc * 64 + lh) * 32 + qs * 8];
    const short* fa1 = &LDS[1][(wr * 32 + lh) * 32 + qs * 8];
    const short* fb1 = &LDS[1][2048 + (wc * 64 + lh) * 32 + qs * 8];

    f32x4 acc[2][4] = {};

#define FFN2_STAGE(BUF)                                      \
    load_lds16(gsrc0, &LDS[BUF][loff0]);                     \
    load_lds16(gsrc1, &LDS[BUF][loff1]);                     \
    if (wave < 4) load_lds16(gsrc2, &LDS[BUF][loff2]);       \
    gsrc0 += 32; gsrc1 += 32; gsrc2 += 32;

#define FFN2_STEP(FA, FB)                                                   \
    {                                                                       \
        bf16x8 af[2], bfr[4];                                               \
        _Pragma("unroll")                                                   \
        for (int i = 0; i < 2; i++)                                         \
            af[i] = *reinterpret_cast<const bf16x8*>((FA) + i * 16 * 32);   \
        _Pragma("unroll")                                                   \
        for (int i = 0; i < 4; i++)                                         \
            bfr[i] = *reinterpret_cast<const bf16x8*>((FB) + i * 16 * 32);  \
        _Pragma("unroll")                                                   \
        for (int mi = 0; mi < 2; mi++)                                      \
            _Pragma("unroll")                                               \
            for (int nj = 0; nj < 4; nj++)                                  \
                acc[mi][nj] = __builtin_amdgcn_mfma_f32_16x16x32_bf16(      \
                    af[mi], bfr[nj], acc[mi][nj], 0, 0, 0);                 \
    }

    // prologue: stage step 0 into buf0
    FFN2_STAGE(0)
    __syncthreads();

    for (int s = 0; s < 32; s += 2) {
        FFN2_STAGE(1)                      // loads for step s+1 (always valid, s+1<=31)
        FFN2_STEP(fa0, fb0)                // compute step s
        __syncthreads();
        if (s < 30) { FFN2_STAGE(0) }      // loads for step s+2
        FFN2_STEP(fa1, fb1)                // compute step s+1
        __syncthreads();
    }
#undef FFN2_STAGE
#undef FFN2_STEP

    // ---- epilogue: v = acc + b2 + xn; per-row LN over 256 cols; write f32 ----
    const int colbase = wc * 64 + lh;   // + nj*16
    float bv[4], gv[4], bbv[4];
#pragma unroll
    for (int nj = 0; nj < 4; nj++) {
        bv[nj]  = bias[colbase + nj * 16];
        gv[nj]  = g[colbase + nj * 16];
        bbv[nj] = bb[colbase + nj * 16];
    }

    float ps[2][4], pq[2][4];
#pragma unroll
    for (int mi = 0; mi < 2; mi++) {
#pragma unroll
        for (int r = 0; r < 4; r++) {
            int gm = m0 + wr * 32 + mi * 16 + q * 4 + r;
            int rgm = (gm < M) ? gm : M - 1;
            float s = 0.f, s2 = 0.f;
#pragma unroll
            for (int nj = 0; nj < 4; nj++) {
                float v = acc[mi][nj][r] + bv[nj]
                        + bf2f(resid[(size_t)rgm * 256 + colbase + nj * 16]);
                acc[mi][nj][r] = v;
                s += v; s2 += v * v;
            }
            ps[mi][r] = s; pq[mi][r] = s2;
        }
    }
#pragma unroll
    for (int off = 1; off <= 8; off <<= 1) {
#pragma unroll
        for (int mi = 0; mi < 2; mi++)
#pragma unroll
            for (int r = 0; r < 4; r++) {
                ps[mi][r] += __shfl_xor(ps[mi][r], off);
                pq[mi][r] += __shfl_xor(pq[mi][r], off);
            }
    }
    // cross-wave (wc) merge via LDS (reuse buf0: 64 rows x 4 wc x 2 vals = 2 KB)
    float* rs = (float*)(&LDS[0][0]);   // [64][4]
    float* rq = rs + 256;
    if (lh == 0) {
#pragma unroll
        for (int mi = 0; mi < 2; mi++)
#pragma unroll
            for (int r = 0; r < 4; r++) {
                int m = wr * 32 + mi * 16 + q * 4 + r;
                rs[m * 4 + wc] = ps[mi][r];
                rq[m * 4 + wc] = pq[mi][r];
            }
    }
    __syncthreads();

#pragma unroll
    for (int mi = 0; mi < 2; mi++) {
#pragma unroll
        for (int r = 0; r < 4; r++) {
            int m = wr * 32 + mi * 16 + q * 4 + r;
            int gm = m0 + m;
            if (gm >= M) continue;
            float4 rsv = *reinterpret_cast<const float4*>(&rs[m * 4]);
            float4 rqv = *reinterpret_cast<const float4*>(&rq[m * 4]);
            float S  = (rsv.x + rsv.y) + (rsv.z + rsv.w);
            float S2 = (rqv.x + rqv.y) + (rqv.z + rqv.w);
            float mean = S * (1.f / (float)D_MODEL);
            float var  = S2 * (1.f / (float)D_MODEL) - mean * mean;
            float inv  = rsqrtf(var + LN_EPS);
#pragma unroll
            for (int nj = 0; nj < 4; nj++)
                out[(size_t)gm * 256 + colbase + nj * 16] =
                    (acc[mi][nj][r] - mean) * inv * gv[nj] + bbv[nj];
        }
    }
}

// ---------------- CSR build ----------------
__global__ void count_kernel(const int* __restrict__ rows, unsigned* __restrict__ counts) {
    int e = blockIdx.x * blockDim.x + threadIdx.x;
    if (e < E_EDGES) atomicAdd(&counts[rows[e]], 1u);
}

__global__ void scan_blk_kernel(const unsigned* __restrict__ counts,
                                unsigned* __restrict__ offs, unsigned* __restrict__ bsum) {
    __shared__ unsigned sh[256];
    int t = threadIdx.x;
    int i = blockIdx.x * 256 + t;
    unsigned v = (i < N_NODES) ? counts[i] : 0u;
    sh[t] = v;
    __syncthreads();
#pragma unroll
    for (int off = 1; off < 256; off <<= 1) {
        unsigned u = (t >= off) ? sh[t - off] : 0u;
        __syncthreads();
        sh[t] += u;
        __syncthreads();
    }
    if (i < N_NODES) offs[i] = sh[t] - v;
    if (t == 255) bsum[blockIdx.x] = sh[255];
}

__global__ void scan_top_kernel(const unsigned* __restrict__ bsum, unsigned* __restrict__ bpre) {
    __shared__ unsigned sh[256];
    int t = threadIdx.x;
    unsigned v = (t < NB_SCAN) ? bsum[t] : 0u;
    sh[t] = v;
    __syncthreads();
#pragma unroll
    for (int off = 1; off < 256; off <<= 1) {
        unsigned u = (t >= off) ? sh[t - off] : 0u;
        __syncthreads();
        sh[t] += u;
        __syncthreads();
    }
    if (t < NB_SCAN) bpre[t] = sh[t] - v;
    if (t == NB_SCAN - 1) bpre[NB_SCAN] = sh[t];
}

__global__ void scan_add_kernel(unsigned* __restrict__ offs, const unsigned* __restrict__ bpre) {
    int i = blockIdx.x * 256 + threadIdx.x;
    if (i < N_NODES) offs[i] += bpre[blockIdx.x];
    if (i == 0) offs[N_NODES] = bpre[NB_SCAN];
}

__global__ void scatter_kernel(const int* __restrict__ rows, const int* __restrict__ cols,
                               const unsigned* __restrict__ offsets, unsigned* __restrict__ cursor,
                               int* __restrict__ scol) {
    int e = blockIdx.x * blockDim.x + threadIdx.x;
    if (e >= E_EDGES) return;
    int r = rows[e];
    unsigned idx = atomicAdd(&cursor[r], 1u);
    scol[offsets[r] + idx] = cols[e];
}

// ---------------- attention (wave-per-node, PAIR-EDGE fp8 k/v) + fused LN1 -----------
// Block = 4 nodes, one wave each. The wave's two 32-lane halves process TWO edges
// simultaneously: half-lane hl owns dims 8hl..8hl+7 (16B = chunks 2hl,2hl+1 of the
// 512B kv row). 4 lanes per head -> 2-level shfl dot reduce. Cross-half merge via
// shfl_xor(32) at the end. Odd tail: both halves read the same (valid) row; upper
// half's exp weight multiplied by 0 (finite -> no NaN).
// Single-pass exp (softmax shift-invariant => identical to reference).
__global__ __launch_bounds__(256)
void att_agg_kernel(const __hip_bfloat16* __restrict__ qb,
                    const unsigned char* __restrict__ kv8,
                    const unsigned* __restrict__ offsets,
                    const int* __restrict__ scol,
                    const float* __restrict__ x,
                    const float* __restrict__ g, const float* __restrict__ bb,
                    __hip_bfloat16* __restrict__ xn) {
    int n = blockIdx.x * 4 + (threadIdx.x >> 6);
    if (n >= N_NODES) return;
    const int lam = threadIdx.x & 63;
    const int hl  = lam & 31;          // dims 8hl..8hl+7
    const int sel = lam >> 5;          // which edge of the pair
    unsigned beg = offsets[n], end = offsets[n + 1];

    float qv[8];
    {
        uint4 u = *reinterpret_cast<const uint4*>(qb + (size_t)n * 256 + hl * 8);
        unpack_bf8(u, qv);
#pragma unroll
        for (int i = 0; i < 8; i++) qv[i] *= ATT_SCALE;
    }

    float acc[8] = {};
    float l = 0.f;

    // w.x = k[8hl..8hl+3], w.y = v[8hl..8hl+3], w.z = k[8hl+4..], w.w = v[8hl+4..]
#define PAIR_BODY(W, VMUL)                                                      \
    {                                                                           \
        auto k01 = __builtin_amdgcn_cvt_pk_f32_fp8((int)(W).x, false);          \
        auto k23 = __builtin_amdgcn_cvt_pk_f32_fp8((int)(W).x, true);           \
        auto k45 = __builtin_amdgcn_cvt_pk_f32_fp8((int)(W).z, false);          \
        auto k67 = __builtin_amdgcn_cvt_pk_f32_fp8((int)(W).z, true);           \
        float sv = qv[0] * k01[0] + qv[1] * k01[1] + qv[2] * k23[0]             \
                 + qv[3] * k23[1] + qv[4] * k45[0] + qv[5] * k45[1]             \
                 + qv[6] * k67[0] + qv[7] * k67[1];                             \
        sv += __shfl_xor(sv, 1);                                                \
        sv += __shfl_xor(sv, 2);                                                \
        float pv = __expf(sv) * (VMUL);                                         \
        l += pv;                                                                \
        auto v01 = __builtin_amdgcn_cvt_pk_f32_fp8((int)(W).y, false);          \
        auto v23 = __builtin_amdgcn_cvt_pk_f32_fp8((int)(W).y, true);           \
        auto v45 = __builtin_amdgcn_cvt_pk_f32_fp8((int)(W).w, false);          \
        auto v67 = __builtin_amdgcn_cvt_pk_f32_fp8((int)(W).w, true);           \
        acc[0] += pv * v01[0]; acc[1] += pv * v01[1];                           \
        acc[2] += pv * v23[0]; acc[3] += pv * v23[1];                           \
        acc[4] += pv * v45[0]; acc[5] += pv * v45[1];                           \
        acc[6] += pv * v67[0]; acc[7] += pv * v67[1];                           \
    }

    unsigned e = beg;
    for (; e + 4 <= end; e += 4) {           // 4 edges per iter (2 pairs in flight)
        int cA = scol[e + sel];
        int cB = scol[e + 2 + sel];
        uint4 wa = *reinterpret_cast<const uint4*>(kv8 + (size_t)cA * 512 + hl * 16);
        uint4 wb = *reinterpret_cast<const uint4*>(kv8 + (size_t)cB * 512 + hl * 16);
        PAIR_BODY(wa, 1.0f)
        PAIR_BODY(wb, 1.0f)
    }
    if (e + 2 <= end) {                      // one more full pair
        int cA = scol[e + sel];
        uint4 wa = *reinterpret_cast<const uint4*>(kv8 + (size_t)cA * 512 + hl * 16);
        PAIR_BODY(wa, 1.0f)
        e += 2;
    }
    if (e < end) {                           // odd tail: upper half masked to 0
        int cA = scol[e];
        uint4 wa = *reinterpret_cast<const uint4*>(kv8 + (size_t)cA * 512 + hl * 16);
        PAIR_BODY(wa, sel ? 0.0f : 1.0f)
    }
#undef PAIR_BODY

    // merge the two halves (different edges, same dims)
    l += __shfl_xor(l, 32);
#pragma unroll
    for (int i = 0; i < 8; i++) acc[i] += __shfl_xor(acc[i], 32);

    float inv_l = (l > 0.f) ? 1.f / l : 0.f;

    float tv[8];
    {
        const float4* xr = reinterpret_cast<const float4*>(x + (size_t)n * D_MODEL);
        float4 x0 = xr[hl * 2], x1 = xr[hl * 2 + 1];
        tv[0] = acc[0] * inv_l + x0.x; tv[1] = acc[1] * inv_l + x0.y;
        tv[2] = acc[2] * inv_l + x0.z; tv[3] = acc[3] * inv_l + x0.w;
        tv[4] = acc[4] * inv_l + x1.x; tv[5] = acc[5] * inv_l + x1.y;
        tv[6] = acc[6] * inv_l + x1.z; tv[7] = acc[7] * inv_l + x1.w;
    }

    float s = 0.f, s2 = 0.f;
#pragma unroll
    for (int i = 0; i < 8; i++) { s += tv[i]; s2 += tv[i] * tv[i]; }
#pragma unroll
    for (int off = 1; off <= 16; off <<= 1) {   // sum within each 32-lane half
        s  += __shfl_xor(s, off);
        s2 += __shfl_xor(s2, off);
    }
    float mean = s * (1.f / (float)D_MODEL);
    float var  = s2 * (1.f / (float)D_MODEL) - mean * mean;
    float inv  = rsqrtf(var + LN_EPS);

    if (sel == 0) {                          // lower half writes the full row
        const float4* gp = reinterpret_cast<const float4*>(g);
        const float4* bp = reinterpret_cast<const float4*>(bb);
        float4 g0 = gp[hl * 2], g1 = gp[hl * 2 + 1];
        float4 b0 = bp[hl * 2], b1 = bp[hl * 2 + 1];
        float gv[8] = {g0.x, g0.y, g0.z, g0.w, g1.x, g1.y, g1.z, g1.w};
        float bv[8] = {b0.x, b0.y, b0.z, b0.w, b1.x, b1.y, b1.z, b1.w};
        u16x8 o;
#pragma unroll
        for (int i = 0; i < 8; i++)
            o[i] = bfbits((tv[i] - mean) * inv * gv[i] + bv[i]);
        *reinterpret_cast<u16x8*>(xn + (size_t)n * D_MODEL + hl * 8) = o;
    }
}

extern "C" void kernel_launch(void* const* d_in, const int* in_sizes, int n_in,
                              void* d_out, int out_size, void* d_ws, size_t ws_size,
                              hipStream_t stream) {
    const float* x     = (const float*)d_in[0];
    const int*   ei    = (const int*)d_in[1];
    const float* w_qkv = (const float*)d_in[2];
    const float* b_qkv = (const float*)d_in[3];
    const float* ln1_g = (const float*)d_in[4];
    const float* ln1_b = (const float*)d_in[5];
    const float* ln2_g = (const float*)d_in[6];
    const float* ln2_b = (const float*)d_in[7];
    const float* w1    = (const float*)d_in[8];
    const float* b1    = (const float*)d_in[9];
    const float* w2    = (const float*)d_in[10];
    const float* b2    = (const float*)d_in[11];
    const int* rows = ei;
    const int* cols = ei + E_EDGES;

    // workspace layout (bytes), total < 179,200,000 (known-good footprint):
    //   [0,          25,600,000)  qb  bf16 N*256 } dead after att_agg;
    //   [25,600,000, 51,200,000)  kv8 fp8  N*512 } region [0,102.4e6) reused
    //                                            } as hbuf bf16 N*1024
    //   [102,400,000,128,000,000) xb bf16 N*256 (dead after qkv gemm)
    //   [128,000,000,128,393,216) wtq bf16 768x256 (perm cols)
    //   [128,400,000,128,924,288) wt1 bf16 1024x256 (perm cols)
    //   [129,000,000,129,524,288) wt2 bf16 256x1024
    //   [129,600,000,129,800,000) counts u32 N
    //   [129,800,000,130,000,004) offsets u32 N+1
    //   [130,000,008,130,200,008) cursor u32 N
    //   [130,200,008,133,400,008) scol i32 E
    //   [133,400,008,133,401,032) bsum u32 256
    //   [133,401,032,133,402,060) bpre u32 257
    //   [133,500,000,133,503,072) bqp f32 768 (perm qkv bias)
    //   [133,510,000,133,514,096) b1p f32 1024 (perm ffn1 bias)
    //   [153,600,000,179,200,000) xn bf16 N*256
    char* ws = (char*)d_ws;
    __hip_bfloat16* qb      = (__hip_bfloat16*)(ws + 0);
    unsigned char*  kv8     = (unsigned char*)(ws + 25600000);
    __hip_bfloat16* hbuf    = (__hip_bfloat16*)(ws + 0);
    __hip_bfloat16* xb      = (__hip_bfloat16*)(ws + 102400000);
    __hip_bfloat16* wtq     = (__hip_bfloat16*)(ws + 128000000);
    __hip_bfloat16* wt1     = (__hip_bfloat16*)(ws + 128400000);
    __hip_bfloat16* wt2     = (__hip_bfloat16*)(ws + 129000000);
    unsigned*       counts  = (unsigned*)(ws + 129600000);
    unsigned*       offsets = (unsigned*)(ws + 129800000);
    unsigned*       cursor  = (unsigned*)(ws + 130000008);
    int*            scol    = (int*)(ws + 130200008);
    unsigned*       bsum    = (unsigned*)(ws + 133400008);
    unsigned*       bpre    = (unsigned*)(ws + 133401032);
    float*          bqp     = (float*)(ws + 133500000);
    float*          b1p     = (float*)(ws + 133510000);
    __hip_bfloat16* xn      = (__hip_bfloat16*)(ws + 153600000);

    const int nbM = (N_NODES + 127) / 128;   // 391

    // fused prep: x->bf16, perm weights/biases, zero counts/cursor
    prep_kernel<<<(PREP_TOT + 255) / 256, 256, 0, stream>>>(
        x, (unsigned short*)xb, w_qkv, wtq, w1, wt1, w2, wt2,
        b_qkv, bqp, b1, b1p, counts, cursor);

    // q(bf16)/kv(fp8) = split(xb @ wtq^T + bqp), packed epilogue, dbuf pipeline
    mfma_gemm<false, 0><<<dim3(768 / 128, nbM), 256, 0, stream>>>(
        xb, wtq, bqp, nullptr, qb, kv8, N_NODES, 768, D_MODEL);

    // CSR build (hierarchical scan)
    count_kernel<<<(E_EDGES + 255) / 256, 256, 0, stream>>>(rows, counts);
    scan_blk_kernel<<<NB_SCAN, 256, 0, stream>>>(counts, offsets, bsum);
    scan_top_kernel<<<1, 256, 0, stream>>>(bsum, bpre);
    scan_add_kernel<<<NB_SCAN, 256, 0, stream>>>(offsets, bpre);
    scatter_kernel<<<(E_EDGES + 255) / 256, 256, 0, stream>>>(rows, cols, offsets, cursor, scol);

    // attention (pair-edge, fp8 kv) + fused LN1 -> xn
    att_agg_kernel<<<(N_NODES + 3) / 4, 256, 0, stream>>>(qb, kv8, offsets, scol,
                                                          x, ln1_g, ln1_b, xn);

    // hbuf = relu(xn @ wt1^T + b1p), packed epilogue, dbuf pipeline
    mfma_gemm<true, 1><<<dim3(F_FFN / 128, nbM), 256, 0, stream>>>(
        xn, wt1, b1p, hbuf, nullptr, nullptr, N_NODES, F_FFN, D_MODEL);

    // d_out = LN2(hbuf @ wt2^T + b2 + xn)   (fused, f32 out; dbuf pipeline)
    ffn2_ln_kernel<<<(N_NODES + 63) / 64, 512, 0, stream>>>(hbuf, wt2, b2, xn, ln2_g, ln2_b,
                                                            (float*)d_out, N_NODES);
}

// Round 4
// 414.342 us; speedup vs baseline: 1.1435x; 1.0029x over previous
//
#include <hip/hip_runtime.h>
#include <hip/hip_bf16.h>

#define N_NODES 50000
#define E_EDGES 800000
#define D_MODEL 256
#define H_HEADS 8
#define HDIM    32
#define F_FFN   1024
#define ATT_SCALE 0.0625f   // 256^-0.5
#define LN_EPS  1e-5f
#define NB_SCAN 196         // ceil(N_NODES/256)

typedef __attribute__((ext_vector_type(8))) short bf16x8;
typedef __attribute__((ext_vector_type(8))) unsigned short u16x8;
typedef __attribute__((ext_vector_type(4))) float f32x4;

__device__ __forceinline__ float bf2f(__hip_bfloat16 v) { return __bfloat162float(v); }
__device__ __forceinline__ __hip_bfloat16 f2bf(float v) { return __float2bfloat16(v); }
__device__ __forceinline__ unsigned short bfbits(float f) {
    __hip_bfloat16 h = __float2bfloat16(f);
    return *reinterpret_cast<unsigned short*>(&h);
}

// unpack 8 consecutive bf16 (16B aligned) -> 8 floats
__device__ __forceinline__ void unpack_bf8(uint4 u, float* f) {
    f[0] = __uint_as_float(u.x << 16); f[1] = __uint_as_float(u.x & 0xFFFF0000u);
    f[2] = __uint_as_float(u.y << 16); f[3] = __uint_as_float(u.y & 0xFFFF0000u);
    f[4] = __uint_as_float(u.z << 16); f[5] = __uint_as_float(u.z & 0xFFFF0000u);
    f[6] = __uint_as_float(u.w << 16); f[7] = __uint_as_float(u.w & 0xFFFF0000u);
}

// async global->LDS, 16B per lane; LDS dest must be wave-uniform base (+lane*16 implicit)
__device__ __forceinline__ void load_lds16(const void* g, void* l) {
    __builtin_amdgcn_global_load_lds(
        (const __attribute__((address_space(1))) unsigned*)g,
        (__attribute__((address_space(3))) unsigned*)l, 16, 0, 0);
}

// Column permutation (16x4 transpose within each 64-col block):
//   gemm perm-col p  <->  logical col T(p) = (p&~63) + ((p&15)<<2) + ((p>>4)&3)
// Weights are built so gemm col p holds original col T(p); the packed epilogue then
// stores each lane's 4 nj-values (perm cols B+lh+16j) at contiguous logical cols
// B + lh*4 + j  ->  outputs land in ORIGINAL logical order (att/wt2 unchanged).

// ---------------- fused prep: cvt_x + 3 weight transposes + bias perms + zero ---------
#define PREP_X   3200000                    // N*256/4 float4 units
#define PREP_WQ  (768 * 256)
#define PREP_W1  (1024 * 256)
#define PREP_W2  (256 * 1024)
#define PREP_BQ  768
#define PREP_B1  1024
#define PREP_TOT (PREP_X + PREP_WQ + PREP_W1 + PREP_W2 + PREP_BQ + PREP_B1 + N_NODES)
__global__ void prep_kernel(const float* __restrict__ x, unsigned short* __restrict__ xb,
                            const float* __restrict__ wq, __hip_bfloat16* __restrict__ wtq,
                            const float* __restrict__ w1, __hip_bfloat16* __restrict__ wt1,
                            const float* __restrict__ w2, __hip_bfloat16* __restrict__ wt2,
                            const float* __restrict__ bq, float* __restrict__ bqp,
                            const float* __restrict__ b1, float* __restrict__ b1p,
                            unsigned* __restrict__ counts, unsigned* __restrict__ cursor) {
    int i = blockIdx.x * blockDim.x + threadIdx.x;
    if (i < PREP_X) {
        float4 v = reinterpret_cast<const float4*>(x)[i];
        ushort4 o;
        o.x = bfbits(v.x); o.y = bfbits(v.y); o.z = bfbits(v.z); o.w = bfbits(v.w);
        reinterpret_cast<ushort4*>(xb)[i] = o;
        return;
    }
    i -= PREP_X;
    if (i < PREP_WQ) {
        int n = i >> 8, k = i & 255;          // n = perm col in [0,768)
        int s = n >> 8, prel = n & 255;       // section 0=q,1=k,2=v
        int d = (prel & 192) + ((prel & 15) << 2) + ((prel >> 4) & 3);  // logical dim
        int co = (d >> 5) * 96 + s * 32 + (d & 31);                     // orig col
        wtq[i] = f2bf(wq[(size_t)k * 768 + co]);
        return;
    }
    i -= PREP_WQ;
    if (i < PREP_W1) {
        int n = i >> 8, k = i & 255;          // n = perm col in [0,1024)
        int f = (n & ~63) + ((n & 15) << 2) + ((n >> 4) & 3);
        wt1[i] = f2bf(w1[(size_t)k * 1024 + f]);
        return;
    }
    i -= PREP_W1;
    if (i < PREP_W2) {
        int n = i >> 10, k = i & 1023;        // unpermuted (hbuf is logical order)
        wt2[i] = f2bf(w2[(size_t)k * 256 + n]);
        return;
    }
    i -= PREP_W2;
    if (i < PREP_BQ) {
        int s = i >> 8, prel = i & 255;
        int d = (prel & 192) + ((prel & 15) << 2) + ((prel >> 4) & 3);
        bqp[i] = bq[(d >> 5) * 96 + s * 32 + (d & 31)];
        return;
    }
    i -= PREP_BQ;
    if (i < PREP_B1) {
        int f = (i & ~63) + ((i & 15) << 2) + ((i >> 4) & 3);
        b1p[i] = b1[f];
        return;
    }
    i -= PREP_B1;
    if (i < N_NODES) { counts[i] = 0u; cursor[i] = 0u; }
}

// ---------------- MFMA GEMM: out = A @ Wt^T + bias (perm cols, packed epilogue) ------
// A: MxK bf16 row-major. Wt: NxK bf16 row-major (perm-transposed weights).
// 128x128 tile, 256 threads = 4 waves (2x2 of 64x64), 16x16x32 bf16 MFMA, BK=32.
// 2-phase LDS double-buffer: STAGE(s+1) issued BEFORE compute(s), one barrier/step.
// XCD-aware bijective swizzle (m204) so same-A-row tiles share one XCD's L2.
// EPI==0 (qkv): perm col space [q:0-255][k:256-511][v:512-767]; tile is section-pure.
// EPI==1: relu + one ushort4 store per (mi,r) at out[gm*Ncols + B + lh*4].
template<bool RELU, int EPI>
__global__ __launch_bounds__(256)
void mfma_gemm(const __hip_bfloat16* __restrict__ A,
               const __hip_bfloat16* __restrict__ Wt,
               const float* __restrict__ bias,
               __hip_bfloat16* __restrict__ outp,
               __hip_bfloat16* __restrict__ qb,
               unsigned char* __restrict__ kv8,
               int M, int Ncols, int K) {
    __shared__ short Al[2][128 * 32];
    __shared__ short Bl[2][128 * 32];
    const int t = threadIdx.x;
    const int wave = t >> 6, lane = t & 63;

    // bijective XCD swizzle: contiguous wg runs per XCD -> same-row tiles co-located
    unsigned flat = blockIdx.y * gridDim.x + blockIdx.x;
    unsigned nwg = gridDim.x * gridDim.y;
    unsigned q8 = nwg >> 3, r8 = nwg & 7;
    unsigned xcd = flat & 7, pos = flat >> 3;
    unsigned wg = (xcd < r8) ? (xcd * (q8 + 1) + pos)
                             : (r8 * (q8 + 1) + (xcd - r8) * q8 + pos);
    const int m0 = (int)(wg / gridDim.x) * 128;
    const int n0 = (int)(wg % gridDim.x) * 128;

    const int wr = wave >> 1, wc = wave & 1;

    const int srow = lane >> 2;                        // row within chunk 0..15
    const int skp  = (lane & 3) ^ ((lane >> 3) & 3);   // swizzled global k-part
    const int c0 = wave * 2;
    int ar0 = m0 + c0 * 16 + srow;      if (ar0 >= M) ar0 = M - 1;
    int ar1 = m0 + c0 * 16 + 16 + srow; if (ar1 >= M) ar1 = M - 1;
    const __hip_bfloat16* ga0 = A + (size_t)ar0 * K + skp * 8;
    const __hip_bfloat16* ga1 = A + (size_t)ar1 * K + skp * 8;
    const __hip_bfloat16* gb0 = Wt + (size_t)(n0 + c0 * 16 + srow) * K + skp * 8;
    const __hip_bfloat16* gb1 = Wt + (size_t)(n0 + c0 * 16 + 16 + srow) * K + skp * 8;

    const int lh = lane & 15, q = lane >> 4;
    const int qs = q ^ ((lane >> 1) & 3);
    const short* fa0 = &Al[0][(wr * 64 + lh) * 32 + qs * 8];
    const short* fb0 = &Bl[0][(wc * 64 + lh) * 32 + qs * 8];
    const short* fa1 = &Al[1][(wr * 64 + lh) * 32 + qs * 8];
    const short* fb1 = &Bl[1][(wc * 64 + lh) * 32 + qs * 8];

    f32x4 acc[4][4] = {};

#define GSTAGE(B)                                    \
    load_lds16(ga0, &Al[B][c0 * 512]);               \
    load_lds16(ga1, &Al[B][c0 * 512 + 512]);         \
    load_lds16(gb0, &Bl[B][c0 * 512]);               \
    load_lds16(gb1, &Bl[B][c0 * 512 + 512]);         \
    ga0 += 32; ga1 += 32; gb0 += 32; gb1 += 32;

#define GSTEP(FA, FB)                                                       \
    {                                                                       \
        bf16x8 af[4], bfr[4];                                               \
        _Pragma("unroll")                                                   \
        for (int i = 0; i < 4; i++) {                                       \
            af[i]  = *reinterpret_cast<const bf16x8*>((FA) + i * 16 * 32);  \
            bfr[i] = *reinterpret_cast<const bf16x8*>((FB) + i * 16 * 32);  \
        }                                                                   \
        _Pragma("unroll")                                                   \
        for (int mi = 0; mi < 4; mi++)                                      \
            _Pragma("unroll")                                               \
            for (int nj = 0; nj < 4; nj++)                                  \
                acc[mi][nj] = __builtin_amdgcn_mfma_f32_16x16x32_bf16(      \
                    af[mi], bfr[nj], acc[mi][nj], 0, 0, 0);                 \
    }

    const int nsteps = K >> 5;          // 8 for K=256 (even)
    GSTAGE(0)
    __syncthreads();
    for (int s = 0; s < nsteps; s += 2) {
        if (s + 1 < nsteps) { GSTAGE(1) }
        GSTEP(fa0, fb0)
        __syncthreads();
        if (s + 2 < nsteps) { GSTAGE(0) }
        GSTEP(fa1, fb1)
        __syncthreads();
    }
#undef GSTAGE
#undef GSTEP

    // epilogue: C/D layout col = lane&15, row = (lane>>4)*4 + reg
    const int B = n0 + wc * 64;
    const int gnbase = B + lh;
    float bv[4];
#pragma unroll
    for (int nj = 0; nj < 4; nj++) bv[nj] = bias[gnbase + nj * 16];

    if (EPI == 0) {
        const int sec = B >> 8;                       // 0=q,1=k,2=v (block-uniform)
        const int c = ((B & 255) >> 6) * 16 + lh;     // chunk index [0,64)
#pragma unroll
        for (int mi = 0; mi < 4; mi++) {
            int gmb = m0 + wr * 64 + mi * 16 + q * 4;
#pragma unroll
            for (int r = 0; r < 4; r++) {
                int gm = gmb + r;
                if (gm >= M) continue;
                float v0 = acc[mi][0][r] + bv[0];
                float v1 = acc[mi][1][r] + bv[1];
                float v2 = acc[mi][2][r] + bv[2];
                float v3 = acc[mi][3][r] + bv[3];
                if (sec == 0) {
                    ushort4 o;
                    o.x = bfbits(v0); o.y = bfbits(v1); o.z = bfbits(v2); o.w = bfbits(v3);
                    *reinterpret_cast<ushort4*>(qb + (size_t)gm * 256 + c * 4) = o;
                } else {
                    unsigned u = (unsigned)__builtin_amdgcn_cvt_pk_fp8_f32(v0, v1, 0, false);
                    u = (unsigned)__builtin_amdgcn_cvt_pk_fp8_f32(v2, v3, (int)u, true);
                    *reinterpret_cast<unsigned*>(
                        kv8 + (size_t)gm * 512 + c * 8 + (sec == 1 ? 0 : 4)) = u;
                }
            }
        }
    } else {
        const int cb = B + lh * 4;                    // logical col base (T-perm)
#pragma unroll
        for (int mi = 0; mi < 4; mi++) {
            int gmb = m0 + wr * 64 + mi * 16 + q * 4;
#pragma unroll
            for (int r = 0; r < 4; r++) {
                int gm = gmb + r;
                if (gm >= M) continue;
                float v0 = acc[mi][0][r] + bv[0];
                float v1 = acc[mi][1][r] + bv[1];
                float v2 = acc[mi][2][r] + bv[2];
                float v3 = acc[mi][3][r] + bv[3];
                if (RELU) {
                    v0 = fmaxf(v0, 0.f); v1 = fmaxf(v1, 0.f);
                    v2 = fmaxf(v2, 0.f); v3 = fmaxf(v3, 0.f);
                }
                ushort4 o;
                o.x = bfbits(v0); o.y = bfbits(v1); o.z = bfbits(v2); o.w = bfbits(v3);
                *reinterpret_cast<ushort4*>(outp + (size_t)gm * Ncols + cb) = o;
            }
        }
    }
}

// ---------------- ffn2 + fused LN2: out = LN(hbuf @ wt2^T + b2 + xn) ------------------
// 64 x 256 tile, 512 threads = 8 waves (2x4 of 32x64), K=1024, BK=32,
// 2-phase double-buffered LDS, single __syncthreads per K-step.
__global__ __launch_bounds__(512)
void ffn2_ln_kernel(const __hip_bfloat16* __restrict__ A,    // M x 1024
                    const __hip_bfloat16* __restrict__ Wt,   // 256 x 1024
                    const float* __restrict__ bias,
                    const __hip_bfloat16* __restrict__ resid,// M x 256
                    const float* __restrict__ g, const float* __restrict__ bb,
                    float* __restrict__ out, int M) {
    __shared__ short LDS[2][(64 + 256) * 32];   // A at [0,2048), B at [2048,10240)
    const int t = threadIdx.x;
    const int wave = t >> 6, lane = t & 63;
    const int m0 = blockIdx.x * 64;
    const int wr = wave >> 2, wc = wave & 3;

    const int srow = lane >> 2;                        // row within chunk 0..15
    const int skp  = (lane & 3) ^ ((lane >> 3) & 3);   // swizzled global k-part

    const __hip_bfloat16* gsrc0; int loff0;
    const __hip_bfloat16* gsrc1; int loff1;
    const __hip_bfloat16* gsrc2; int loff2;
    {
#define STAGE_INIT(GS, LO, C)                                            \
        if ((C) < 4) {                                                   \
            int r_ = m0 + (C) * 16 + srow; if (r_ >= M) r_ = M - 1;      \
            GS = A + (size_t)r_ * 1024 + skp * 8;                        \
            LO = (C) * 512;                                              \
        } else {                                                         \
            GS = Wt + (size_t)(((C) - 4) * 16 + srow) * 1024 + skp * 8;  \
            LO = 2048 + ((C) - 4) * 512;                                 \
        }
        STAGE_INIT(gsrc0, loff0, wave)
        STAGE_INIT(gsrc1, loff1, wave + 8)
        int c2 = (wave < 4) ? wave + 16 : 16;
        STAGE_INIT(gsrc2, loff2, c2)
#undef STAGE_INIT
    }

    const int lh = lane & 15, q = lane >> 4;
    const int qs = q ^ ((lane >> 1) & 3);
    const short* fa0 = &LDS[0][(wr * 32 + lh) * 32 + qs * 8];
    const short* fb0 = &LDS[0][2048 + (wc * 64 + lh) * 32 + qs * 8];
    const short* fa1 = &LDS[1][(wr * 32 + lh) * 32 + qs * 8];
    const short* fb1 = &LDS[1][2048 + (wc * 64 + lh) * 32 + qs * 8];

    f32x4 acc[2][4] = {};

#define FFN2_STAGE(BUF)                                      \
    load_lds16(gsrc0, &LDS[BUF][loff0]);                     \
    load_lds16(gsrc1, &LDS[BUF][loff1]);                     \
    if (wave < 4) load_lds16(gsrc2, &LDS[BUF][loff2]);       \
    gsrc0 += 32; gsrc1 += 32; gsrc2 += 32;

#define FFN2_STEP(FA, FB)                                                   \
    {                                                                       \
        bf16x8 af[2], bfr[4];                                               \
        _Pragma("unroll")                                                   \
        for (int i = 0; i < 2; i++)                                         \
            af[i] = *reinterpret_cast<const bf16x8*>((FA) + i * 16 * 32);   \
        _Pragma("unroll")                                                   \
        for (int i = 0; i < 4; i++)                                         \
            bfr[i] = *reinterpret_cast<const bf16x8*>((FB) + i * 16 * 32);  \
        _Pragma("unroll")                                                   \
        for (int mi = 0; mi < 2; mi++)                                      \
            _Pragma("unroll")                                               \
            for (int nj = 0; nj < 4; nj++)                                  \
                acc[mi][nj] = __builtin_amdgcn_mfma_f32_16x16x32_bf16(      \
                    af[mi], bfr[nj], acc[mi][nj], 0, 0, 0);                 \
    }

    // prologue: stage step 0 into buf0
    FFN2_STAGE(0)
    __syncthreads();

    for (int s = 0; s < 32; s += 2) {
        FFN2_STAGE(1)                      // loads for step s+1 (always valid, s+1<=31)
        FFN2_STEP(fa0, fb0)                // compute step s
        __syncthreads();
        if (s < 30) { FFN2_STAGE(0) }      // loads for step s+2
        FFN2_STEP(fa1, fb1)                // compute step s+1
        __syncthreads();
    }
#undef FFN2_STAGE
#undef FFN2_STEP

    // ---- epilogue: v = acc + b2 + xn; per-row LN over 256 cols; write f32 ----
    const int colbase = wc * 64 + lh;   // + nj*16
    float bv[4], gv[4], bbv[4];
#pragma unroll
    for (int nj = 0; nj < 4; nj++) {
        bv[nj]  = bias[colbase + nj * 16];
        gv[nj]  = g[colbase + nj * 16];
        bbv[nj] = bb[colbase + nj * 16];
    }

    float ps[2][4], pq[2][4];
#pragma unroll
    for (int mi = 0; mi < 2; mi++) {
#pragma unroll
        for (int r = 0; r < 4; r++) {
            int gm = m0 + wr * 32 + mi * 16 + q * 4 + r;
            int rgm = (gm < M) ? gm : M - 1;
            float s = 0.f, s2 = 0.f;
#pragma unroll
            for (int nj = 0; nj < 4; nj++) {
                float v = acc[mi][nj][r] + bv[nj]
                        + bf2f(resid[(size_t)rgm * 256 + colbase + nj * 16]);
                acc[mi][nj][r] = v;
                s += v; s2 += v * v;
            }
            ps[mi][r] = s; pq[mi][r] = s2;
        }
    }
#pragma unroll
    for (int off = 1; off <= 8; off <<= 1) {
#pragma unroll
        for (int mi = 0; mi < 2; mi++)
#pragma unroll
            for (int r = 0; r < 4; r++) {
                ps[mi][r] += __shfl_xor(ps[mi][r], off);
                pq[mi][r] += __shfl_xor(pq[mi][r], off);
            }
    }
    // cross-wave (wc) merge via LDS (reuse buf0: 64 rows x 4 wc x 2 vals = 2 KB)
    float* rs = (float*)(&LDS[0][0]);   // [64][4]
    float* rq = rs + 256;
    if (lh == 0) {
#pragma unroll
        for (int mi = 0; mi < 2; mi++)
#pragma unroll
            for (int r = 0; r < 4; r++) {
                int m = wr * 32 + mi * 16 + q * 4 + r;
                rs[m * 4 + wc] = ps[mi][r];
                rq[m * 4 + wc] = pq[mi][r];
            }
    }
    __syncthreads();

#pragma unroll
    for (int mi = 0; mi < 2; mi++) {
#pragma unroll
        for (int r = 0; r < 4; r++) {
            int m = wr * 32 + mi * 16 + q * 4 + r;
            int gm = m0 + m;
            if (gm >= M) continue;
            float4 rsv = *reinterpret_cast<const float4*>(&rs[m * 4]);
            float4 rqv = *reinterpret_cast<const float4*>(&rq[m * 4]);
            float S  = (rsv.x + rsv.y) + (rsv.z + rsv.w);
            float S2 = (rqv.x + rqv.y) + (rqv.z + rqv.w);
            float mean = S * (1.f / (float)D_MODEL);
            float var  = S2 * (1.f / (float)D_MODEL) - mean * mean;
            float inv  = rsqrtf(var + LN_EPS);
#pragma unroll
            for (int nj = 0; nj < 4; nj++)
                out[(size_t)gm * 256 + colbase + nj * 16] =
                    (acc[mi][nj][r] - mean) * inv * gv[nj] + bbv[nj];
        }
    }
}

// ---------------- CSR build ----------------
__global__ void count_kernel(const int* __restrict__ rows, unsigned* __restrict__ counts) {
    int e = blockIdx.x * blockDim.x + threadIdx.x;
    if (e < E_EDGES) atomicAdd(&counts[rows[e]], 1u);
}

__global__ void scan_blk_kernel(const unsigned* __restrict__ counts,
                                unsigned* __restrict__ offs, unsigned* __restrict__ bsum) {
    __shared__ unsigned sh[256];
    int t = threadIdx.x;
    int i = blockIdx.x * 256 + t;
    unsigned v = (i < N_NODES) ? counts[i] : 0u;
    sh[t] = v;
    __syncthreads();
#pragma unroll
    for (int off = 1; off < 256; off <<= 1) {
        unsigned u = (t >= off) ? sh[t - off] : 0u;
        __syncthreads();
        sh[t] += u;
        __syncthreads();
    }
    if (i < N_NODES) offs[i] = sh[t] - v;
    if (t == 255) bsum[blockIdx.x] = sh[255];
}

__global__ void scan_top_kernel(const unsigned* __restrict__ bsum, unsigned* __restrict__ bpre) {
    __shared__ unsigned sh[256];
    int t = threadIdx.x;
    unsigned v = (t < NB_SCAN) ? bsum[t] : 0u;
    sh[t] = v;
    __syncthreads();
#pragma unroll
    for (int off = 1; off < 256; off <<= 1) {
        unsigned u = (t >= off) ? sh[t - off] : 0u;
        __syncthreads();
        sh[t] += u;
        __syncthreads();
    }
    if (t < NB_SCAN) bpre[t] = sh[t] - v;
    if (t == NB_SCAN - 1) bpre[NB_SCAN] = sh[t];
}

__global__ void scan_add_kernel(unsigned* __restrict__ offs, const unsigned* __restrict__ bpre) {
    int i = blockIdx.x * 256 + threadIdx.x;
    if (i < N_NODES) offs[i] += bpre[blockIdx.x];
    if (i == 0) offs[N_NODES] = bpre[NB_SCAN];
}

__global__ void scatter_kernel(const int* __restrict__ rows, const int* __restrict__ cols,
                               const unsigned* __restrict__ offsets, unsigned* __restrict__ cursor,
                               int* __restrict__ scol) {
    int e = blockIdx.x * blockDim.x + threadIdx.x;
    if (e >= E_EDGES) return;
    int r = rows[e];
    unsigned idx = atomicAdd(&cursor[r], 1u);
    scol[offsets[r] + idx] = cols[e];
}

// ---------------- attention (wave-per-node, PAIR-EDGE fp8 k/v) + fused LN1 -----------
// Block = 2 nodes, one wave each (fine retirement granularity for degree variance).
// The wave's two 32-lane halves process TWO edges simultaneously: half-lane hl owns
// dims 8hl..8hl+7 (16B of the 512B kv row). 4 lanes per head -> 2-level shfl reduce.
// 8-edge main batch: 4 independent dwordx4 gathers (64 cache lines) in flight per wave;
// next batch's scol indices are loaded DURING current batch's compute (breaks the
// scol->kv serial chain). Odd tail masks the upper half's exp weight to 0.
// Single-pass exp (softmax shift-invariant => identical to reference).
__global__ __launch_bounds__(128)
void att_agg_kernel(const __hip_bfloat16* __restrict__ qb,
                    const unsigned char* __restrict__ kv8,
                    const unsigned* __restrict__ offsets,
                    const int* __restrict__ scol,
                    const float* __restrict__ x,
                    const float* __restrict__ g, const float* __restrict__ bb,
                    __hip_bfloat16* __restrict__ xn) {
    int n = blockIdx.x * 2 + (threadIdx.x >> 6);
    if (n >= N_NODES) return;
    const int lam = threadIdx.x & 63;
    const int hl  = lam & 31;          // dims 8hl..8hl+7
    const int sel = lam >> 5;          // which edge of the pair
    unsigned beg = offsets[n], end = offsets[n + 1];

    float qv[8];
    {
        uint4 u = *reinterpret_cast<const uint4*>(qb + (size_t)n * 256 + hl * 8);
        unpack_bf8(u, qv);
#pragma unroll
        for (int i = 0; i < 8; i++) qv[i] *= ATT_SCALE;
    }

    float acc[8] = {};
    float l = 0.f;

    // w.x = k[8hl..8hl+3], w.y = v[8hl..8hl+3], w.z = k[8hl+4..], w.w = v[8hl+4..]
#define PAIR_BODY(W, VMUL)                                                      \
    {                                                                           \
        auto k01 = __builtin_amdgcn_cvt_pk_f32_fp8((int)(W).x, false);          \
        auto k23 = __builtin_amdgcn_cvt_pk_f32_fp8((int)(W).x, true);           \
        auto k45 = __builtin_amdgcn_cvt_pk_f32_fp8((int)(W).z, false);          \
        auto k67 = __builtin_amdgcn_cvt_pk_f32_fp8((int)(W).z, true);           \
        float sv = qv[0] * k01[0] + qv[1] * k01[1] + qv[2] * k23[0]             \
                 + qv[3] * k23[1] + qv[4] * k45[0] + qv[5] * k45[1]             \
                 + qv[6] * k67[0] + qv[7] * k67[1];                             \
        sv += __shfl_xor(sv, 1);                                                \
        sv += __shfl_xor(sv, 2);                                                \
        float pv = __expf(sv) * (VMUL);                                         \
        l += pv;                                                                \
        auto v01 = __builtin_amdgcn_cvt_pk_f32_fp8((int)(W).y, false);          \
        auto v23 = __builtin_amdgcn_cvt_pk_f32_fp8((int)(W).y, true);           \
        auto v45 = __builtin_amdgcn_cvt_pk_f32_fp8((int)(W).w, false);          \
        auto v67 = __builtin_amdgcn_cvt_pk_f32_fp8((int)(W).w, true);           \
        acc[0] += pv * v01[0]; acc[1] += pv * v01[1];                           \
        acc[2] += pv * v23[0]; acc[3] += pv * v23[1];                           \
        acc[4] += pv * v45[0]; acc[5] += pv * v45[1];                           \
        acc[6] += pv * v67[0]; acc[7] += pv * v67[1];                           \
    }

    unsigned e = beg;
    // ---- 8-edge pipelined main loop: 4 gathers in flight, scol one batch ahead ----
    int cA = 0, cB = 0, cC = 0, cD = 0;
    if (e + 8 <= end) {
        cA = scol[e + sel];     cB = scol[e + 2 + sel];
        cC = scol[e + 4 + sel]; cD = scol[e + 6 + sel];
    }
    while (e + 8 <= end) {
        uint4 wa = *reinterpret_cast<const uint4*>(kv8 + (size_t)cA * 512 + hl * 16);
        uint4 wb = *reinterpret_cast<const uint4*>(kv8 + (size_t)cB * 512 + hl * 16);
        uint4 wc = *reinterpret_cast<const uint4*>(kv8 + (size_t)cC * 512 + hl * 16);
        uint4 wd = *reinterpret_cast<const uint4*>(kv8 + (size_t)cD * 512 + hl * 16);
        e += 8;
        if (e + 8 <= end) {                 // prefetch next batch's indices
            cA = scol[e + sel];     cB = scol[e + 2 + sel];
            cC = scol[e + 4 + sel]; cD = scol[e + 6 + sel];
        }
        PAIR_BODY(wa, 1.0f)
        PAIR_BODY(wb, 1.0f)
        PAIR_BODY(wc, 1.0f)
        PAIR_BODY(wd, 1.0f)
    }
    // ---- tails: 2-edge pairs, then odd ----
    for (; e + 2 <= end; e += 2) {
        int c0 = scol[e + sel];
        uint4 wa = *reinterpret_cast<const uint4*>(kv8 + (size_t)c0 * 512 + hl * 16);
        PAIR_BODY(wa, 1.0f)
    }
    if (e < end) {                           // odd tail: upper half masked to 0
        int c0 = scol[e];
        uint4 wa = *reinterpret_cast<const uint4*>(kv8 + (size_t)c0 * 512 + hl * 16);
        PAIR_BODY(wa, sel ? 0.0f : 1.0f)
    }
#undef PAIR_BODY

    // merge the two halves (different edges, same dims)
    l += __shfl_xor(l, 32);
#pragma unroll
    for (int i = 0; i < 8; i++) acc[i] += __shfl_xor(acc[i], 32);

    float inv_l = (l > 0.f) ? 1.f / l : 0.f;

    float tv[8];
    {
        const float4* xr = reinterpret_cast<const float4*>(x + (size_t)n * D_MODEL);
        float4 x0 = xr[hl * 2], x1 = xr[hl * 2 + 1];
        tv[0] = acc[0] * inv_l + x0.x; tv[1] = acc[1] * inv_l + x0.y;
        tv[2] = acc[2] * inv_l + x0.z; tv[3] = acc[3] * inv_l + x0.w;
        tv[4] = acc[4] * inv_l + x1.x; tv[5] = acc[5] * inv_l + x1.y;
        tv[6] = acc[6] * inv_l + x1.z; tv[7] = acc[7] * inv_l + x1.w;
    }

    float s = 0.f, s2 = 0.f;
#pragma unroll
    for (int i = 0; i < 8; i++) { s += tv[i]; s2 += tv[i] * tv[i]; }
#pragma unroll
    for (int off = 1; off <= 16; off <<= 1) {   // sum within each 32-lane half
        s  += __shfl_xor(s, off);
        s2 += __shfl_xor(s2, off);
    }
    float mean = s * (1.f / (float)D_MODEL);
    float var  = s2 * (1.f / (float)D_MODEL) - mean * mean;
    float inv  = rsqrtf(var + LN_EPS);

    if (sel == 0) {                          // lower half writes the full row
        const float4* gp = reinterpret_cast<const float4*>(g);
        const float4* bp = reinterpret_cast<const float4*>(bb);
        float4 g0 = gp[hl * 2], g1 = gp[hl * 2 + 1];
        float4 b0 = bp[hl * 2], b1 = bp[hl * 2 + 1];
        float gv[8] = {g0.x, g0.y, g0.z, g0.w, g1.x, g1.y, g1.z, g1.w};
        float bv[8] = {b0.x, b0.y, b0.z, b0.w, b1.x, b1.y, b1.z, b1.w};
        u16x8 o;
#pragma unroll
        for (int i = 0; i < 8; i++)
            o[i] = bfbits((tv[i] - mean) * inv * gv[i] + bv[i]);
        *reinterpret_cast<u16x8*>(xn + (size_t)n * D_MODEL + hl * 8) = o;
    }
}

extern "C" void kernel_launch(void* const* d_in, const int* in_sizes, int n_in,
                              void* d_out, int out_size, void* d_ws, size_t ws_size,
                              hipStream_t stream) {
    const float* x     = (const float*)d_in[0];
    const int*   ei    = (const int*)d_in[1];
    const float* w_qkv = (const float*)d_in[2];
    const float* b_qkv = (const float*)d_in[3];
    const float* ln1_g = (const float*)d_in[4];
    const float* ln1_b = (const float*)d_in[5];
    const float* ln2_g = (const float*)d_in[6];
    const float* ln2_b = (const float*)d_in[7];
    const float* w1    = (const float*)d_in[8];
    const float* b1    = (const float*)d_in[9];
    const float* w2    = (const float*)d_in[10];
    const float* b2    = (const float*)d_in[11];
    const int* rows = ei;
    const int* cols = ei + E_EDGES;

    // workspace layout (bytes), total < 179,200,000 (known-good footprint):
    //   [0,          25,600,000)  qb  bf16 N*256 } dead after att_agg;
    //   [25,600,000, 51,200,000)  kv8 fp8  N*512 } region [0,102.4e6) reused
    //                                            } as hbuf bf16 N*1024
    //   [102,400,000,128,000,000) xb bf16 N*256 (dead after qkv gemm)
    //   [128,000,000,128,393,216) wtq bf16 768x256 (perm cols)
    //   [128,400,000,128,924,288) wt1 bf16 1024x256 (perm cols)
    //   [129,000,000,129,524,288) wt2 bf16 256x1024
    //   [129,600,000,129,800,000) counts u32 N
    //   [129,800,000,130,000,004) offsets u32 N+1
    //   [130,000,008,130,200,008) cursor u32 N
    //   [130,200,008,133,400,008) scol i32 E
    //   [133,400,008,133,401,032) bsum u32 256
    //   [133,401,032,133,402,060) bpre u32 257
    //   [133,500,000,133,503,072) bqp f32 768 (perm qkv bias)
    //   [133,510,000,133,514,096) b1p f32 1024 (perm ffn1 bias)
    //   [153,600,000,179,200,000) xn bf16 N*256
    char* ws = (char*)d_ws;
    __hip_bfloat16* qb      = (__hip_bfloat16*)(ws + 0);
    unsigned char*  kv8     = (unsigned char*)(ws + 25600000);
    __hip_bfloat16* hbuf    = (__hip_bfloat16*)(ws + 0);
    __hip_bfloat16* xb      = (__hip_bfloat16*)(ws + 102400000);
    __hip_bfloat16* wtq     = (__hip_bfloat16*)(ws + 128000000);
    __hip_bfloat16* wt1     = (__hip_bfloat16*)(ws + 128400000);
    __hip_bfloat16* wt2     = (__hip_bfloat16*)(ws + 129000000);
    unsigned*       counts  = (unsigned*)(ws + 129600000);
    unsigned*       offsets = (unsigned*)(ws + 129800000);
    unsigned*       cursor  = (unsigned*)(ws + 130000008);
    int*            scol    = (int*)(ws + 130200008);
    unsigned*       bsum    = (unsigned*)(ws + 133400008);
    unsigned*       bpre    = (unsigned*)(ws + 133401032);
    float*          bqp     = (float*)(ws + 133500000);
    float*          b1p     = (float*)(ws + 133510000);
    __hip_bfloat16* xn      = (__hip_bfloat16*)(ws + 153600000);

    const int nbM = (N_NODES + 127) / 128;   // 391

    // fused prep: x->bf16, perm weights/biases, zero counts/cursor
    prep_kernel<<<(PREP_TOT + 255) / 256, 256, 0, stream>>>(
        x, (unsigned short*)xb, w_qkv, wtq, w1, wt1, w2, wt2,
        b_qkv, bqp, b1, b1p, counts, cursor);

    // q(bf16)/kv(fp8) = split(xb @ wtq^T + bqp), packed epilogue, dbuf pipeline
    mfma_gemm<false, 0><<<dim3(768 / 128, nbM), 256, 0, stream>>>(
        xb, wtq, bqp, nullptr, qb, kv8, N_NODES, 768, D_MODEL);

    // CSR build (hierarchical scan)
    count_kernel<<<(E_EDGES + 255) / 256, 256, 0, stream>>>(rows, counts);
    scan_blk_kernel<<<NB_SCAN, 256, 0, stream>>>(counts, offsets, bsum);
    scan_top_kernel<<<1, 256, 0, stream>>>(bsum, bpre);
    scan_add_kernel<<<NB_SCAN, 256, 0, stream>>>(offsets, bpre);
    scatter_kernel<<<(E_EDGES + 255) / 256, 256, 0, stream>>>(rows, cols, offsets, cursor, scol);

    // attention (pair-edge, 8-edge pipelined batches, fp8 kv) + fused LN1 -> xn
    att_agg_kernel<<<(N_NODES + 1) / 2, 128, 0, stream>>>(qb, kv8, offsets, scol,
                                                          x, ln1_g, ln1_b, xn);

    // hbuf = relu(xn @ wt1^T + b1p), packed epilogue, dbuf pipeline
    mfma_gemm<true, 1><<<dim3(F_FFN / 128, nbM), 256, 0, stream>>>(
        xn, wt1, b1p, hbuf, nullptr, nullptr, N_NODES, F_FFN, D_MODEL);

    // d_out = LN2(hbuf @ wt2^T + b2 + xn)   (fused, f32 out; dbuf pipeline)
    ffn2_ln_kernel<<<(N_NODES + 63) / 64, 512, 0, stream>>>(hbuf, wt2, b2, xn, ln2_g, ln2_b,
                                                            (float*)d_out, N_NODES);
}

// Round 6
// 410.672 us; speedup vs baseline: 1.1537x; 1.0089x over previous
//
#include <hip/hip_runtime.h>
#include <hip/hip_bf16.h>

#define N_NODES 50000
#define E_EDGES 800000
#define D_MODEL 256
#define H_HEADS 8
#define HDIM    32
#define F_FFN   1024
#define ATT_SCALE 0.0625f   // 256^-0.5
#define LN_EPS  1e-5f
#define NB_SCAN 196         // ceil(N_NODES/256)

typedef __attribute__((ext_vector_type(8))) short bf16x8;
typedef __attribute__((ext_vector_type(8))) unsigned short u16x8;
typedef __attribute__((ext_vector_type(4))) float f32x4;

__device__ __forceinline__ float bf2f(__hip_bfloat16 v) { return __bfloat162float(v); }
__device__ __forceinline__ __hip_bfloat16 f2bf(float v) { return __float2bfloat16(v); }
__device__ __forceinline__ unsigned short bfbits(float f) {
    __hip_bfloat16 h = __float2bfloat16(f);
    return *reinterpret_cast<unsigned short*>(&h);
}

// unpack 8 consecutive bf16 (16B aligned) -> 8 floats
__device__ __forceinline__ void unpack_bf8(uint4 u, float* f) {
    f[0] = __uint_as_float(u.x << 16); f[1] = __uint_as_float(u.x & 0xFFFF0000u);
    f[2] = __uint_as_float(u.y << 16); f[3] = __uint_as_float(u.y & 0xFFFF0000u);
    f[4] = __uint_as_float(u.z << 16); f[5] = __uint_as_float(u.z & 0xFFFF0000u);
    f[6] = __uint_as_float(u.w << 16); f[7] = __uint_as_float(u.w & 0xFFFF0000u);
}

// VALU-only quad reduce: v + dpp_perm(v). CTRL 0xB1 = lanes[1,0,3,2] (xor1),
// 0x4E = lanes[2,3,0,1] (xor2). Avoids ds_swizzle + lgkmcnt on the score chain.
// CTRL must be a compile-time constant -> template parameter.
template<int CTRL>
__device__ __forceinline__ float dpp_add(float v) {
    int t = __builtin_amdgcn_update_dpp(0, __float_as_int(v), CTRL, 0xF, 0xF, true);
    return v + __int_as_float(t);
}

// async global->LDS, 16B per lane; LDS dest must be wave-uniform base (+lane*16 implicit)
__device__ __forceinline__ void load_lds16(const void* g, void* l) {
    __builtin_amdgcn_global_load_lds(
        (const __attribute__((address_space(1))) unsigned*)g,
        (__attribute__((address_space(3))) unsigned*)l, 16, 0, 0);
}

// Column permutation (16x4 transpose within each 64-col block):
//   gemm perm-col p  <->  logical col T(p) = (p&~63) + ((p&15)<<2) + ((p>>4)&3)
// Weights are built so gemm col p holds original col T(p); the packed epilogue then
// stores each lane's 4 nj-values (perm cols B+lh+16j) at contiguous logical cols
// B + lh*4 + j  ->  outputs land in ORIGINAL logical order (att/wt2 unchanged).

// ---------------- fused prep: cvt_x + 3 weight transposes + bias perms + zero ---------
#define PREP_X   3200000                    // N*256/4 float4 units
#define PREP_WQ  (768 * 256)
#define PREP_W1  (1024 * 256)
#define PREP_W2  (256 * 1024)
#define PREP_BQ  768
#define PREP_B1  1024
#define PREP_TOT (PREP_X + PREP_WQ + PREP_W1 + PREP_W2 + PREP_BQ + PREP_B1 + N_NODES)
__global__ void prep_kernel(const float* __restrict__ x, unsigned short* __restrict__ xb,
                            const float* __restrict__ wq, __hip_bfloat16* __restrict__ wtq,
                            const float* __restrict__ w1, __hip_bfloat16* __restrict__ wt1,
                            const float* __restrict__ w2, __hip_bfloat16* __restrict__ wt2,
                            const float* __restrict__ bq, float* __restrict__ bqp,
                            const float* __restrict__ b1, float* __restrict__ b1p,
                            unsigned* __restrict__ counts, unsigned* __restrict__ cursor) {
    int i = blockIdx.x * blockDim.x + threadIdx.x;
    if (i < PREP_X) {
        float4 v = reinterpret_cast<const float4*>(x)[i];
        ushort4 o;
        o.x = bfbits(v.x); o.y = bfbits(v.y); o.z = bfbits(v.z); o.w = bfbits(v.w);
        reinterpret_cast<ushort4*>(xb)[i] = o;
        return;
    }
    i -= PREP_X;
    if (i < PREP_WQ) {
        int n = i >> 8, k = i & 255;          // n = perm col in [0,768)
        int s = n >> 8, prel = n & 255;       // section 0=q,1=k,2=v
        int d = (prel & 192) + ((prel & 15) << 2) + ((prel >> 4) & 3);  // logical dim
        int co = (d >> 5) * 96 + s * 32 + (d & 31);                     // orig col
        wtq[i] = f2bf(wq[(size_t)k * 768 + co]);
        return;
    }
    i -= PREP_WQ;
    if (i < PREP_W1) {
        int n = i >> 8, k = i & 255;          // n = perm col in [0,1024)
        int f = (n & ~63) + ((n & 15) << 2) + ((n >> 4) & 3);
        wt1[i] = f2bf(w1[(size_t)k * 1024 + f]);
        return;
    }
    i -= PREP_W1;
    if (i < PREP_W2) {
        int n = i >> 10, k = i & 1023;        // unpermuted (hbuf is logical order)
        wt2[i] = f2bf(w2[(size_t)k * 256 + n]);
        return;
    }
    i -= PREP_W2;
    if (i < PREP_BQ) {
        int s = i >> 8, prel = i & 255;
        int d = (prel & 192) + ((prel & 15) << 2) + ((prel >> 4) & 3);
        bqp[i] = bq[(d >> 5) * 96 + s * 32 + (d & 31)];
        return;
    }
    i -= PREP_BQ;
    if (i < PREP_B1) {
        int f = (i & ~63) + ((i & 15) << 2) + ((i >> 4) & 3);
        b1p[i] = b1[f];
        return;
    }
    i -= PREP_B1;
    if (i < N_NODES) { counts[i] = 0u; cursor[i] = 0u; }
}

// ---------------- MFMA GEMM: out = A @ Wt^T + bias (perm cols, packed epilogue) ------
// A: MxK bf16 row-major. Wt: NxK bf16 row-major (perm-transposed weights).
// 128x128 tile, 256 threads = 4 waves (2x2 of 64x64), 16x16x32 bf16 MFMA, BK=32.
// 2-phase LDS double-buffer: STAGE(s+1) issued BEFORE compute(s), one barrier/step.
// XCD-aware bijective swizzle (m204) so same-A-row tiles share one XCD's L2.
// EPI==0 (qkv): perm col space [q:0-255][k:256-511][v:512-767]; tile is section-pure.
// EPI==1: relu + one ushort4 store per (mi,r) at out[gm*Ncols + B + lh*4].
template<bool RELU, int EPI>
__global__ __launch_bounds__(256)
void mfma_gemm(const __hip_bfloat16* __restrict__ A,
               const __hip_bfloat16* __restrict__ Wt,
               const float* __restrict__ bias,
               __hip_bfloat16* __restrict__ outp,
               __hip_bfloat16* __restrict__ qb,
               unsigned char* __restrict__ kv8,
               int M, int Ncols, int K) {
    __shared__ short Al[2][128 * 32];
    __shared__ short Bl[2][128 * 32];
    const int t = threadIdx.x;
    const int wave = t >> 6, lane = t & 63;

    // bijective XCD swizzle: contiguous wg runs per XCD -> same-row tiles co-located
    unsigned flat = blockIdx.y * gridDim.x + blockIdx.x;
    unsigned nwg = gridDim.x * gridDim.y;
    unsigned q8 = nwg >> 3, r8 = nwg & 7;
    unsigned xcd = flat & 7, pos = flat >> 3;
    unsigned wg = (xcd < r8) ? (xcd * (q8 + 1) + pos)
                             : (r8 * (q8 + 1) + (xcd - r8) * q8 + pos);
    const int m0 = (int)(wg / gridDim.x) * 128;
    const int n0 = (int)(wg % gridDim.x) * 128;

    const int wr = wave >> 1, wc = wave & 1;

    const int srow = lane >> 2;                        // row within chunk 0..15
    const int skp  = (lane & 3) ^ ((lane >> 3) & 3);   // swizzled global k-part
    const int c0 = wave * 2;
    int ar0 = m0 + c0 * 16 + srow;      if (ar0 >= M) ar0 = M - 1;
    int ar1 = m0 + c0 * 16 + 16 + srow; if (ar1 >= M) ar1 = M - 1;
    const __hip_bfloat16* ga0 = A + (size_t)ar0 * K + skp * 8;
    const __hip_bfloat16* ga1 = A + (size_t)ar1 * K + skp * 8;
    const __hip_bfloat16* gb0 = Wt + (size_t)(n0 + c0 * 16 + srow) * K + skp * 8;
    const __hip_bfloat16* gb1 = Wt + (size_t)(n0 + c0 * 16 + 16 + srow) * K + skp * 8;

    const int lh = lane & 15, q = lane >> 4;
    const int qs = q ^ ((lane >> 1) & 3);
    const short* fa0 = &Al[0][(wr * 64 + lh) * 32 + qs * 8];
    const short* fb0 = &Bl[0][(wc * 64 + lh) * 32 + qs * 8];
    const short* fa1 = &Al[1][(wr * 64 + lh) * 32 + qs * 8];
    const short* fb1 = &Bl[1][(wc * 64 + lh) * 32 + qs * 8];

    f32x4 acc[4][4] = {};

#define GSTAGE(B)                                    \
    load_lds16(ga0, &Al[B][c0 * 512]);               \
    load_lds16(ga1, &Al[B][c0 * 512 + 512]);         \
    load_lds16(gb0, &Bl[B][c0 * 512]);               \
    load_lds16(gb1, &Bl[B][c0 * 512 + 512]);         \
    ga0 += 32; ga1 += 32; gb0 += 32; gb1 += 32;

#define GSTEP(FA, FB)                                                       \
    {                                                                       \
        bf16x8 af[4], bfr[4];                                               \
        _Pragma("unroll")                                                   \
        for (int i = 0; i < 4; i++) {                                       \
            af[i]  = *reinterpret_cast<const bf16x8*>((FA) + i * 16 * 32);  \
            bfr[i] = *reinterpret_cast<const bf16x8*>((FB) + i * 16 * 32);  \
        }                                                                   \
        _Pragma("unroll")                                                   \
        for (int mi = 0; mi < 4; mi++)                                      \
            _Pragma("unroll")                                               \
            for (int nj = 0; nj < 4; nj++)                                  \
                acc[mi][nj] = __builtin_amdgcn_mfma_f32_16x16x32_bf16(      \
                    af[mi], bfr[nj], acc[mi][nj], 0, 0, 0);                 \
    }

    const int nsteps = K >> 5;          // 8 for K=256 (even)
    GSTAGE(0)
    __syncthreads();
    for (int s = 0; s < nsteps; s += 2) {
        if (s + 1 < nsteps) { GSTAGE(1) }
        GSTEP(fa0, fb0)
        __syncthreads();
        if (s + 2 < nsteps) { GSTAGE(0) }
        GSTEP(fa1, fb1)
        __syncthreads();
    }
#undef GSTAGE
#undef GSTEP

    // epilogue: C/D layout col = lane&15, row = (lane>>4)*4 + reg
    const int B = n0 + wc * 64;
    const int gnbase = B + lh;
    float bv[4];
#pragma unroll
    for (int nj = 0; nj < 4; nj++) bv[nj] = bias[gnbase + nj * 16];

    if (EPI == 0) {
        const int sec = B >> 8;                       // 0=q,1=k,2=v (block-uniform)
        const int c = ((B & 255) >> 6) * 16 + lh;     // chunk index [0,64)
#pragma unroll
        for (int mi = 0; mi < 4; mi++) {
            int gmb = m0 + wr * 64 + mi * 16 + q * 4;
#pragma unroll
            for (int r = 0; r < 4; r++) {
                int gm = gmb + r;
                if (gm >= M) continue;
                float v0 = acc[mi][0][r] + bv[0];
                float v1 = acc[mi][1][r] + bv[1];
                float v2 = acc[mi][2][r] + bv[2];
                float v3 = acc[mi][3][r] + bv[3];
                if (sec == 0) {
                    ushort4 o;
                    o.x = bfbits(v0); o.y = bfbits(v1); o.z = bfbits(v2); o.w = bfbits(v3);
                    *reinterpret_cast<ushort4*>(qb + (size_t)gm * 256 + c * 4) = o;
                } else {
                    unsigned u = (unsigned)__builtin_amdgcn_cvt_pk_fp8_f32(v0, v1, 0, false);
                    u = (unsigned)__builtin_amdgcn_cvt_pk_fp8_f32(v2, v3, (int)u, true);
                    *reinterpret_cast<unsigned*>(
                        kv8 + (size_t)gm * 512 + c * 8 + (sec == 1 ? 0 : 4)) = u;
                }
            }
        }
    } else {
        const int cb = B + lh * 4;                    // logical col base (T-perm)
#pragma unroll
        for (int mi = 0; mi < 4; mi++) {
            int gmb = m0 + wr * 64 + mi * 16 + q * 4;
#pragma unroll
            for (int r = 0; r < 4; r++) {
                int gm = gmb + r;
                if (gm >= M) continue;
                float v0 = acc[mi][0][r] + bv[0];
                float v1 = acc[mi][1][r] + bv[1];
                float v2 = acc[mi][2][r] + bv[2];
                float v3 = acc[mi][3][r] + bv[3];
                if (RELU) {
                    v0 = fmaxf(v0, 0.f); v1 = fmaxf(v1, 0.f);
                    v2 = fmaxf(v2, 0.f); v3 = fmaxf(v3, 0.f);
                }
                ushort4 o;
                o.x = bfbits(v0); o.y = bfbits(v1); o.z = bfbits(v2); o.w = bfbits(v3);
                *reinterpret_cast<ushort4*>(outp + (size_t)gm * Ncols + cb) = o;
            }
        }
    }
}

// ---------------- ffn2 + fused LN2: out = LN(hbuf @ wt2^T + b2 + xn) ------------------
// 64 x 256 tile, 512 threads = 8 waves (2x4 of 32x64), K=1024, BK=32,
// 2-phase double-buffered LDS, single __syncthreads per K-step.
__global__ __launch_bounds__(512)
void ffn2_ln_kernel(const __hip_bfloat16* __restrict__ A,    // M x 1024
                    const __hip_bfloat16* __restrict__ Wt,   // 256 x 1024
                    const float* __restrict__ bias,
                    const __hip_bfloat16* __restrict__ resid,// M x 256
                    const float* __restrict__ g, const float* __restrict__ bb,
                    float* __restrict__ out, int M) {
    __shared__ short LDS[2][(64 + 256) * 32];   // A at [0,2048), B at [2048,10240)
    const int t = threadIdx.x;
    const int wave = t >> 6, lane = t & 63;
    const int m0 = blockIdx.x * 64;
    const int wr = wave >> 2, wc = wave & 3;

    const int srow = lane >> 2;                        // row within chunk 0..15
    const int skp  = (lane & 3) ^ ((lane >> 3) & 3);   // swizzled global k-part

    const __hip_bfloat16* gsrc0; int loff0;
    const __hip_bfloat16* gsrc1; int loff1;
    const __hip_bfloat16* gsrc2; int loff2;
    {
#define STAGE_INIT(GS, LO, C)                                            \
        if ((C) < 4) {                                                   \
            int r_ = m0 + (C) * 16 + srow; if (r_ >= M) r_ = M - 1;      \
            GS = A + (size_t)r_ * 1024 + skp * 8;                        \
            LO = (C) * 512;                                              \
        } else {                                                         \
            GS = Wt + (size_t)(((C) - 4) * 16 + srow) * 1024 + skp * 8;  \
            LO = 2048 + ((C) - 4) * 512;                                 \
        }
        STAGE_INIT(gsrc0, loff0, wave)
        STAGE_INIT(gsrc1, loff1, wave + 8)
        int c2 = (wave < 4) ? wave + 16 : 16;
        STAGE_INIT(gsrc2, loff2, c2)
#undef STAGE_INIT
    }

    const int lh = lane & 15, q = lane >> 4;
    const int qs = q ^ ((lane >> 1) & 3);
    const short* fa0 = &LDS[0][(wr * 32 + lh) * 32 + qs * 8];
    const short* fb0 = &LDS[0][2048 + (wc * 64 + lh) * 32 + qs * 8];
    const short* fa1 = &LDS[1][(wr * 32 + lh) * 32 + qs * 8];
    const short* fb1 = &LDS[1][2048 + (wc * 64 + lh) * 32 + qs * 8];

    f32x4 acc[2][4] = {};

#define FFN2_STAGE(BUF)                                      \
    load_lds16(gsrc0, &LDS[BUF][loff0]);                     \
    load_lds16(gsrc1, &LDS[BUF][loff1]);                     \
    if (wave < 4) load_lds16(gsrc2, &LDS[BUF][loff2]);       \
    gsrc0 += 32; gsrc1 += 32; gsrc2 += 32;

#define FFN2_STEP(FA, FB)                                                   \
    {                                                                       \
        bf16x8 af[2], bfr[4];                                               \
        _Pragma("unroll")                                                   \
        for (int i = 0; i < 2; i++)                                         \
            af[i] = *reinterpret_cast<const bf16x8*>((FA) + i * 16 * 32);   \
        _Pragma("unroll")                                                   \
        for (int i = 0; i < 4; i++)                                         \
            bfr[i] = *reinterpret_cast<const bf16x8*>((FB) + i * 16 * 32);  \
        _Pragma("unroll")                                                   \
        for (int mi = 0; mi < 2; mi++)                                      \
            _Pragma("unroll")                                               \
            for (int nj = 0; nj < 4; nj++)                                  \
                acc[mi][nj] = __builtin_amdgcn_mfma_f32_16x16x32_bf16(      \
                    af[mi], bfr[nj], acc[mi][nj], 0, 0, 0);                 \
    }

    // prologue: stage step 0 into buf0
    FFN2_STAGE(0)
    __syncthreads();

    for (int s = 0; s < 32; s += 2) {
        FFN2_STAGE(1)                      // loads for step s+1 (always valid, s+1<=31)
        FFN2_STEP(fa0, fb0)                // compute step s
        __syncthreads();
        if (s < 30) { FFN2_STAGE(0) }      // loads for step s+2
        FFN2_STEP(fa1, fb1)                // compute step s+1
        __syncthreads();
    }
#undef FFN2_STAGE
#undef FFN2_STEP

    // ---- epilogue: v = acc + b2 + xn; per-row LN over 256 cols; write f32 ----
    const int colbase = wc * 64 + lh;   // + nj*16
    float bv[4], gv[4], bbv[4];
#pragma unroll
    for (int nj = 0; nj < 4; nj++) {
        bv[nj]  = bias[colbase + nj * 16];
        gv[nj]  = g[colbase + nj * 16];
        bbv[nj] = bb[colbase + nj * 16];
    }

    float ps[2][4], pq[2][4];
#pragma unroll
    for (int mi = 0; mi < 2; mi++) {
#pragma unroll
        for (int r = 0; r < 4; r++) {
            int gm = m0 + wr * 32 + mi * 16 + q * 4 + r;
            int rgm = (gm < M) ? gm : M - 1;
            float s = 0.f, s2 = 0.f;
#pragma unroll
            for (int nj = 0; nj < 4; nj++) {
                float v = acc[mi][nj][r] + bv[nj]
                        + bf2f(resid[(size_t)rgm * 256 + colbase + nj * 16]);
                acc[mi][nj][r] = v;
                s += v; s2 += v * v;
            }
            ps[mi][r] = s; pq[mi][r] = s2;
        }
    }
#pragma unroll
    for (int off = 1; off <= 8; off <<= 1) {
#pragma unroll
        for (int mi = 0; mi < 2; mi++)
#pragma unroll
            for (int r = 0; r < 4; r++) {
                ps[mi][r] += __shfl_xor(ps[mi][r], off);
                pq[mi][r] += __shfl_xor(pq[mi][r], off);
            }
    }
    // cross-wave (wc) merge via LDS (reuse buf0: 64 rows x 4 wc x 2 vals = 2 KB)
    float* rs = (float*)(&LDS[0][0]);   // [64][4]
    float* rq = rs + 256;
    if (lh == 0) {
#pragma unroll
        for (int mi = 0; mi < 2; mi++)
#pragma unroll
            for (int r = 0; r < 4; r++) {
                int m = wr * 32 + mi * 16 + q * 4 + r;
                rs[m * 4 + wc] = ps[mi][r];
                rq[m * 4 + wc] = pq[mi][r];
            }
    }
    __syncthreads();

#pragma unroll
    for (int mi = 0; mi < 2; mi++) {
#pragma unroll
        for (int r = 0; r < 4; r++) {
            int m = wr * 32 + mi * 16 + q * 4 + r;
            int gm = m0 + m;
            if (gm >= M) continue;
            float4 rsv = *reinterpret_cast<const float4*>(&rs[m * 4]);
            float4 rqv = *reinterpret_cast<const float4*>(&rq[m * 4]);
            float S  = (rsv.x + rsv.y) + (rsv.z + rsv.w);
            float S2 = (rqv.x + rqv.y) + (rqv.z + rqv.w);
            float mean = S * (1.f / (float)D_MODEL);
            float var  = S2 * (1.f / (float)D_MODEL) - mean * mean;
            float inv  = rsqrtf(var + LN_EPS);
#pragma unroll
            for (int nj = 0; nj < 4; nj++)
                out[(size_t)gm * 256 + colbase + nj * 16] =
                    (acc[mi][nj][r] - mean) * inv * gv[nj] + bbv[nj];
        }
    }
}

// ---------------- CSR build ----------------
__global__ void count_kernel(const int* __restrict__ rows, unsigned* __restrict__ counts) {
    int e = blockIdx.x * blockDim.x + threadIdx.x;
    if (e < E_EDGES) atomicAdd(&counts[rows[e]], 1u);
}

__global__ void scan_blk_kernel(const unsigned* __restrict__ counts,
                                unsigned* __restrict__ offs, unsigned* __restrict__ bsum) {
    __shared__ unsigned sh[256];
    int t = threadIdx.x;
    int i = blockIdx.x * 256 + t;
    unsigned v = (i < N_NODES) ? counts[i] : 0u;
    sh[t] = v;
    __syncthreads();
#pragma unroll
    for (int off = 1; off < 256; off <<= 1) {
        unsigned u = (t >= off) ? sh[t - off] : 0u;
        __syncthreads();
        sh[t] += u;
        __syncthreads();
    }
    if (i < N_NODES) offs[i] = sh[t] - v;
    if (t == 255) bsum[blockIdx.x] = sh[255];
}

__global__ void scan_top_kernel(const unsigned* __restrict__ bsum, unsigned* __restrict__ bpre) {
    __shared__ unsigned sh[256];
    int t = threadIdx.x;
    unsigned v = (t < NB_SCAN) ? bsum[t] : 0u;
    sh[t] = v;
    __syncthreads();
#pragma unroll
    for (int off = 1; off < 256; off <<= 1) {
        unsigned u = (t >= off) ? sh[t - off] : 0u;
        __syncthreads();
        sh[t] += u;
        __syncthreads();
    }
    if (t < NB_SCAN) bpre[t] = sh[t] - v;
    if (t == NB_SCAN - 1) bpre[NB_SCAN] = sh[t];
}

__global__ void scan_add_kernel(unsigned* __restrict__ offs, const unsigned* __restrict__ bpre) {
    int i = blockIdx.x * 256 + threadIdx.x;
    if (i < N_NODES) offs[i] += bpre[blockIdx.x];
    if (i == 0) offs[N_NODES] = bpre[NB_SCAN];
}

__global__ void scatter_kernel(const int* __restrict__ rows, const int* __restrict__ cols,
                               const unsigned* __restrict__ offsets, unsigned* __restrict__ cursor,
                               int* __restrict__ scol) {
    int e = blockIdx.x * blockDim.x + threadIdx.x;
    if (e >= E_EDGES) return;
    int r = rows[e];
    unsigned idx = atomicAdd(&cursor[r], 1u);
    scol[offsets[r] + idx] = cols[e];
}

// ---------------- attention (wave-per-node, PAIR-EDGE fp8 k/v) + fused LN1 -----------
// Block = 2 nodes, one wave each. The wave's two 32-lane halves process TWO edges
// simultaneously: half-lane hl owns dims 8hl..8hl+7 (16B of the 512B kv row).
// 4 lanes per head -> 2-level DPP quad-perm reduce (pure VALU, no ds_swizzle).
// 8-edge main batch: 4 dwordx4 gathers in flight; scol byte-offsets (col<<9)
// prefetched one batch ahead -> 32-bit saddr addressing in the loads.
// Residual comes from xb (bf16) -> 25.6 MB fetch instead of 51.2 MB f32.
// Single-pass exp (softmax shift-invariant => identical to reference).
__global__ __launch_bounds__(128)
void att_agg_kernel(const __hip_bfloat16* __restrict__ qb,
                    const unsigned char* __restrict__ kv8,
                    const unsigned* __restrict__ offsets,
                    const int* __restrict__ scol,
                    const __hip_bfloat16* __restrict__ xres,
                    const float* __restrict__ g, const float* __restrict__ bb,
                    __hip_bfloat16* __restrict__ xn) {
    int n = blockIdx.x * 2 + (threadIdx.x >> 6);
    if (n >= N_NODES) return;
    const int lam = threadIdx.x & 63;
    const int hl  = lam & 31;          // dims 8hl..8hl+7
    const int sel = lam >> 5;          // which edge of the pair
    const unsigned hlb = hl * 16;      // byte offset within kv row
    unsigned beg = offsets[n], end = offsets[n + 1];

    float qv[8];
    {
        uint4 u = *reinterpret_cast<const uint4*>(qb + (size_t)n * 256 + hl * 8);
        unpack_bf8(u, qv);
#pragma unroll
        for (int i = 0; i < 8; i++) qv[i] *= ATT_SCALE;
    }

    float acc[8] = {};
    float l = 0.f;

    // w.x = k[8hl..8hl+3], w.y = v[8hl..8hl+3], w.z = k[8hl+4..], w.w = v[8hl+4..]
#define PAIR_BODY(W, VMUL)                                                      \
    {                                                                           \
        auto k01 = __builtin_amdgcn_cvt_pk_f32_fp8((int)(W).x, false);          \
        auto k23 = __builtin_amdgcn_cvt_pk_f32_fp8((int)(W).x, true);           \
        auto k45 = __builtin_amdgcn_cvt_pk_f32_fp8((int)(W).z, false);          \
        auto k67 = __builtin_amdgcn_cvt_pk_f32_fp8((int)(W).z, true);           \
        float sv = qv[0] * k01[0] + qv[1] * k01[1] + qv[2] * k23[0]             \
                 + qv[3] * k23[1] + qv[4] * k45[0] + qv[5] * k45[1]             \
                 + qv[6] * k67[0] + qv[7] * k67[1];                             \
        sv = dpp_add<0xB1>(sv);   /* xor1 within quad */                        \
        sv = dpp_add<0x4E>(sv);   /* xor2 within quad */                        \
        float pv = __expf(sv) * (VMUL);                                         \
        l += pv;                                                                \
        auto v01 = __builtin_amdgcn_cvt_pk_f32_fp8((int)(W).y, false);          \
        auto v23 = __builtin_amdgcn_cvt_pk_f32_fp8((int)(W).y, true);           \
        auto v45 = __builtin_amdgcn_cvt_pk_f32_fp8((int)(W).w, false);          \
        auto v67 = __builtin_amdgcn_cvt_pk_f32_fp8((int)(W).w, true);           \
        acc[0] += pv * v01[0]; acc[1] += pv * v01[1];                           \
        acc[2] += pv * v23[0]; acc[3] += pv * v23[1];                           \
        acc[4] += pv * v45[0]; acc[5] += pv * v45[1];                           \
        acc[6] += pv * v67[0]; acc[7] += pv * v67[1];                           \
    }

    unsigned e = beg;
    // ---- 8-edge pipelined main loop: 4 gathers in flight, offsets one batch ahead ----
    unsigned oA = 0, oB = 0, oC = 0, oD = 0;
    if (e + 8 <= end) {
        oA = ((unsigned)scol[e + sel])     << 9;
        oB = ((unsigned)scol[e + 2 + sel]) << 9;
        oC = ((unsigned)scol[e + 4 + sel]) << 9;
        oD = ((unsigned)scol[e + 6 + sel]) << 9;
    }
    while (e + 8 <= end) {
        uint4 wa = *reinterpret_cast<const uint4*>(kv8 + (oA + hlb));
        uint4 wb = *reinterpret_cast<const uint4*>(kv8 + (oB + hlb));
        uint4 wc = *reinterpret_cast<const uint4*>(kv8 + (oC + hlb));
        uint4 wd = *reinterpret_cast<const uint4*>(kv8 + (oD + hlb));
        e += 8;
        if (e + 8 <= end) {                 // prefetch next batch's byte offsets
            oA = ((unsigned)scol[e + sel])     << 9;
            oB = ((unsigned)scol[e + 2 + sel]) << 9;
            oC = ((unsigned)scol[e + 4 + sel]) << 9;
            oD = ((unsigned)scol[e + 6 + sel]) << 9;
        }
        PAIR_BODY(wa, 1.0f)
        PAIR_BODY(wb, 1.0f)
        PAIR_BODY(wc, 1.0f)
        PAIR_BODY(wd, 1.0f)
    }
    // ---- tails: 2-edge pairs, then odd ----
    for (; e + 2 <= end; e += 2) {
        unsigned o0 = ((unsigned)scol[e + sel]) << 9;
        uint4 wa = *reinterpret_cast<const uint4*>(kv8 + (o0 + hlb));
        PAIR_BODY(wa, 1.0f)
    }
    if (e < end) {                           // odd tail: upper half masked to 0
        unsigned o0 = ((unsigned)scol[e]) << 9;
        uint4 wa = *reinterpret_cast<const uint4*>(kv8 + (o0 + hlb));
        PAIR_BODY(wa, sel ? 0.0f : 1.0f)
    }
#undef PAIR_BODY

    // merge the two halves (different edges, same dims)
    l += __shfl_xor(l, 32);
#pragma unroll
    for (int i = 0; i < 8; i++) acc[i] += __shfl_xor(acc[i], 32);

    float inv_l = (l > 0.f) ? 1.f / l : 0.f;

    float tv[8];
    {
        float xv[8];
        uint4 u = *reinterpret_cast<const uint4*>(xres + (size_t)n * D_MODEL + hl * 8);
        unpack_bf8(u, xv);
#pragma unroll
        for (int i = 0; i < 8; i++) tv[i] = acc[i] * inv_l + xv[i];
    }

    float s = 0.f, s2 = 0.f;
#pragma unroll
    for (int i = 0; i < 8; i++) { s += tv[i]; s2 += tv[i] * tv[i]; }
#pragma unroll
    for (int off = 1; off <= 16; off <<= 1) {   // sum within each 32-lane half
        s  += __shfl_xor(s, off);
        s2 += __shfl_xor(s2, off);
    }
    float mean = s * (1.f / (float)D_MODEL);
    float var  = s2 * (1.f / (float)D_MODEL) - mean * mean;
    float inv  = rsqrtf(var + LN_EPS);

    if (sel == 0) {                          // lower half writes the full row
        const float4* gp = reinterpret_cast<const float4*>(g);
        const float4* bp = reinterpret_cast<const float4*>(bb);
        float4 g0 = gp[hl * 2], g1 = gp[hl * 2 + 1];
        float4 b0 = bp[hl * 2], b1 = bp[hl * 2 + 1];
        float gv[8] = {g0.x, g0.y, g0.z, g0.w, g1.x, g1.y, g1.z, g1.w};
        float bv[8] = {b0.x, b0.y, b0.z, b0.w, b1.x, b1.y, b1.z, b1.w};
        u16x8 o;
#pragma unroll
        for (int i = 0; i < 8; i++)
            o[i] = bfbits((tv[i] - mean) * inv * gv[i] + bv[i]);
        *reinterpret_cast<u16x8*>(xn + (size_t)n * D_MODEL + hl * 8) = o;
    }
}

extern "C" void kernel_launch(void* const* d_in, const int* in_sizes, int n_in,
                              void* d_out, int out_size, void* d_ws, size_t ws_size,
                              hipStream_t stream) {
    const float* x     = (const float*)d_in[0];
    const int*   ei    = (const int*)d_in[1];
    const float* w_qkv = (const float*)d_in[2];
    const float* b_qkv = (const float*)d_in[3];
    const float* ln1_g = (const float*)d_in[4];
    const float* ln1_b = (const float*)d_in[5];
    const float* ln2_g = (const float*)d_in[6];
    const float* ln2_b = (const float*)d_in[7];
    const float* w1    = (const float*)d_in[8];
    const float* b1    = (const float*)d_in[9];
    const float* w2    = (const float*)d_in[10];
    const float* b2    = (const float*)d_in[11];
    const int* rows = ei;
    const int* cols = ei + E_EDGES;

    // workspace layout (bytes), total < 179,200,000 (known-good footprint):
    //   [0,          25,600,000)  qb  bf16 N*256 } dead after att_agg;
    //   [25,600,000, 51,200,000)  kv8 fp8  N*512 } region [0,102.4e6) reused
    //                                            } as hbuf bf16 N*1024
    //   [102,400,000,128,000,000) xb bf16 N*256 (live through att_agg: residual src)
    //   [128,000,000,128,393,216) wtq bf16 768x256 (perm cols)
    //   [128,400,000,128,924,288) wt1 bf16 1024x256 (perm cols)
    //   [129,000,000,129,524,288) wt2 bf16 256x1024
    //   [129,600,000,129,800,000) counts u32 N
    //   [129,800,000,130,000,004) offsets u32 N+1
    //   [130,000,008,130,200,008) cursor u32 N
    //   [130,200,008,133,400,008) scol i32 E
    //   [133,400,008,133,401,032) bsum u32 256
    //   [133,401,032,133,402,060) bpre u32 257
    //   [133,500,000,133,503,072) bqp f32 768 (perm qkv bias)
    //   [133,510,000,133,514,096) b1p f32 1024 (perm ffn1 bias)
    //   [153,600,000,179,200,000) xn bf16 N*256
    char* ws = (char*)d_ws;
    __hip_bfloat16* qb      = (__hip_bfloat16*)(ws + 0);
    unsigned char*  kv8     = (unsigned char*)(ws + 25600000);
    __hip_bfloat16* hbuf    = (__hip_bfloat16*)(ws + 0);
    __hip_bfloat16* xb      = (__hip_bfloat16*)(ws + 102400000);
    __hip_bfloat16* wtq     = (__hip_bfloat16*)(ws + 128000000);
    __hip_bfloat16* wt1     = (__hip_bfloat16*)(ws + 128400000);
    __hip_bfloat16* wt2     = (__hip_bfloat16*)(ws + 129000000);
    unsigned*       counts  = (unsigned*)(ws + 129600000);
    unsigned*       offsets = (unsigned*)(ws + 129800000);
    unsigned*       cursor  = (unsigned*)(ws + 130000008);
    int*            scol    = (int*)(ws + 130200008);
    unsigned*       bsum    = (unsigned*)(ws + 133400008);
    unsigned*       bpre    = (unsigned*)(ws + 133401032);
    float*          bqp     = (float*)(ws + 133500000);
    float*          b1p     = (float*)(ws + 133510000);
    __hip_bfloat16* xn      = (__hip_bfloat16*)(ws + 153600000);

    const int nbM = (N_NODES + 127) / 128;   // 391

    // fused prep: x->bf16, perm weights/biases, zero counts/cursor
    prep_kernel<<<(PREP_TOT + 255) / 256, 256, 0, stream>>>(
        x, (unsigned short*)xb, w_qkv, wtq, w1, wt1, w2, wt2,
        b_qkv, bqp, b1, b1p, counts, cursor);

    // q(bf16)/kv(fp8) = split(xb @ wtq^T + bqp), packed epilogue, dbuf pipeline
    mfma_gemm<false, 0><<<dim3(768 / 128, nbM), 256, 0, stream>>>(
        xb, wtq, bqp, nullptr, qb, kv8, N_NODES, 768, D_MODEL);

    // CSR build (hierarchical scan)
    count_kernel<<<(E_EDGES + 255) / 256, 256, 0, stream>>>(rows, counts);
    scan_blk_kernel<<<NB_SCAN, 256, 0, stream>>>(counts, offsets, bsum);
    scan_top_kernel<<<1, 256, 0, stream>>>(bsum, bpre);
    scan_add_kernel<<<NB_SCAN, 256, 0, stream>>>(offsets, bpre);
    scatter_kernel<<<(E_EDGES + 255) / 256, 256, 0, stream>>>(rows, cols, offsets, cursor, scol);

    // attention (pair-edge, 8-edge pipelined, DPP reduce, bf16 residual) + LN1 -> xn
    att_agg_kernel<<<(N_NODES + 1) / 2, 128, 0, stream>>>(qb, kv8, offsets, scol,
                                                          xb, ln1_g, ln1_b, xn);

    // hbuf = relu(xn @ wt1^T + b1p), packed epilogue, dbuf pipeline
    mfma_gemm<true, 1><<<dim3(F_FFN / 128, nbM), 256, 0, stream>>>(
        xn, wt1, b1p, hbuf, nullptr, nullptr, N_NODES, F_FFN, D_MODEL);

    // d_out = LN2(hbuf @ wt2^T + b2 + xn)   (fused, f32 out; dbuf pipeline)
    ffn2_ln_kernel<<<(N_NODES + 63) / 64, 512, 0, stream>>>(hbuf, wt2, b2, xn, ln2_g, ln2_b,
                                                            (float*)d_out, N_NODES);
}

// Round 7
// 409.206 us; speedup vs baseline: 1.1578x; 1.0036x over previous
//
#include <hip/hip_runtime.h>
#include <hip/hip_bf16.h>

#define N_NODES 50000
#define E_EDGES 800000
#define D_MODEL 256
#define H_HEADS 8
#define HDIM    32
#define F_FFN   1024
#define ATT_SCALE 0.0625f   // 256^-0.5
#define LN_EPS  1e-5f
#define NB_SCAN 196         // ceil(N_NODES/256)

typedef __attribute__((ext_vector_type(8))) short bf16x8;
typedef __attribute__((ext_vector_type(8))) unsigned short u16x8;
typedef __attribute__((ext_vector_type(4))) float f32x4;

__device__ __forceinline__ float bf2f(__hip_bfloat16 v) { return __bfloat162float(v); }
__device__ __forceinline__ __hip_bfloat16 f2bf(float v) { return __float2bfloat16(v); }
__device__ __forceinline__ unsigned short bfbits(float f) {
    __hip_bfloat16 h = __float2bfloat16(f);
    return *reinterpret_cast<unsigned short*>(&h);
}

// unpack 8 consecutive bf16 (16B aligned) -> 8 floats
__device__ __forceinline__ void unpack_bf8(uint4 u, float* f) {
    f[0] = __uint_as_float(u.x << 16); f[1] = __uint_as_float(u.x & 0xFFFF0000u);
    f[2] = __uint_as_float(u.y << 16); f[3] = __uint_as_float(u.y & 0xFFFF0000u);
    f[4] = __uint_as_float(u.z << 16); f[5] = __uint_as_float(u.z & 0xFFFF0000u);
    f[6] = __uint_as_float(u.w << 16); f[7] = __uint_as_float(u.w & 0xFFFF0000u);
}

// VALU-only quad reduce: v + dpp_perm(v). CTRL 0xB1 = lanes[1,0,3,2] (xor1),
// 0x4E = lanes[2,3,0,1] (xor2). CTRL must be a compile-time constant.
template<int CTRL>
__device__ __forceinline__ float dpp_add(float v) {
    int t = __builtin_amdgcn_update_dpp(0, __float_as_int(v), CTRL, 0xF, 0xF, true);
    return v + __int_as_float(t);
}

// async global->LDS, 16B per lane; LDS dest must be wave-uniform base (+lane*16 implicit)
__device__ __forceinline__ void load_lds16(const void* g, void* l) {
    __builtin_amdgcn_global_load_lds(
        (const __attribute__((address_space(1))) unsigned*)g,
        (__attribute__((address_space(3))) unsigned*)l, 16, 0, 0);
}

// Counted-vmcnt pipeline primitives (T4): waits/barriers without the compiler's
// full vmcnt(0) drain. "memory" clobber orders surrounding memory ops at IR level;
// sched_barrier(0) pins the MIR schedule (rule #18).
#define WAITV(N) asm volatile("s_waitcnt vmcnt(" #N ")" ::: "memory")
#define SBAR()   { __builtin_amdgcn_sched_barrier(0); __builtin_amdgcn_s_barrier(); \
                   __builtin_amdgcn_sched_barrier(0); }

// Column permutation (16x4 transpose within each 64-col block):
//   gemm perm-col p  <->  logical col T(p) = (p&~63) + ((p&15)<<2) + ((p>>4)&3)
// Weights are built so gemm col p holds original col T(p); the packed epilogue then
// stores each lane's 4 nj-values at contiguous logical cols -> outputs land in
// ORIGINAL logical order (att/wt2 unchanged).

// ---------------- fused prep: cvt_x + 3 weight transposes + bias perms + zero ---------
#define PREP_X   3200000                    // N*256/4 float4 units
#define PREP_WQ  (768 * 256)
#define PREP_W1  (1024 * 256)
#define PREP_W2  (256 * 1024)
#define PREP_BQ  768
#define PREP_B1  1024
#define PREP_TOT (PREP_X + PREP_WQ + PREP_W1 + PREP_W2 + PREP_BQ + PREP_B1 + N_NODES)
__global__ void prep_kernel(const float* __restrict__ x, unsigned short* __restrict__ xb,
                            const float* __restrict__ wq, __hip_bfloat16* __restrict__ wtq,
                            const float* __restrict__ w1, __hip_bfloat16* __restrict__ wt1,
                            const float* __restrict__ w2, __hip_bfloat16* __restrict__ wt2,
                            const float* __restrict__ bq, float* __restrict__ bqp,
                            const float* __restrict__ b1, float* __restrict__ b1p,
                            unsigned* __restrict__ counts, unsigned* __restrict__ cursor) {
    int i = blockIdx.x * blockDim.x + threadIdx.x;
    if (i < PREP_X) {
        float4 v = reinterpret_cast<const float4*>(x)[i];
        ushort4 o;
        o.x = bfbits(v.x); o.y = bfbits(v.y); o.z = bfbits(v.z); o.w = bfbits(v.w);
        reinterpret_cast<ushort4*>(xb)[i] = o;
        return;
    }
    i -= PREP_X;
    if (i < PREP_WQ) {
        int n = i >> 8, k = i & 255;          // n = perm col in [0,768)
        int s = n >> 8, prel = n & 255;       // section 0=q,1=k,2=v
        int d = (prel & 192) + ((prel & 15) << 2) + ((prel >> 4) & 3);  // logical dim
        int co = (d >> 5) * 96 + s * 32 + (d & 31);                     // orig col
        wtq[i] = f2bf(wq[(size_t)k * 768 + co]);
        return;
    }
    i -= PREP_WQ;
    if (i < PREP_W1) {
        int n = i >> 8, k = i & 255;          // n = perm col in [0,1024)
        int f = (n & ~63) + ((n & 15) << 2) + ((n >> 4) & 3);
        wt1[i] = f2bf(w1[(size_t)k * 1024 + f]);
        return;
    }
    i -= PREP_W1;
    if (i < PREP_W2) {
        int n = i >> 10, k = i & 1023;        // unpermuted (hbuf is logical order)
        wt2[i] = f2bf(w2[(size_t)k * 256 + n]);
        return;
    }
    i -= PREP_W2;
    if (i < PREP_BQ) {
        int s = i >> 8, prel = i & 255;
        int d = (prel & 192) + ((prel & 15) << 2) + ((prel >> 4) & 3);
        bqp[i] = bq[(d >> 5) * 96 + s * 32 + (d & 31)];
        return;
    }
    i -= PREP_BQ;
    if (i < PREP_B1) {
        int f = (i & ~63) + ((i & 15) << 2) + ((i >> 4) & 3);
        b1p[i] = b1[f];
        return;
    }
    i -= PREP_B1;
    if (i < N_NODES) { counts[i] = 0u; cursor[i] = 0u; }
}

// ---------------- MFMA GEMM: out = A @ Wt^T + bias (perm cols, packed epilogue) ------
// 128x128 tile, 256 threads = 4 waves (2x2 of 64x64), 16x16x32 bf16 MFMA, BK=32.
// 3-buffer counted-vmcnt pipeline (T4), ONE barrier per K-step, loads 2 steps deep:
//   step s: { wait vmcnt(4|0); s_barrier; issue G(s+2)->buf((s+2)%3); compute buf(s%3) }
// Race-free: at the issue point all waves passed barrier_s => finished compute(s-1),
// the last reader of buf((s+2)%3); vmcnt(4) retires G(s) before the barrier.
// XCD-aware bijective swizzle (m204). EPI==0: qkv split epilogue; EPI==1: relu+bf16.
template<bool RELU, int EPI, int KT>
__global__ __launch_bounds__(256)
void mfma_gemm(const __hip_bfloat16* __restrict__ A,
               const __hip_bfloat16* __restrict__ Wt,
               const float* __restrict__ bias,
               __hip_bfloat16* __restrict__ outp,
               __hip_bfloat16* __restrict__ qb,
               unsigned char* __restrict__ kv8,
               int M, int Ncols) {
    __shared__ short Al[3][128 * 32];
    __shared__ short Bl[3][128 * 32];
    const int t = threadIdx.x;
    const int wave = t >> 6, lane = t & 63;

    // bijective XCD swizzle: contiguous wg runs per XCD -> same-row tiles co-located
    unsigned flat = blockIdx.y * gridDim.x + blockIdx.x;
    unsigned nwg = gridDim.x * gridDim.y;
    unsigned q8 = nwg >> 3, r8 = nwg & 7;
    unsigned xcd = flat & 7, pos = flat >> 3;
    unsigned wg = (xcd < r8) ? (xcd * (q8 + 1) + pos)
                             : (r8 * (q8 + 1) + (xcd - r8) * q8 + pos);
    const int m0 = (int)(wg / gridDim.x) * 128;
    const int n0 = (int)(wg % gridDim.x) * 128;

    const int wr = wave >> 1, wc = wave & 1;

    const int srow = lane >> 2;                        // row within chunk 0..15
    const int skp  = (lane & 3) ^ ((lane >> 3) & 3);   // swizzled global k-part
    const int c0 = wave * 2;
    int ar0 = m0 + c0 * 16 + srow;      if (ar0 >= M) ar0 = M - 1;
    int ar1 = m0 + c0 * 16 + 16 + srow; if (ar1 >= M) ar1 = M - 1;
    const __hip_bfloat16* ga0 = A + (size_t)ar0 * KT + skp * 8;
    const __hip_bfloat16* ga1 = A + (size_t)ar1 * KT + skp * 8;
    const __hip_bfloat16* gb0 = Wt + (size_t)(n0 + c0 * 16 + srow) * KT + skp * 8;
    const __hip_bfloat16* gb1 = Wt + (size_t)(n0 + c0 * 16 + 16 + srow) * KT + skp * 8;

    const int lh = lane & 15, q = lane >> 4;
    const int qs = q ^ ((lane >> 1) & 3);
    const short* faB = &Al[0][(wr * 64 + lh) * 32 + qs * 8];
    const short* fbB = &Bl[0][(wc * 64 + lh) * 32 + qs * 8];

    f32x4 acc[4][4] = {};

#define GSTAGE(B)                                    \
    load_lds16(ga0, &Al[B][c0 * 512]);               \
    load_lds16(ga1, &Al[B][c0 * 512 + 512]);         \
    load_lds16(gb0, &Bl[B][c0 * 512]);               \
    load_lds16(gb1, &Bl[B][c0 * 512 + 512]);         \
    ga0 += 32; ga1 += 32; gb0 += 32; gb1 += 32;

#define GSTEP(FA, FB)                                                       \
    {                                                                       \
        bf16x8 af[4], bfr[4];                                               \
        _Pragma("unroll")                                                   \
        for (int i = 0; i < 4; i++) {                                       \
            af[i]  = *reinterpret_cast<const bf16x8*>((FA) + i * 16 * 32);  \
            bfr[i] = *reinterpret_cast<const bf16x8*>((FB) + i * 16 * 32);  \
        }                                                                   \
        _Pragma("unroll")                                                   \
        for (int mi = 0; mi < 4; mi++)                                      \
            _Pragma("unroll")                                               \
            for (int nj = 0; nj < 4; nj++)                                  \
                acc[mi][nj] = __builtin_amdgcn_mfma_f32_16x16x32_bf16(      \
                    af[mi], bfr[nj], acc[mi][nj], 0, 0, 0);                 \
    }

    constexpr int ns = KT >> 5;         // 8 for K=256
    GSTAGE(0)
    GSTAGE(1)
#pragma unroll
    for (int s = 0; s < ns; ++s) {
        if (s < ns - 1) { WAITV(4); } else { WAITV(0); }
        SBAR();
        if (s + 2 < ns) {
            switch ((s + 2) % 3) {
                case 0: { GSTAGE(0) } break;
                case 1: { GSTAGE(1) } break;
                default: { GSTAGE(2) } break;
            }
        }
        const short* fa = faB + (s % 3) * 4096;
        const short* fb = fbB + (s % 3) * 4096;
        GSTEP(fa, fb)
    }
#undef GSTAGE
#undef GSTEP

    // epilogue: C/D layout col = lane&15, row = (lane>>4)*4 + reg
    const int B = n0 + wc * 64;
    const int gnbase = B + lh;
    float bv[4];
#pragma unroll
    for (int nj = 0; nj < 4; nj++) bv[nj] = bias[gnbase + nj * 16];

    if (EPI == 0) {
        const int sec = B >> 8;                       // 0=q,1=k,2=v (block-uniform)
        const int c = ((B & 255) >> 6) * 16 + lh;     // chunk index [0,64)
#pragma unroll
        for (int mi = 0; mi < 4; mi++) {
            int gmb = m0 + wr * 64 + mi * 16 + q * 4;
#pragma unroll
            for (int r = 0; r < 4; r++) {
                int gm = gmb + r;
                if (gm >= M) continue;
                float v0 = acc[mi][0][r] + bv[0];
                float v1 = acc[mi][1][r] + bv[1];
                float v2 = acc[mi][2][r] + bv[2];
                float v3 = acc[mi][3][r] + bv[3];
                if (sec == 0) {
                    ushort4 o;
                    o.x = bfbits(v0); o.y = bfbits(v1); o.z = bfbits(v2); o.w = bfbits(v3);
                    *reinterpret_cast<ushort4*>(qb + (size_t)gm * 256 + c * 4) = o;
                } else {
                    unsigned u = (unsigned)__builtin_amdgcn_cvt_pk_fp8_f32(v0, v1, 0, false);
                    u = (unsigned)__builtin_amdgcn_cvt_pk_fp8_f32(v2, v3, (int)u, true);
                    *reinterpret_cast<unsigned*>(
                        kv8 + (size_t)gm * 512 + c * 8 + (sec == 1 ? 0 : 4)) = u;
                }
            }
        }
    } else {
        const int cb = B + lh * 4;                    // logical col base (T-perm)
#pragma unroll
        for (int mi = 0; mi < 4; mi++) {
            int gmb = m0 + wr * 64 + mi * 16 + q * 4;
#pragma unroll
            for (int r = 0; r < 4; r++) {
                int gm = gmb + r;
                if (gm >= M) continue;
                float v0 = acc[mi][0][r] + bv[0];
                float v1 = acc[mi][1][r] + bv[1];
                float v2 = acc[mi][2][r] + bv[2];
                float v3 = acc[mi][3][r] + bv[3];
                if (RELU) {
                    v0 = fmaxf(v0, 0.f); v1 = fmaxf(v1, 0.f);
                    v2 = fmaxf(v2, 0.f); v3 = fmaxf(v3, 0.f);
                }
                ushort4 o;
                o.x = bfbits(v0); o.y = bfbits(v1); o.z = bfbits(v2); o.w = bfbits(v3);
                *reinterpret_cast<ushort4*>(outp + (size_t)gm * Ncols + cb) = o;
            }
        }
    }
}

// ---------------- ffn2 + fused LN2: out = LN(hbuf @ wt2^T + b2 + xn) ------------------
// 64 x 256 tile, 512 threads = 8 waves (2x4 of 32x64), K=1024, BK=32.
// 3-buffer counted-vmcnt pipeline (same schedule as mfma_gemm; per-wave load count
// NL = 3 for waves 0-3, 2 for waves 4-7 -> per-wave vmcnt immediates).
__global__ __launch_bounds__(512)
void ffn2_ln_kernel(const __hip_bfloat16* __restrict__ A,    // M x 1024
                    const __hip_bfloat16* __restrict__ Wt,   // 256 x 1024
                    const float* __restrict__ bias,
                    const __hip_bfloat16* __restrict__ resid,// M x 256
                    const float* __restrict__ g, const float* __restrict__ bb,
                    float* __restrict__ out, int M) {
    __shared__ short LDS[3][(64 + 256) * 32];   // A at [0,2048), B at [2048,10240)
    const int t = threadIdx.x;
    const int wave = t >> 6, lane = t & 63;
    const int m0 = blockIdx.x * 64;
    const int wr = wave >> 2, wc = wave & 3;

    const int srow = lane >> 2;                        // row within chunk 0..15
    const int skp  = (lane & 3) ^ ((lane >> 3) & 3);   // swizzled global k-part

    const __hip_bfloat16* gsrc0; int loff0;
    const __hip_bfloat16* gsrc1; int loff1;
    const __hip_bfloat16* gsrc2; int loff2;
    {
#define STAGE_INIT(GS, LO, C)                                            \
        if ((C) < 4) {                                                   \
            int r_ = m0 + (C) * 16 + srow; if (r_ >= M) r_ = M - 1;      \
            GS = A + (size_t)r_ * 1024 + skp * 8;                        \
            LO = (C) * 512;                                              \
        } else {                                                         \
            GS = Wt + (size_t)(((C) - 4) * 16 + srow) * 1024 + skp * 8;  \
            LO = 2048 + ((C) - 4) * 512;                                 \
        }
        STAGE_INIT(gsrc0, loff0, wave)
        STAGE_INIT(gsrc1, loff1, wave + 8)
        int c2 = (wave < 4) ? wave + 16 : 16;
        STAGE_INIT(gsrc2, loff2, c2)
#undef STAGE_INIT
    }

    const int lh = lane & 15, q = lane >> 4;
    const int qs = q ^ ((lane >> 1) & 3);
    const short* faB = &LDS[0][(wr * 32 + lh) * 32 + qs * 8];
    const short* fbB = &LDS[0][2048 + (wc * 64 + lh) * 32 + qs * 8];

    f32x4 acc[2][4] = {};

#define FFN2_STAGE(BUF)                                      \
    load_lds16(gsrc0, &LDS[BUF][loff0]);                     \
    load_lds16(gsrc1, &LDS[BUF][loff1]);                     \
    if (wave < 4) load_lds16(gsrc2, &LDS[BUF][loff2]);       \
    gsrc0 += 32; gsrc1 += 32; gsrc2 += 32;

#define FFN2_STEP(FA, FB)                                                   \
    {                                                                       \
        bf16x8 af[2], bfr[4];                                               \
        _Pragma("unroll")                                                   \
        for (int i = 0; i < 2; i++)                                         \
            af[i] = *reinterpret_cast<const bf16x8*>((FA) + i * 16 * 32);   \
        _Pragma("unroll")                                                   \
        for (int i = 0; i < 4; i++)                                         \
            bfr[i] = *reinterpret_cast<const bf16x8*>((FB) + i * 16 * 32);  \
        _Pragma("unroll")                                                   \
        for (int mi = 0; mi < 2; mi++)                                      \
            _Pragma("unroll")                                               \
            for (int nj = 0; nj < 4; nj++)                                  \
                acc[mi][nj] = __builtin_amdgcn_mfma_f32_16x16x32_bf16(      \
                    af[mi], bfr[nj], acc[mi][nj], 0, 0, 0);                 \
    }

    FFN2_STAGE(0)
    FFN2_STAGE(1)
#pragma unroll
    for (int s = 0; s < 32; ++s) {
        if (s < 31) {
            if (wave < 4) { WAITV(3); } else { WAITV(2); }
        } else {
            WAITV(0);
        }
        SBAR();
        if (s + 2 < 32) {
            switch ((s + 2) % 3) {
                case 0: { FFN2_STAGE(0) } break;
                case 1: { FFN2_STAGE(1) } break;
                default: { FFN2_STAGE(2) } break;
            }
        }
        const short* fa = faB + (s % 3) * 10240;
        const short* fb = fbB + (s % 3) * 10240;
        FFN2_STEP(fa, fb)
    }
    WAITV(0);
    SBAR();                                  // LDS reused below for LN merge
#undef FFN2_STAGE
#undef FFN2_STEP

    // ---- epilogue: v = acc + b2 + xn; per-row LN over 256 cols; write f32 ----
    const int colbase = wc * 64 + lh;   // + nj*16
    float bv[4], gv[4], bbv[4];
#pragma unroll
    for (int nj = 0; nj < 4; nj++) {
        bv[nj]  = bias[colbase + nj * 16];
        gv[nj]  = g[colbase + nj * 16];
        bbv[nj] = bb[colbase + nj * 16];
    }

    float ps[2][4], pq[2][4];
#pragma unroll
    for (int mi = 0; mi < 2; mi++) {
#pragma unroll
        for (int r = 0; r < 4; r++) {
            int gm = m0 + wr * 32 + mi * 16 + q * 4 + r;
            int rgm = (gm < M) ? gm : M - 1;
            float s = 0.f, s2 = 0.f;
#pragma unroll
            for (int nj = 0; nj < 4; nj++) {
                float v = acc[mi][nj][r] + bv[nj]
                        + bf2f(resid[(size_t)rgm * 256 + colbase + nj * 16]);
                acc[mi][nj][r] = v;
                s += v; s2 += v * v;
            }
            ps[mi][r] = s; pq[mi][r] = s2;
        }
    }
#pragma unroll
    for (int off = 1; off <= 8; off <<= 1) {
#pragma unroll
        for (int mi = 0; mi < 2; mi++)
#pragma unroll
            for (int r = 0; r < 4; r++) {
                ps[mi][r] += __shfl_xor(ps[mi][r], off);
                pq[mi][r] += __shfl_xor(pq[mi][r], off);
            }
    }
    // cross-wave (wc) merge via LDS (reuse buf0: 64 rows x 4 wc x 2 vals = 2 KB)
    float* rs = (float*)(&LDS[0][0]);   // [64][4]
    float* rq = rs + 256;
    if (lh == 0) {
#pragma unroll
        for (int mi = 0; mi < 2; mi++)
#pragma unroll
            for (int r = 0; r < 4; r++) {
                int m = wr * 32 + mi * 16 + q * 4 + r;
                rs[m * 4 + wc] = ps[mi][r];
                rq[m * 4 + wc] = pq[mi][r];
            }
    }
    __syncthreads();

#pragma unroll
    for (int mi = 0; mi < 2; mi++) {
#pragma unroll
        for (int r = 0; r < 4; r++) {
            int m = wr * 32 + mi * 16 + q * 4 + r;
            int gm = m0 + m;
            if (gm >= M) continue;
            float4 rsv = *reinterpret_cast<const float4*>(&rs[m * 4]);
            float4 rqv = *reinterpret_cast<const float4*>(&rq[m * 4]);
            float S  = (rsv.x + rsv.y) + (rsv.z + rsv.w);
            float S2 = (rqv.x + rqv.y) + (rqv.z + rqv.w);
            float mean = S * (1.f / (float)D_MODEL);
            float var  = S2 * (1.f / (float)D_MODEL) - mean * mean;
            float inv  = rsqrtf(var + LN_EPS);
#pragma unroll
            for (int nj = 0; nj < 4; nj++)
                out[(size_t)gm * 256 + colbase + nj * 16] =
                    (acc[mi][nj][r] - mean) * inv * gv[nj] + bbv[nj];
        }
    }
}

// ---------------- CSR build ----------------
__global__ void count_kernel(const int* __restrict__ rows, unsigned* __restrict__ counts) {
    int e = blockIdx.x * blockDim.x + threadIdx.x;
    if (e < E_EDGES) atomicAdd(&counts[rows[e]], 1u);
}

__global__ void scan_blk_kernel(const unsigned* __restrict__ counts,
                                unsigned* __restrict__ offs, unsigned* __restrict__ bsum) {
    __shared__ unsigned sh[256];
    int t = threadIdx.x;
    int i = blockIdx.x * 256 + t;
    unsigned v = (i < N_NODES) ? counts[i] : 0u;
    sh[t] = v;
    __syncthreads();
#pragma unroll
    for (int off = 1; off < 256; off <<= 1) {
        unsigned u = (t >= off) ? sh[t - off] : 0u;
        __syncthreads();
        sh[t] += u;
        __syncthreads();
    }
    if (i < N_NODES) offs[i] = sh[t] - v;
    if (t == 255) bsum[blockIdx.x] = sh[255];
}

__global__ void scan_top_kernel(const unsigned* __restrict__ bsum, unsigned* __restrict__ bpre) {
    __shared__ unsigned sh[256];
    int t = threadIdx.x;
    unsigned v = (t < NB_SCAN) ? bsum[t] : 0u;
    sh[t] = v;
    __syncthreads();
#pragma unroll
    for (int off = 1; off < 256; off <<= 1) {
        unsigned u = (t >= off) ? sh[t - off] : 0u;
        __syncthreads();
        sh[t] += u;
        __syncthreads();
    }
    if (t < NB_SCAN) bpre[t] = sh[t] - v;
    if (t == NB_SCAN - 1) bpre[NB_SCAN] = sh[t];
}

// scatter folds the top-level prefix (bpre) in on the fly -> scan_add kernel removed.
__global__ void scatter_kernel(const int* __restrict__ rows, const int* __restrict__ cols,
                               const unsigned* __restrict__ offsets,
                               const unsigned* __restrict__ bpre,
                               unsigned* __restrict__ cursor,
                               int* __restrict__ scol) {
    int e = blockIdx.x * blockDim.x + threadIdx.x;
    if (e >= E_EDGES) return;
    int r = rows[e];
    unsigned idx = atomicAdd(&cursor[r], 1u);
    scol[offsets[r] + bpre[r >> 8] + idx] = cols[e];
}

// ---------------- attention (wave-per-node, PAIR-EDGE fp8 k/v) + fused LN1 -----------
// Block = 2 nodes, one wave each. Two 32-lane halves process TWO edges at once:
// half-lane hl owns dims 8hl..8hl+7 (16B of the 512B kv row). DPP quad reduce.
// 8-edge batches, 4 dwordx4 gathers in flight, byte-offsets prefetched one batch
// ahead. Row offsets composed from offsets[] + bpre[] (scan_add folded in).
__global__ __launch_bounds__(128)
void att_agg_kernel(const __hip_bfloat16* __restrict__ qb,
                    const unsigned char* __restrict__ kv8,
                    const unsigned* __restrict__ offsets,
                    const unsigned* __restrict__ bpre,
                    const int* __restrict__ scol,
                    const __hip_bfloat16* __restrict__ xres,
                    const float* __restrict__ g, const float* __restrict__ bb,
                    __hip_bfloat16* __restrict__ xn) {
    int n = blockIdx.x * 2 + (threadIdx.x >> 6);
    if (n >= N_NODES) return;
    const int lam = threadIdx.x & 63;
    const int hl  = lam & 31;          // dims 8hl..8hl+7
    const int sel = lam >> 5;          // which edge of the pair
    const unsigned hlb = hl * 16;      // byte offset within kv row
    unsigned beg = offsets[n] + bpre[n >> 8];
    unsigned end = (n + 1 == N_NODES) ? bpre[NB_SCAN]
                                      : offsets[n + 1] + bpre[(n + 1) >> 8];

    float qv[8];
    {
        uint4 u = *reinterpret_cast<const uint4*>(qb + (size_t)n * 256 + hl * 8);
        unpack_bf8(u, qv);
#pragma unroll
        for (int i = 0; i < 8; i++) qv[i] *= ATT_SCALE;
    }

    float acc[8] = {};
    float l = 0.f;

    // w.x = k[8hl..8hl+3], w.y = v[8hl..8hl+3], w.z = k[8hl+4..], w.w = v[8hl+4..]
#define PAIR_BODY(W, VMUL)                                                      \
    {                                                                           \
        auto k01 = __builtin_amdgcn_cvt_pk_f32_fp8((int)(W).x, false);          \
        auto k23 = __builtin_amdgcn_cvt_pk_f32_fp8((int)(W).x, true);           \
        auto k45 = __builtin_amdgcn_cvt_pk_f32_fp8((int)(W).z, false);          \
        auto k67 = __builtin_amdgcn_cvt_pk_f32_fp8((int)(W).z, true);           \
        float sv = qv[0] * k01[0] + qv[1] * k01[1] + qv[2] * k23[0]             \
                 + qv[3] * k23[1] + qv[4] * k45[0] + qv[5] * k45[1]             \
                 + qv[6] * k67[0] + qv[7] * k67[1];                             \
        sv = dpp_add<0xB1>(sv);   /* xor1 within quad */                        \
        sv = dpp_add<0x4E>(sv);   /* xor2 within quad */                        \
        float pv = __expf(sv) * (VMUL);                                         \
        l += pv;                                                                \
        auto v01 = __builtin_amdgcn_cvt_pk_f32_fp8((int)(W).y, false);          \
        auto v23 = __builtin_amdgcn_cvt_pk_f32_fp8((int)(W).y, true);           \
        auto v45 = __builtin_amdgcn_cvt_pk_f32_fp8((int)(W).w, false);          \
        auto v67 = __builtin_amdgcn_cvt_pk_f32_fp8((int)(W).w, true);           \
        acc[0] += pv * v01[0]; acc[1] += pv * v01[1];                           \
        acc[2] += pv * v23[0]; acc[3] += pv * v23[1];                           \
        acc[4] += pv * v45[0]; acc[5] += pv * v45[1];                           \
        acc[6] += pv * v67[0]; acc[7] += pv * v67[1];                           \
    }

    unsigned e = beg;
    unsigned oA = 0, oB = 0, oC = 0, oD = 0;
    if (e + 8 <= end) {
        oA = ((unsigned)scol[e + sel])     << 9;
        oB = ((unsigned)scol[e + 2 + sel]) << 9;
        oC = ((unsigned)scol[e + 4 + sel]) << 9;
        oD = ((unsigned)scol[e + 6 + sel]) << 9;
    }
    while (e + 8 <= end) {
        uint4 wa = *reinterpret_cast<const uint4*>(kv8 + (oA + hlb));
        uint4 wb = *reinterpret_cast<const uint4*>(kv8 + (oB + hlb));
        uint4 wc = *reinterpret_cast<const uint4*>(kv8 + (oC + hlb));
        uint4 wd = *reinterpret_cast<const uint4*>(kv8 + (oD + hlb));
        e += 8;
        if (e + 8 <= end) {                 // prefetch next batch's byte offsets
            oA = ((unsigned)scol[e + sel])     << 9;
            oB = ((unsigned)scol[e + 2 + sel]) << 9;
            oC = ((unsigned)scol[e + 4 + sel]) << 9;
            oD = ((unsigned)scol[e + 6 + sel]) << 9;
        }
        PAIR_BODY(wa, 1.0f)
        PAIR_BODY(wb, 1.0f)
        PAIR_BODY(wc, 1.0f)
        PAIR_BODY(wd, 1.0f)
    }
    for (; e + 2 <= end; e += 2) {
        unsigned o0 = ((unsigned)scol[e + sel]) << 9;
        uint4 wa = *reinterpret_cast<const uint4*>(kv8 + (o0 + hlb));
        PAIR_BODY(wa, 1.0f)
    }
    if (e < end) {                           // odd tail: upper half masked to 0
        unsigned o0 = ((unsigned)scol[e]) << 9;
        uint4 wa = *reinterpret_cast<const uint4*>(kv8 + (o0 + hlb));
        PAIR_BODY(wa, sel ? 0.0f : 1.0f)
    }
#undef PAIR_BODY

    // merge the two halves (different edges, same dims)
    l += __shfl_xor(l, 32);
#pragma unroll
    for (int i = 0; i < 8; i++) acc[i] += __shfl_xor(acc[i], 32);

    float inv_l = (l > 0.f) ? 1.f / l : 0.f;

    float tv[8];
    {
        float xv[8];
        uint4 u = *reinterpret_cast<const uint4*>(xres + (size_t)n * D_MODEL + hl * 8);
        unpack_bf8(u, xv);
#pragma unroll
        for (int i = 0; i < 8; i++) tv[i] = acc[i] * inv_l + xv[i];
    }

    float s = 0.f, s2 = 0.f;
#pragma unroll
    for (int i = 0; i < 8; i++) { s += tv[i]; s2 += tv[i] * tv[i]; }
#pragma unroll
    for (int off = 1; off <= 16; off <<= 1) {   // sum within each 32-lane half
        s  += __shfl_xor(s, off);
        s2 += __shfl_xor(s2, off);
    }
    float mean = s * (1.f / (float)D_MODEL);
    float var  = s2 * (1.f / (float)D_MODEL) - mean * mean;
    float inv  = rsqrtf(var + LN_EPS);

    if (sel == 0) {                          // lower half writes the full row
        const float4* gp = reinterpret_cast<const float4*>(g);
        const float4* bp = reinterpret_cast<const float4*>(bb);
        float4 g0 = gp[hl * 2], g1 = gp[hl * 2 + 1];
        float4 b0 = bp[hl * 2], b1 = bp[hl * 2 + 1];
        float gv[8] = {g0.x, g0.y, g0.z, g0.w, g1.x, g1.y, g1.z, g1.w};
        float bv[8] = {b0.x, b0.y, b0.z, b0.w, b1.x, b1.y, b1.z, b1.w};
        u16x8 o;
#pragma unroll
        for (int i = 0; i < 8; i++)
            o[i] = bfbits((tv[i] - mean) * inv * gv[i] + bv[i]);
        *reinterpret_cast<u16x8*>(xn + (size_t)n * D_MODEL + hl * 8) = o;
    }
}

extern "C" void kernel_launch(void* const* d_in, const int* in_sizes, int n_in,
                              void* d_out, int out_size, void* d_ws, size_t ws_size,
                              hipStream_t stream) {
    const float* x     = (const float*)d_in[0];
    const int*   ei    = (const int*)d_in[1];
    const float* w_qkv = (const float*)d_in[2];
    const float* b_qkv = (const float*)d_in[3];
    const float* ln1_g = (const float*)d_in[4];
    const float* ln1_b = (const float*)d_in[5];
    const float* ln2_g = (const float*)d_in[6];
    const float* ln2_b = (const float*)d_in[7];
    const float* w1    = (const float*)d_in[8];
    const float* b1    = (const float*)d_in[9];
    const float* w2    = (const float*)d_in[10];
    const float* b2    = (const float*)d_in[11];
    const int* rows = ei;
    const int* cols = ei + E_EDGES;

    // workspace layout (bytes), total < 179,200,000 (known-good footprint):
    //   [0,          25,600,000)  qb  bf16 N*256 } dead after att_agg;
    //   [25,600,000, 51,200,000)  kv8 fp8  N*512 } region [0,102.4e6) reused
    //                                            } as hbuf bf16 N*1024
    //   [102,400,000,128,000,000) xb bf16 N*256 (live through att_agg: residual src)
    //   [128,000,000,128,393,216) wtq bf16 768x256 (perm cols)
    //   [128,400,000,128,924,288) wt1 bf16 1024x256 (perm cols)
    //   [129,000,000,129,524,288) wt2 bf16 256x1024
    //   [129,600,000,129,800,000) counts u32 N
    //   [129,800,000,130,000,004) offsets u32 N+1 (block-local prefixes)
    //   [130,000,008,130,200,008) cursor u32 N
    //   [130,200,008,133,400,008) scol i32 E
    //   [133,400,008,133,401,032) bsum u32 256
    //   [133,401,032,133,402,060) bpre u32 257
    //   [133,500,000,133,503,072) bqp f32 768 (perm qkv bias)
    //   [133,510,000,133,514,096) b1p f32 1024 (perm ffn1 bias)
    //   [153,600,000,179,200,000) xn bf16 N*256
    char* ws = (char*)d_ws;
    __hip_bfloat16* qb      = (__hip_bfloat16*)(ws + 0);
    unsigned char*  kv8     = (unsigned char*)(ws + 25600000);
    __hip_bfloat16* hbuf    = (__hip_bfloat16*)(ws + 0);
    __hip_bfloat16* xb      = (__hip_bfloat16*)(ws + 102400000);
    __hip_bfloat16* wtq     = (__hip_bfloat16*)(ws + 128000000);
    __hip_bfloat16* wt1     = (__hip_bfloat16*)(ws + 128400000);
    __hip_bfloat16* wt2     = (__hip_bfloat16*)(ws + 129000000);
    unsigned*       counts  = (unsigned*)(ws + 129600000);
    unsigned*       offsets = (unsigned*)(ws + 129800000);
    unsigned*       cursor  = (unsigned*)(ws + 130000008);
    int*            scol    = (int*)(ws + 130200008);
    unsigned*       bsum    = (unsigned*)(ws + 133400008);
    unsigned*       bpre    = (unsigned*)(ws + 133401032);
    float*          bqp     = (float*)(ws + 133500000);
    float*          b1p     = (float*)(ws + 133510000);
    __hip_bfloat16* xn      = (__hip_bfloat16*)(ws + 153600000);

    const int nbM = (N_NODES + 127) / 128;   // 391

    // fused prep: x->bf16, perm weights/biases, zero counts/cursor
    prep_kernel<<<(PREP_TOT + 255) / 256, 256, 0, stream>>>(
        x, (unsigned short*)xb, w_qkv, wtq, w1, wt1, w2, wt2,
        b_qkv, bqp, b1, b1p, counts, cursor);

    // q(bf16)/kv(fp8) = split(xb @ wtq^T + bqp), counted-vmcnt 3-buf pipeline
    mfma_gemm<false, 0, 256><<<dim3(768 / 128, nbM), 256, 0, stream>>>(
        xb, wtq, bqp, nullptr, qb, kv8, N_NODES, 768);

    // CSR build (hierarchical scan; top-level prefix folded into consumers)
    count_kernel<<<(E_EDGES + 255) / 256, 256, 0, stream>>>(rows, counts);
    scan_blk_kernel<<<NB_SCAN, 256, 0, stream>>>(counts, offsets, bsum);
    scan_top_kernel<<<1, 256, 0, stream>>>(bsum, bpre);
    scatter_kernel<<<(E_EDGES + 255) / 256, 256, 0, stream>>>(rows, cols, offsets, bpre,
                                                              cursor, scol);

    // attention (pair-edge, 8-edge pipelined, DPP reduce, bf16 residual) + LN1 -> xn
    att_agg_kernel<<<(N_NODES + 1) / 2, 128, 0, stream>>>(qb, kv8, offsets, bpre, scol,
                                                          xb, ln1_g, ln1_b, xn);

    // hbuf = relu(xn @ wt1^T + b1p), counted-vmcnt 3-buf pipeline
    mfma_gemm<true, 1, 256><<<dim3(F_FFN / 128, nbM), 256, 0, stream>>>(
        xn, wt1, b1p, hbuf, nullptr, nullptr, N_NODES, F_FFN);

    // d_out = LN2(hbuf @ wt2^T + b2 + xn)   (fused, f32 out; counted-vmcnt pipeline)
    ffn2_ln_kernel<<<(N_NODES + 63) / 64, 512, 0, stream>>>(hbuf, wt2, b2, xn, ln2_g, ln2_b,
                                                            (float*)d_out, N_NODES);
}